// Round 3
// 1351.633 us; speedup vs baseline: 1.0295x; 1.0295x over previous
//
// MultiheadSelectiveAttentionWithTokenPruning — MI355X round 2
//
// Pipeline (all on `stream`, graph-capture safe, no statics):
//  1  cast_x      : X fp32 -> Xhi/Xlo bf16 (split for bf16x3 GEMM)
//  2  cast_w x4   : W fp32 -> W^T bf16 (hi[+lo for Wq/Wk])
//  3  gemm split  : Yq = X@Wq  (hi*hi + hi*lo + lo*hi)  ~fp32 accuracy
//  4  gemm split  : Yk = X@Wk
//  5  gemm        : Yv = X@Wv  (plain bf16)
//  6  lnpack      : LN(Yq) -> Qb bf16 + q0s fp32 (head-0 selection)
//  7  lnpack      : LN(Yk) -> Kb + k0s
//  8  lnpack      : Yv -> Vb (cast only)
//  9  s_kernel    : S[b,n,m] = relu(q0s.k0s/8), causal/diag/col0-zeroed
// 10  p_kernel    : column partial sums of S rows 0..1023 (8 chunks)
// 11  evict       : ROUND-1 REWRITE. 1024 sequential argmax evictions on a
//                   SINGLE WAVE per batch (64 thr): no barriers, no LDS.
//                   Lane owns 32 slots (8 chunks x float4). Evicted slot =
//                   cum set to -inf; candidate pack compared as SIGNED i64
//                   (hi = float bits: monotonic for cum>=0, -inf loses).
//                   Insertion via per-segment partial-chunk predicate
//                   (4 template instantiations, chunk activity compile-time).
//                   Tie-break low word = 2048-m  -> smallest m on value tie
//                   (identical semantics to round-0 kernel; bit-identical
//                   accumulation order -> identical evt output).
//                   S rows double-banked in registers, prefetched one
//                   iteration ahead.
// 12  flash       : all 16 heads, online softmax, mask = causal && n<evt[m]
// 13  gemm        : out = Ob @ Wo -> d_out fp32
//
// ws overlays: Ob reuses Xhi slot (dead after step 5); S reuses Yq+Yk slots
// (dead after steps 6/7). Peak ws ~107.1 MB.

#include <hip/hip_runtime.h>

#define B_    2
#define N_    2048
#define D_    1024
#define H_    16
#define DH_   64
#define M_    2048
#define ROWS_ 4096
#define BUD_  1024

typedef unsigned short u16;
typedef unsigned int   u32;
typedef unsigned long long u64;
typedef __attribute__((ext_vector_type(8))) short short8;
typedef __attribute__((ext_vector_type(4))) float floatx4;

__device__ __forceinline__ u16 f2b(float f) {
    u32 u = __float_as_uint(f);
    return (u16)((u + 0x7FFFu + ((u >> 16) & 1u)) >> 16);   // RNE
}
__device__ __forceinline__ float b2f(u16 h) {
    return __uint_as_float(((u32)h) << 16);
}

// ---------------------------------------------------------------- cast X
__global__ __launch_bounds__(256) void cast_x_kernel(
    const float* __restrict__ X, u16* __restrict__ Xhi, u16* __restrict__ Xlo)
{
    int idx = (blockIdx.x * 256 + threadIdx.x) * 4;
    float4 v = *(const float4*)&X[idx];
    u16 h0 = f2b(v.x), h1 = f2b(v.y), h2 = f2b(v.z), h3 = f2b(v.w);
    ushort4 hv; hv.x = h0; hv.y = h1; hv.z = h2; hv.w = h3;
    *(ushort4*)&Xhi[idx] = hv;
    ushort4 lv;
    lv.x = f2b(v.x - b2f(h0)); lv.y = f2b(v.y - b2f(h1));
    lv.z = f2b(v.z - b2f(h2)); lv.w = f2b(v.w - b2f(h3));
    *(ushort4*)&Xlo[idx] = lv;
}

// ------------------------------------------------- cast + transpose W
__global__ __launch_bounds__(1024) void cast_w_kernel(
    const float* __restrict__ W, u16* __restrict__ Whi, u16* __restrict__ Wlo,
    int do_lo)
{
    __shared__ float tile[32][33];
    int tx = threadIdx.x, ty = threadIdx.y;
    int x = blockIdx.x * 32 + tx, y = blockIdx.y * 32 + ty;
    tile[ty][tx] = W[(size_t)y * D_ + x];
    __syncthreads();
    float v = tile[tx][ty];
    int n = blockIdx.x * 32 + ty, k = blockIdx.y * 32 + tx;
    u16 h = f2b(v);
    Whi[(size_t)n * D_ + k] = h;
    if (do_lo) Wlo[(size_t)n * D_ + k] = f2b(v - b2f(h));
}

// ------------------------------------------------------------- GEMM
// C[4096][1024] = A[4096][1024] @ Bt^T   (Bt stored [n][k])
// mode 1: C = Ah*Bh + Ah*Bl + Al*Bh  (bf16x3 split, ~fp32 precision)
__global__ __launch_bounds__(256) void gemm_kernel(
    const u16* __restrict__ Ah, const u16* __restrict__ Al,
    const u16* __restrict__ Bh, const u16* __restrict__ Bl,
    int mode, float* __restrict__ C)
{
    __shared__ __align__(16) u16 sAh[128 * 32];
    __shared__ __align__(16) u16 sBh[128 * 32];
    __shared__ __align__(16) u16 sAl[128 * 32];
    __shared__ __align__(16) u16 sBl[128 * 32];
    int tid = threadIdx.x;
    int lane = tid & 63, wv = tid >> 6;
    int wr = wv >> 1, wc = wv & 1;
    int quad = lane >> 4, l16 = lane & 15;
    int m0 = blockIdx.y * 128, n0 = blockIdx.x * 128;

    floatx4 acc[4][4];
    floatx4 zero = {0.f, 0.f, 0.f, 0.f};
#pragma unroll
    for (int i = 0; i < 4; ++i)
#pragma unroll
        for (int j = 0; j < 4; ++j) acc[i][j] = zero;

    for (int k0 = 0; k0 < 1024; k0 += 32) {
#pragma unroll
        for (int it = 0; it < 2; ++it) {
            int e = (tid + it * 256) * 8;
            int r = e >> 5, c = e & 31;
            *(uint4*)&sAh[e] = *(const uint4*)&Ah[(size_t)(m0 + r) * 1024 + k0 + c];
            *(uint4*)&sBh[e] = *(const uint4*)&Bh[(size_t)(n0 + r) * 1024 + k0 + c];
            if (mode) {
                *(uint4*)&sAl[e] = *(const uint4*)&Al[(size_t)(m0 + r) * 1024 + k0 + c];
                *(uint4*)&sBl[e] = *(const uint4*)&Bl[(size_t)(n0 + r) * 1024 + k0 + c];
            }
        }
        __syncthreads();
        short8 ah[4], al[4], bh[4], bl[4];
#pragma unroll
        for (int x = 0; x < 4; ++x) {
            int ra = (wr * 64 + x * 16 + l16) * 32 + quad * 8;
            int rb = (wc * 64 + x * 16 + l16) * 32 + quad * 8;
            ah[x] = *(const short8*)&sAh[ra];
            bh[x] = *(const short8*)&sBh[rb];
            if (mode) {
                al[x] = *(const short8*)&sAl[ra];
                bl[x] = *(const short8*)&sBl[rb];
            }
        }
#pragma unroll
        for (int mi = 0; mi < 4; ++mi)
#pragma unroll
            for (int ni = 0; ni < 4; ++ni) {
                acc[mi][ni] = __builtin_amdgcn_mfma_f32_16x16x32_bf16(
                    ah[mi], bh[ni], acc[mi][ni], 0, 0, 0);
                if (mode) {
                    acc[mi][ni] = __builtin_amdgcn_mfma_f32_16x16x32_bf16(
                        ah[mi], bl[ni], acc[mi][ni], 0, 0, 0);
                    acc[mi][ni] = __builtin_amdgcn_mfma_f32_16x16x32_bf16(
                        al[mi], bh[ni], acc[mi][ni], 0, 0, 0);
                }
            }
        __syncthreads();
    }
    // C/D layout: col = lane&15, row = (lane>>4)*4 + reg   [verified m89/m91]
#pragma unroll
    for (int mi = 0; mi < 4; ++mi)
#pragma unroll
        for (int ni = 0; ni < 4; ++ni)
#pragma unroll
            for (int r = 0; r < 4; ++r) {
                int row = m0 + wr * 64 + mi * 16 + quad * 4 + r;
                int col = n0 + wc * 64 + ni * 16 + l16;
                C[(size_t)row * 1024 + col] = acc[mi][ni][r];
            }
}

// ----------------------------------------------------- LayerNorm + pack
__global__ __launch_bounds__(256) void lnpack_kernel(
    const float* __restrict__ Y, const float* __restrict__ gamma,
    const float* __restrict__ beta, u16* __restrict__ Pk,
    float* __restrict__ head0, int do_ln)
{
    int r = blockIdx.x;
    int tid = threadIdx.x;
    float4 v = *(const float4*)&Y[(size_t)r * D_ + tid * 4];
    float mu = 0.f, rsig = 1.f;
    __shared__ float sS[4], sQ[4];
    if (do_ln) {
        float s = v.x + v.y + v.z + v.w;
        float q = v.x * v.x + v.y * v.y + v.z * v.z + v.w * v.w;
#pragma unroll
        for (int d = 1; d < 64; d <<= 1) { s += __shfl_xor(s, d); q += __shfl_xor(q, d); }
        if ((tid & 63) == 0) { sS[tid >> 6] = s; sQ[tid >> 6] = q; }
        __syncthreads();
        s = sS[0] + sS[1] + sS[2] + sS[3];
        q = sQ[0] + sQ[1] + sQ[2] + sQ[3];
        mu = s * (1.f / 1024.f);
        float var = q * (1.f / 1024.f) - mu * mu;
        rsig = rsqrtf(var + 1e-5f);
    }
    int b = r >> 11, n = r & 2047;
    float xs[4] = {v.x, v.y, v.z, v.w};
#pragma unroll
    for (int j = 0; j < 4; ++j) {
        int c = tid * 4 + j;
        float val = do_ln ? ((xs[j] - mu) * rsig * gamma[c] + beta[c]) : xs[j];
        int h = c >> 6, dh = c & 63;
        Pk[(((size_t)b * H_ + h) * N_ + n) * DH_ + dh] = f2b(val);
        if (head0 && c < 64) head0[(size_t)r * 64 + c] = val;
    }
}

// -------------------------------------------- head-0 selection scores S
__global__ void s_kernel(const float* __restrict__ q0,
                         const float* __restrict__ k0, float* __restrict__ S)
{
    int b = blockIdx.z;
    int n0 = blockIdx.y * 16, m0 = blockIdx.x * 16;
    int tx = threadIdx.x, ty = threadIdx.y;
    int n = n0 + ty, m = m0 + tx;
    float* out = S + ((size_t)b * N_ + n) * M_ + m;
    if (m0 > n0 + 15) { *out = 0.f; return; }   // fully above diagonal
    __shared__ float sq[16][65], sk[16][65];
    int tid = ty * 16 + tx;
    {
        int rr = tid >> 4, cc = (tid & 15) * 4;
        float4 qa = *(const float4*)&q0[((size_t)b * N_ + n0 + rr) * 64 + cc];
        sq[rr][cc] = qa.x; sq[rr][cc + 1] = qa.y; sq[rr][cc + 2] = qa.z; sq[rr][cc + 3] = qa.w;
        float4 ka = *(const float4*)&k0[((size_t)b * N_ + m0 + rr) * 64 + cc];
        sk[rr][cc] = ka.x; sk[rr][cc + 1] = ka.y; sk[rr][cc + 2] = ka.z; sk[rr][cc + 3] = ka.w;
    }
    __syncthreads();
    float acc = 0.f;
#pragma unroll 8
    for (int d = 0; d < 64; ++d) acc += sq[ty][d] * sk[tx][d];
    // causal (m>n) -> relu(-inf)=0 ; diagonal m==n -> 0 ; col 0 -> 0
    float val;
    if (m < n && m != 0) val = fmaxf(acc * 0.125f, 0.f); else val = 0.f;
    *out = val;
}

// -------------------------------- partial column sums of S rows 0..1023
__global__ __launch_bounds__(256) void p_kernel(const float* __restrict__ S,
                                                float* __restrict__ P)
{
    int b = blockIdx.z, c = blockIdx.y;
    int m = blockIdx.x * 256 + threadIdx.x;
    const float* base = S + ((size_t)b * N_ + c * 128) * M_ + m;
    float s = 0.f;
    for (int j = 0; j < 128; ++j) s += base[(size_t)j * M_];
    P[((size_t)b * 8 + c) * M_ + m] = s;
}

// --------------------------------------------- sequential greedy eviction
// Single wave (64 lanes) per batch: no barriers, no LDS. Lane t owns slots
// m = c*256 + 4t + e (c chunk 0..7, e 0..3), values in cum[8][4] registers.
//   - evicted slot  -> cum = -inf  (stays -inf: adds are nonneg/-inf)
//   - candidate pack = SIGNED i64 { hi = float bits of cum, lo = 2048-m }
//     nonneg float bits sort correctly as signed int; -inf hi is negative
//     and always loses; lo tie-break -> smallest m (first-max semantics).
//   - chunk activity: chunks 0..NC-1 full, chunk NC partial (m<=i), >NC
//     excluded from argmax but still accumulated. NC = i>>8 via 4 template
//     instantiations (compile-time chunk classification).
//   - S rows double-banked in registers, prefetched one iteration ahead.
__device__ __forceinline__ long long maxll(long long a, long long b) {
    return a > b ? a : b;
}

template<int NC>
__device__ __forceinline__ void evict_step(
    int i, int t, int lo0, int m0, float (&cum)[8][4],
    const float4 (&rr)[8], int* __restrict__ evtb)
{
    const float NEGINF = __uint_as_float(0xFF800000u);
    const int relm = (i & 255) - m0;          // partial chunk: active iff e <= relm
    long long cb[NC + 1];
#pragma unroll
    for (int c = 0; c <= NC; ++c) {
        long long p[4];
#pragma unroll
        for (int e = 0; e < 4; ++e) {
            float v = cum[c][e];
            if (c == NC) v = (relm >= e) ? v : NEGINF;
            p[e] = ((long long)(int)__float_as_uint(v) << 32) |
                   (u32)(lo0 - c * 256 - e);
        }
        cb[c] = maxll(maxll(p[0], p[1]), maxll(p[2], p[3]));
    }
    long long best = cb[0];
#pragma unroll
    for (int c = 1; c <= NC; ++c) best = maxll(best, cb[c]);
#pragma unroll
    for (int d = 1; d < 64; d <<= 1) {
        long long o = __shfl_xor(best, d);
        best = maxll(best, o);
    }
    int mstar = 2048 - (int)(u32)(best & 0xFFFFFFFFLL);
    if (t == 0) evtb[mstar] = i;
    const int dd = mstar - m0;                // slot hit iff dd == c*256+e
#pragma unroll
    for (int c = 0; c < 8; ++c) {
        float rv[4] = {rr[c].x, rr[c].y, rr[c].z, rr[c].w};
#pragma unroll
        for (int e = 0; e < 4; ++e) {
            float nv = cum[c][e] + rv[e];
            if (c <= NC) cum[c][e] = (dd == c * 256 + e) ? NEGINF : nv;
            else         cum[c][e] = nv;
        }
    }
}

template<int NC>
__device__ __forceinline__ void evict_seg(
    int t, float (&cum)[8][4], float4 (&bankA)[8], float4 (&bankB)[8],
    const float* __restrict__ Sb, int* __restrict__ evtb)
{
    const int lo0 = 2048 - 4 * t;
    const int m0 = 4 * t;
#pragma unroll 1
    for (int ip = NC * 256; ip < NC * 256 + 256; ip += 2) {
        // prefetch row ip+1 (consumed at end of second step this trip)
#pragma unroll
        for (int c = 0; c < 8; ++c)
            bankB[c] = *(const float4*)&Sb[(size_t)(ip + 1) * M_ + c * 256 + m0];
        evict_step<NC>(ip, t, lo0, m0, cum, bankA, evtb);
        if (ip + 2 < 2048) {
            // prefetch row ip+2 (consumed at end of next trip's first step)
#pragma unroll
            for (int c = 0; c < 8; ++c)
                bankA[c] = *(const float4*)&Sb[(size_t)(ip + 2) * M_ + c * 256 + m0];
        }
        evict_step<NC>(ip + 1, t, lo0, m0, cum, bankB, evtb);
    }
}

__global__ __launch_bounds__(64) void evict_kernel(
    const float* __restrict__ S, const float* __restrict__ P,
    int* __restrict__ evt)
{
    int b = blockIdx.x, t = threadIdx.x;       // 64 threads = 1 wave
    const float* Sb = S + (size_t)b * N_ * M_;
    int* evtb = evt + b * M_;
    // initial cum = column sums of the 8 partial chunks (same add order as
    // round 0 -> bitwise identical trajectories -> identical argmax results)
    float cum[8][4];
#pragma unroll
    for (int c = 0; c < 8; ++c) {
        float ax = 0.f, ay = 0.f, az = 0.f, aw = 0.f;
#pragma unroll
        for (int cc = 0; cc < 8; ++cc) {
            float4 pv = *(const float4*)&P[((size_t)b * 8 + cc) * M_ + c * 256 + 4 * t];
            ax += pv.x; ay += pv.y; az += pv.z; aw += pv.w;
        }
        cum[c][0] = ax; cum[c][1] = ay; cum[c][2] = az; cum[c][3] = aw;
    }
#pragma unroll
    for (int c = 0; c < 8; ++c) {
        int4 big = {0x3FFFFFFF, 0x3FFFFFFF, 0x3FFFFFFF, 0x3FFFFFFF};
        *(int4*)&evtb[c * 256 + 4 * t] = big;
    }
    float4 bankA[8], bankB[8];
#pragma unroll
    for (int c = 0; c < 8; ++c)
        bankA[c] = *(const float4*)&Sb[(size_t)1024 * M_ + c * 256 + 4 * t];
    evict_seg<4>(t, cum, bankA, bankB, Sb, evtb);
    evict_seg<5>(t, cum, bankA, bankB, Sb, evtb);
    evict_seg<6>(t, cum, bankA, bankB, Sb, evtb);
    evict_seg<7>(t, cum, bankA, bankB, Sb, evtb);
}

// ------------------------------------------------------ flash attention
__global__ __launch_bounds__(256) void flash_kernel(
    const u16* __restrict__ Qb, const u16* __restrict__ Kb,
    const u16* __restrict__ Vb, const int* __restrict__ evt,
    u16* __restrict__ Ob)
{
    int bh = blockIdx.y;
    int b = bh >> 4, h = bh & 15;
    int q0 = blockIdx.x * 64;
    int tid = threadIdx.x, lane = tid & 63, w = tid >> 6;
    int quad = lane >> 4, l16 = lane & 15;
    const u16* Qh = Qb + (size_t)bh * N_ * DH_;
    const u16* Kh = Kb + (size_t)bh * N_ * DH_;
    const u16* Vh = Vb + (size_t)bh * N_ * DH_;
    __shared__ __align__(16) u16 sK[64 * 64];
    __shared__ __align__(16) u16 sV[64 * 64];     // transposed [dh][key]
    __shared__ __align__(16) u16 sP[4][16 * 64];  // wave-private P
    __shared__ int sevt[64];

    // Q A-frags in registers: A[m=lane&15][k=quad*8+j]
    short8 aq0 = *(const short8*)&Qh[(size_t)(q0 + w * 16 + l16) * 64 + quad * 8];
    short8 aq1 = *(const short8*)&Qh[(size_t)(q0 + w * 16 + l16) * 64 + quad * 8 + 32];

    floatx4 zero = {0.f, 0.f, 0.f, 0.f};
    floatx4 accO[4];
#pragma unroll
    for (int d = 0; d < 4; ++d) accO[d] = zero;
    float m_i[4] = {-1e30f, -1e30f, -1e30f, -1e30f};
    float l_i[4] = {0.f, 0.f, 0.f, 0.f};

    int ktiles = blockIdx.x + 1;
    for (int kt = 0; kt < ktiles; ++kt) {
        int k0 = kt * 64;
#pragma unroll
        for (int it = 0; it < 2; ++it) {
            int e = (tid + it * 256) * 8;
            int r = e >> 6, c = e & 63;
            *(uint4*)&sK[e] = *(const uint4*)&Kh[(size_t)(k0 + r) * 64 + c];
            uint4 vv = *(const uint4*)&Vh[(size_t)(k0 + r) * 64 + c];
            sV[(c + 0) * 64 + r] = (u16)(vv.x & 0xFFFF);
            sV[(c + 1) * 64 + r] = (u16)(vv.x >> 16);
            sV[(c + 2) * 64 + r] = (u16)(vv.y & 0xFFFF);
            sV[(c + 3) * 64 + r] = (u16)(vv.y >> 16);
            sV[(c + 4) * 64 + r] = (u16)(vv.z & 0xFFFF);
            sV[(c + 5) * 64 + r] = (u16)(vv.z >> 16);
            sV[(c + 6) * 64 + r] = (u16)(vv.w & 0xFFFF);
            sV[(c + 7) * 64 + r] = (u16)(vv.w >> 16);
        }
        if (tid < 64) sevt[tid] = evt[b * M_ + k0 + tid];
        __syncthreads();

        floatx4 lg[4];
        int nbase = q0 + w * 16 + quad * 4;
#pragma unroll
        for (int s = 0; s < 4; ++s) {
            floatx4 sc = zero;
            short8 bk0 = *(const short8*)&sK[(s * 16 + l16) * 64 + quad * 8];
            short8 bk1 = *(const short8*)&sK[(s * 16 + l16) * 64 + quad * 8 + 32];
            sc = __builtin_amdgcn_mfma_f32_16x16x32_bf16(aq0, bk0, sc, 0, 0, 0);
            sc = __builtin_amdgcn_mfma_f32_16x16x32_bf16(aq1, bk1, sc, 0, 0, 0);
            int m = k0 + s * 16 + l16;
            int ev = sevt[s * 16 + l16];
#pragma unroll
            for (int r = 0; r < 4; ++r) {
                int n = nbase + r;
                bool keep = (m <= n) && (n < ev);
                lg[s][r] = keep ? sc[r] * 0.125f : -1e30f;
            }
        }
        float mnew[4], scale[4], rs[4];
#pragma unroll
        for (int r = 0; r < 4; ++r) {
            float mx = fmaxf(fmaxf(lg[0][r], lg[1][r]), fmaxf(lg[2][r], lg[3][r]));
#pragma unroll
            for (int d = 1; d < 16; d <<= 1) mx = fmaxf(mx, __shfl_xor(mx, d));
            mnew[r] = fmaxf(m_i[r], mx);
            scale[r] = __expf(m_i[r] - mnew[r]);
            m_i[r] = mnew[r];
            rs[r] = 0.f;
        }
#pragma unroll
        for (int s = 0; s < 4; ++s)
#pragma unroll
            for (int r = 0; r < 4; ++r) {
                float p = __expf(lg[s][r] - mnew[r]);
                rs[r] += p;
                sP[w][(quad * 4 + r) * 64 + s * 16 + l16] = f2b(p);
            }
#pragma unroll
        for (int r = 0; r < 4; ++r) {
            float t_ = rs[r];
#pragma unroll
            for (int d = 1; d < 16; d <<= 1) t_ += __shfl_xor(t_, d);
            l_i[r] = l_i[r] * scale[r] + t_;
        }
#pragma unroll
        for (int dd = 0; dd < 4; ++dd) {
            accO[dd][0] *= scale[0]; accO[dd][1] *= scale[1];
            accO[dd][2] *= scale[2]; accO[dd][3] *= scale[3];
        }
        // P: C-layout -> A-layout via wave-private LDS round-trip
        short8 ap0 = *(const short8*)&sP[w][l16 * 64 + quad * 8];
        short8 ap1 = *(const short8*)&sP[w][l16 * 64 + quad * 8 + 32];
#pragma unroll
        for (int dd = 0; dd < 4; ++dd) {
            short8 bv0 = *(const short8*)&sV[(dd * 16 + l16) * 64 + quad * 8];
            short8 bv1 = *(const short8*)&sV[(dd * 16 + l16) * 64 + quad * 8 + 32];
            accO[dd] = __builtin_amdgcn_mfma_f32_16x16x32_bf16(ap0, bv0, accO[dd], 0, 0, 0);
            accO[dd] = __builtin_amdgcn_mfma_f32_16x16x32_bf16(ap1, bv1, accO[dd], 0, 0, 0);
        }
        __syncthreads();
    }
#pragma unroll
    for (int dd = 0; dd < 4; ++dd)
#pragma unroll
        for (int r = 0; r < 4; ++r) {
            int n = q0 + w * 16 + quad * 4 + r;
            int col = h * 64 + dd * 16 + l16;
            Ob[((size_t)b * N_ + n) * D_ + col] = f2b(accO[dd][r] / l_i[r]);
        }
}

// ---------------------------------------------------------------- launch
extern "C" void kernel_launch(void* const* d_in, const int* in_sizes, int n_in,
                              void* d_out, int out_size, void* d_ws, size_t ws_size,
                              hipStream_t stream)
{
    (void)in_sizes; (void)n_in; (void)out_size; (void)ws_size;
    const float* X  = (const float*)d_in[0];
    const float* Wq = (const float*)d_in[1];
    const float* Wk = (const float*)d_in[2];
    const float* Wv = (const float*)d_in[3];
    const float* Wo = (const float*)d_in[4];
    const float* gq = (const float*)d_in[5];
    const float* bq = (const float*)d_in[6];
    const float* gk = (const float*)d_in[7];
    const float* bk = (const float*)d_in[8];
    // d_in[9] cache_k, d_in[10] cache_v, d_in[11] start_pos: start_pos==0 here.

    char* p = (char*)d_ws;
    const size_t SZ_XH = (size_t)ROWS_ * D_ * 2;   // 8 MiB bf16
    const size_t SZ_W  = (size_t)D_ * D_ * 2;      // 2 MiB bf16
    const size_t SZ_Y  = (size_t)ROWS_ * D_ * 4;   // 16 MiB fp32
    const size_t SZ_PK = (size_t)ROWS_ * D_ * 2;   // 8 MiB bf16
    const size_t SZ_H0 = (size_t)ROWS_ * 64 * 4;   // 1 MiB fp32

    size_t o = 0;
    u16* Xhi = (u16*)(p + o); o += SZ_XH;
    u16* Xlo = (u16*)(p + o); o += SZ_XH;
    u16* Wqh = (u16*)(p + o); o += SZ_W;
    u16* Wql = (u16*)(p + o); o += SZ_W;
    u16* Wkh = (u16*)(p + o); o += SZ_W;
    u16* Wkl = (u16*)(p + o); o += SZ_W;
    u16* Wvh = (u16*)(p + o); o += SZ_W;
    u16* Woh = (u16*)(p + o); o += SZ_W;
    float* Yq = (float*)(p + o); size_t oYq = o; o += SZ_Y;
    float* Yk = (float*)(p + o); o += SZ_Y;
    float* Yv = (float*)(p + o); o += SZ_Y;
    u16* Qb = (u16*)(p + o); o += SZ_PK;
    u16* Kb = (u16*)(p + o); o += SZ_PK;
    u16* Vb = (u16*)(p + o); o += SZ_PK;
    float* q0s = (float*)(p + o); o += SZ_H0;
    float* k0s = (float*)(p + o); o += SZ_H0;
    float* Pp  = (float*)(p + o); o += (size_t)B_ * 8 * M_ * 4;
    int* evt   = (int*)(p + o);  o += (size_t)B_ * M_ * 4;
    // overlays (dead slots):
    float* S = (float*)(p + oYq);   // 32 MiB over Yq+Yk, used after LN
    u16* Ob  = Xhi;                 // 8 MiB over Xhi, used after all X-GEMMs

    cast_x_kernel<<<ROWS_ * D_ / (256 * 4), 256, 0, stream>>>(X, Xhi, Xlo);
    dim3 wgrid(32, 32), wblk(32, 32);
    cast_w_kernel<<<wgrid, wblk, 0, stream>>>(Wq, Wqh, Wql, 1);
    cast_w_kernel<<<wgrid, wblk, 0, stream>>>(Wk, Wkh, Wkl, 1);
    cast_w_kernel<<<wgrid, wblk, 0, stream>>>(Wv, Wvh, nullptr, 0);
    cast_w_kernel<<<wgrid, wblk, 0, stream>>>(Wo, Woh, nullptr, 0);

    dim3 ggrid(D_ / 128, ROWS_ / 128);
    gemm_kernel<<<ggrid, 256, 0, stream>>>(Xhi, Xlo, Wqh, Wql, 1, Yq);
    gemm_kernel<<<ggrid, 256, 0, stream>>>(Xhi, Xlo, Wkh, Wkl, 1, Yk);
    gemm_kernel<<<ggrid, 256, 0, stream>>>(Xhi, nullptr, Wvh, nullptr, 0, Yv);

    lnpack_kernel<<<ROWS_, 256, 0, stream>>>(Yq, gq, bq, Qb, q0s, 1);
    lnpack_kernel<<<ROWS_, 256, 0, stream>>>(Yk, gk, bk, Kb, k0s, 1);
    lnpack_kernel<<<ROWS_, 256, 0, stream>>>(Yv, nullptr, nullptr, Vb, nullptr, 0);

    s_kernel<<<dim3(M_ / 16, N_ / 16, B_), dim3(16, 16), 0, stream>>>(q0s, k0s, S);
    p_kernel<<<dim3(M_ / 256, 8, B_), 256, 0, stream>>>(S, Pp);
    evict_kernel<<<B_, 64, 0, stream>>>(S, Pp, evt);

    flash_kernel<<<dim3(N_ / 64, B_ * H_), 256, 0, stream>>>(Qb, Kb, Vb, evt, Ob);
    gemm_kernel<<<ggrid, 256, 0, stream>>>(Ob, nullptr, Woh, nullptr, 0, (float*)d_out);
}

// Round 4
// 1287.244 us; speedup vs baseline: 1.0810x; 1.0500x over previous
//
// MultiheadSelectiveAttentionWithTokenPruning — MI355X round 3
//
// Pipeline (all on `stream`, graph-capture safe, no statics):
//  1  cast_x      : X fp32 -> Xhi/Xlo bf16 (split for bf16x3 GEMM)
//  2  cast_w x4   : W fp32 -> W^T bf16 (hi[+lo for Wq/Wk])
//  3  gemm split  : Yq = X@Wq  (hi*hi + hi*lo + lo*hi)  ~fp32 accuracy
//  4  gemm split  : Yk = X@Wk
//  5  gemm        : Yv = X@Wv  (plain bf16)
//  6  lnpack      : LN(Yq) -> Qb bf16 + q0s fp32 (head-0 selection)
//  7  lnpack      : LN(Yk) -> Kb + k0s
//  8  lnpack      : Yv -> Vb (cast only)
//  9  s_kernel    : S[b,n,m] = relu(q0s.k0s/8), causal/diag/col0-zeroed
// 10  p_kernel    : column partial sums of S rows 0..1023 (8 chunks)
// 11  evict       : ROUND-3 REWRITE of the reduction. Round-1 made it a
//                   single wave (no barriers/LDS) but kept the 64-bit
//                   __shfl_xor butterfly: 12 dependent ds_bpermute/iter at
//                   ~130 cyc each = ~84% of the 1850 cyc/iter observed.
//                   Now: two-phase argmax with DPP (VALU-latency) reduction:
//                     phase 1: fmax tree + DPP max (ror1/2/4/8 +
//                              row_bcast15[0xA] + row_bcast31[0xC]) ->
//                              lane 63 -> readlane -> M* (SGPR)
//                     phase 2: per-slot (cum==M* ? c*256+e : BIG) + u32-min
//                              tree + same DPP min -> smallest m among
//                              maxima (== i64-pack lexicographic argmax,
//                              == jnp.argmax first-max; bit-identical
//                              eviction schedule)
//                   Poison via scalar-guided branch on uniform mstar.
//                   S rows stay double-banked/prefetched one iter ahead.
// 12  flash       : all 16 heads, online softmax, mask = causal && n<evt[m]
// 13  gemm        : out = Ob @ Wo -> d_out fp32
//
// ws overlays: Ob reuses Xhi slot (dead after step 5); S reuses Yq+Yk slots
// (dead after steps 6/7). Peak ws ~107.1 MB.

#include <hip/hip_runtime.h>

#define B_    2
#define N_    2048
#define D_    1024
#define H_    16
#define DH_   64
#define M_    2048
#define ROWS_ 4096
#define BUD_  1024

typedef unsigned short u16;
typedef unsigned int   u32;
typedef unsigned long long u64;
typedef __attribute__((ext_vector_type(8))) short short8;
typedef __attribute__((ext_vector_type(4))) float floatx4;

__device__ __forceinline__ u16 f2b(float f) {
    u32 u = __float_as_uint(f);
    return (u16)((u + 0x7FFFu + ((u >> 16) & 1u)) >> 16);   // RNE
}
__device__ __forceinline__ float b2f(u16 h) {
    return __uint_as_float(((u32)h) << 16);
}

// ---------------------------------------------------------------- cast X
__global__ __launch_bounds__(256) void cast_x_kernel(
    const float* __restrict__ X, u16* __restrict__ Xhi, u16* __restrict__ Xlo)
{
    int idx = (blockIdx.x * 256 + threadIdx.x) * 4;
    float4 v = *(const float4*)&X[idx];
    u16 h0 = f2b(v.x), h1 = f2b(v.y), h2 = f2b(v.z), h3 = f2b(v.w);
    ushort4 hv; hv.x = h0; hv.y = h1; hv.z = h2; hv.w = h3;
    *(ushort4*)&Xhi[idx] = hv;
    ushort4 lv;
    lv.x = f2b(v.x - b2f(h0)); lv.y = f2b(v.y - b2f(h1));
    lv.z = f2b(v.z - b2f(h2)); lv.w = f2b(v.w - b2f(h3));
    *(ushort4*)&Xlo[idx] = lv;
}

// ------------------------------------------------- cast + transpose W
__global__ __launch_bounds__(1024) void cast_w_kernel(
    const float* __restrict__ W, u16* __restrict__ Whi, u16* __restrict__ Wlo,
    int do_lo)
{
    __shared__ float tile[32][33];
    int tx = threadIdx.x, ty = threadIdx.y;
    int x = blockIdx.x * 32 + tx, y = blockIdx.y * 32 + ty;
    tile[ty][tx] = W[(size_t)y * D_ + x];
    __syncthreads();
    float v = tile[tx][ty];
    int n = blockIdx.x * 32 + ty, k = blockIdx.y * 32 + tx;
    u16 h = f2b(v);
    Whi[(size_t)n * D_ + k] = h;
    if (do_lo) Wlo[(size_t)n * D_ + k] = f2b(v - b2f(h));
}

// ------------------------------------------------------------- GEMM
// C[4096][1024] = A[4096][1024] @ Bt^T   (Bt stored [n][k])
// mode 1: C = Ah*Bh + Ah*Bl + Al*Bh  (bf16x3 split, ~fp32 precision)
__global__ __launch_bounds__(256) void gemm_kernel(
    const u16* __restrict__ Ah, const u16* __restrict__ Al,
    const u16* __restrict__ Bh, const u16* __restrict__ Bl,
    int mode, float* __restrict__ C)
{
    __shared__ __align__(16) u16 sAh[128 * 32];
    __shared__ __align__(16) u16 sBh[128 * 32];
    __shared__ __align__(16) u16 sAl[128 * 32];
    __shared__ __align__(16) u16 sBl[128 * 32];
    int tid = threadIdx.x;
    int lane = tid & 63, wv = tid >> 6;
    int wr = wv >> 1, wc = wv & 1;
    int quad = lane >> 4, l16 = lane & 15;
    int m0 = blockIdx.y * 128, n0 = blockIdx.x * 128;

    floatx4 acc[4][4];
    floatx4 zero = {0.f, 0.f, 0.f, 0.f};
#pragma unroll
    for (int i = 0; i < 4; ++i)
#pragma unroll
        for (int j = 0; j < 4; ++j) acc[i][j] = zero;

    for (int k0 = 0; k0 < 1024; k0 += 32) {
#pragma unroll
        for (int it = 0; it < 2; ++it) {
            int e = (tid + it * 256) * 8;
            int r = e >> 5, c = e & 31;
            *(uint4*)&sAh[e] = *(const uint4*)&Ah[(size_t)(m0 + r) * 1024 + k0 + c];
            *(uint4*)&sBh[e] = *(const uint4*)&Bh[(size_t)(n0 + r) * 1024 + k0 + c];
            if (mode) {
                *(uint4*)&sAl[e] = *(const uint4*)&Al[(size_t)(m0 + r) * 1024 + k0 + c];
                *(uint4*)&sBl[e] = *(const uint4*)&Bl[(size_t)(n0 + r) * 1024 + k0 + c];
            }
        }
        __syncthreads();
        short8 ah[4], al[4], bh[4], bl[4];
#pragma unroll
        for (int x = 0; x < 4; ++x) {
            int ra = (wr * 64 + x * 16 + l16) * 32 + quad * 8;
            int rb = (wc * 64 + x * 16 + l16) * 32 + quad * 8;
            ah[x] = *(const short8*)&sAh[ra];
            bh[x] = *(const short8*)&sBh[rb];
            if (mode) {
                al[x] = *(const short8*)&sAl[ra];
                bl[x] = *(const short8*)&sBl[rb];
            }
        }
#pragma unroll
        for (int mi = 0; mi < 4; ++mi)
#pragma unroll
            for (int ni = 0; ni < 4; ++ni) {
                acc[mi][ni] = __builtin_amdgcn_mfma_f32_16x16x32_bf16(
                    ah[mi], bh[ni], acc[mi][ni], 0, 0, 0);
                if (mode) {
                    acc[mi][ni] = __builtin_amdgcn_mfma_f32_16x16x32_bf16(
                        ah[mi], bl[ni], acc[mi][ni], 0, 0, 0);
                    acc[mi][ni] = __builtin_amdgcn_mfma_f32_16x16x32_bf16(
                        al[mi], bh[ni], acc[mi][ni], 0, 0, 0);
                }
            }
        __syncthreads();
    }
    // C/D layout: col = lane&15, row = (lane>>4)*4 + reg   [verified m89/m91]
#pragma unroll
    for (int mi = 0; mi < 4; ++mi)
#pragma unroll
        for (int ni = 0; ni < 4; ++ni)
#pragma unroll
            for (int r = 0; r < 4; ++r) {
                int row = m0 + wr * 64 + mi * 16 + quad * 4 + r;
                int col = n0 + wc * 64 + ni * 16 + l16;
                C[(size_t)row * 1024 + col] = acc[mi][ni][r];
            }
}

// ----------------------------------------------------- LayerNorm + pack
__global__ __launch_bounds__(256) void lnpack_kernel(
    const float* __restrict__ Y, const float* __restrict__ gamma,
    const float* __restrict__ beta, u16* __restrict__ Pk,
    float* __restrict__ head0, int do_ln)
{
    int r = blockIdx.x;
    int tid = threadIdx.x;
    float4 v = *(const float4*)&Y[(size_t)r * D_ + tid * 4];
    float mu = 0.f, rsig = 1.f;
    __shared__ float sS[4], sQ[4];
    if (do_ln) {
        float s = v.x + v.y + v.z + v.w;
        float q = v.x * v.x + v.y * v.y + v.z * v.z + v.w * v.w;
#pragma unroll
        for (int d = 1; d < 64; d <<= 1) { s += __shfl_xor(s, d); q += __shfl_xor(q, d); }
        if ((tid & 63) == 0) { sS[tid >> 6] = s; sQ[tid >> 6] = q; }
        __syncthreads();
        s = sS[0] + sS[1] + sS[2] + sS[3];
        q = sQ[0] + sQ[1] + sQ[2] + sQ[3];
        mu = s * (1.f / 1024.f);
        float var = q * (1.f / 1024.f) - mu * mu;
        rsig = rsqrtf(var + 1e-5f);
    }
    int b = r >> 11, n = r & 2047;
    float xs[4] = {v.x, v.y, v.z, v.w};
#pragma unroll
    for (int j = 0; j < 4; ++j) {
        int c = tid * 4 + j;
        float val = do_ln ? ((xs[j] - mu) * rsig * gamma[c] + beta[c]) : xs[j];
        int h = c >> 6, dh = c & 63;
        Pk[(((size_t)b * H_ + h) * N_ + n) * DH_ + dh] = f2b(val);
        if (head0 && c < 64) head0[(size_t)r * 64 + c] = val;
    }
}

// -------------------------------------------- head-0 selection scores S
__global__ void s_kernel(const float* __restrict__ q0,
                         const float* __restrict__ k0, float* __restrict__ S)
{
    int b = blockIdx.z;
    int n0 = blockIdx.y * 16, m0 = blockIdx.x * 16;
    int tx = threadIdx.x, ty = threadIdx.y;
    int n = n0 + ty, m = m0 + tx;
    float* out = S + ((size_t)b * N_ + n) * M_ + m;
    if (m0 > n0 + 15) { *out = 0.f; return; }   // fully above diagonal
    __shared__ float sq[16][65], sk[16][65];
    int tid = ty * 16 + tx;
    {
        int rr = tid >> 4, cc = (tid & 15) * 4;
        float4 qa = *(const float4*)&q0[((size_t)b * N_ + n0 + rr) * 64 + cc];
        sq[rr][cc] = qa.x; sq[rr][cc + 1] = qa.y; sq[rr][cc + 2] = qa.z; sq[rr][cc + 3] = qa.w;
        float4 ka = *(const float4*)&k0[((size_t)b * N_ + m0 + rr) * 64 + cc];
        sk[rr][cc] = ka.x; sk[rr][cc + 1] = ka.y; sk[rr][cc + 2] = ka.z; sk[rr][cc + 3] = ka.w;
    }
    __syncthreads();
    float acc = 0.f;
#pragma unroll 8
    for (int d = 0; d < 64; ++d) acc += sq[ty][d] * sk[tx][d];
    // causal (m>n) -> relu(-inf)=0 ; diagonal m==n -> 0 ; col 0 -> 0
    float val;
    if (m < n && m != 0) val = fmaxf(acc * 0.125f, 0.f); else val = 0.f;
    *out = val;
}

// -------------------------------- partial column sums of S rows 0..1023
__global__ __launch_bounds__(256) void p_kernel(const float* __restrict__ S,
                                                float* __restrict__ P)
{
    int b = blockIdx.z, c = blockIdx.y;
    int m = blockIdx.x * 256 + threadIdx.x;
    const float* base = S + ((size_t)b * N_ + c * 128) * M_ + m;
    float s = 0.f;
    for (int j = 0; j < 128; ++j) s += base[(size_t)j * M_];
    P[((size_t)b * 8 + c) * M_ + m] = s;
}

// --------------------------------------------- sequential greedy eviction
// Single wave (64 lanes) per batch. Lane t owns slots m = c*256 + 4t + e
// (c chunk 0..7, e 0..3), values in cum[8][4] registers.
//   - evicted slot -> cum = -inf (stays -inf: adds are nonneg/-inf)
//   - argmax in two phases, each reduced with DPP (VALU latency, no LDS):
//       phase 1: M* = max value  (fmax tree + 6 DPP-max stages + readlane63)
//       phase 2: m* = min m among {cum == M*, active}  (select + umin tree +
//                6 DPP-min stages + readlane63)
//     Equivalent to lexicographic (value, -m) argmax == jnp.argmax first-max.
//   - chunk activity: chunks 0..NC-1 full, chunk NC partial (m<=i), >NC
//     excluded from argmax but still accumulated. NC = i>>8 via 4 template
//     instantiations (compile-time chunk classification).
//   - S rows double-banked in registers, prefetched one iteration ahead.
//   - poison via scalar-guided branch on uniform mstar (readlane -> SGPR).

__device__ __forceinline__ u32 umin2(u32 a, u32 b) { return a < b ? a : b; }

// DPP-combine helpers: old = v so lanes outside row_mask keep their value.
template<int CTRL, int RMASK>
__device__ __forceinline__ float dpp_maxf(float v) {
    int iv = __float_as_int(v);
    int t = __builtin_amdgcn_update_dpp(iv, iv, CTRL, RMASK, 0xF, false);
    return fmaxf(v, __int_as_float(t));
}
template<int CTRL, int RMASK>
__device__ __forceinline__ u32 dpp_minu(u32 v) {
    int iv = (int)v;
    int t = __builtin_amdgcn_update_dpp(iv, iv, CTRL, RMASK, 0xF, false);
    return umin2(v, (u32)t);
}

// Wave64 reduction: ror 1/2/4/8 (row-reduce, all lanes) then
// row_bcast15 (rows 1,3) + row_bcast31 (rows 2,3) -> lane 63 has result.
__device__ __forceinline__ float wave_max_to63(float v) {
    v = dpp_maxf<0x121, 0xF>(v);   // row_ror:1
    v = dpp_maxf<0x122, 0xF>(v);   // row_ror:2
    v = dpp_maxf<0x124, 0xF>(v);   // row_ror:4
    v = dpp_maxf<0x128, 0xF>(v);   // row_ror:8
    v = dpp_maxf<0x142, 0xA>(v);   // row_bcast15 -> rows 1,3
    v = dpp_maxf<0x143, 0xC>(v);   // row_bcast31 -> rows 2,3
    return v;
}
__device__ __forceinline__ u32 wave_min_to63(u32 v) {
    v = dpp_minu<0x121, 0xF>(v);
    v = dpp_minu<0x122, 0xF>(v);
    v = dpp_minu<0x124, 0xF>(v);
    v = dpp_minu<0x128, 0xF>(v);
    v = dpp_minu<0x142, 0xA>(v);
    v = dpp_minu<0x143, 0xC>(v);
    return v;
}

template<int NC>
__device__ __forceinline__ void evict_step(
    int i, int t, float (&cum)[8][4], const float4 (&rr)[8],
    int* __restrict__ evtb)
{
    const float NEGINF = __uint_as_float(0xFF800000u);
    const int m0 = 4 * t;
    const int relm = (i & 255) - m0;     // chunk NC: slot e active iff e <= relm

    // ---- phase 1: global max value
    float tc[NC + 1];
#pragma unroll
    for (int c = 0; c <= NC; ++c) {
        float x0 = cum[c][0], x1 = cum[c][1], x2 = cum[c][2], x3 = cum[c][3];
        if (c == NC) {
            x0 = (relm >= 0) ? x0 : NEGINF;
            x1 = (relm >= 1) ? x1 : NEGINF;
            x2 = (relm >= 2) ? x2 : NEGINF;
            x3 = (relm >= 3) ? x3 : NEGINF;
        }
        tc[c] = fmaxf(fmaxf(x0, x1), fmaxf(x2, x3));
    }
    float mx = fmaxf(fmaxf(tc[0], tc[1]), fmaxf(tc[2], tc[3]));
#pragma unroll
    for (int c = 4; c <= NC; ++c) mx = fmaxf(mx, tc[c]);
    mx = wave_max_to63(mx);
    const float Ms = __int_as_float(
        __builtin_amdgcn_readlane(__float_as_int(mx), 63));

    // ---- phase 2: min m among {cum == Ms, active}
    const u32 BIGC = 0x3FFFFFFFu;
    u32 tm[NC + 1];
#pragma unroll
    for (int c = 0; c <= NC; ++c) {
        u32 k0 = (cum[c][0] == Ms) ? (u32)(c * 256 + 0) : BIGC;
        u32 k1 = (cum[c][1] == Ms) ? (u32)(c * 256 + 1) : BIGC;
        u32 k2 = (cum[c][2] == Ms) ? (u32)(c * 256 + 2) : BIGC;
        u32 k3 = (cum[c][3] == Ms) ? (u32)(c * 256 + 3) : BIGC;
        if (c == NC) {
            k0 = (relm >= 0) ? k0 : BIGC;
            k1 = (relm >= 1) ? k1 : BIGC;
            k2 = (relm >= 2) ? k2 : BIGC;
            k3 = (relm >= 3) ? k3 : BIGC;
        }
        tm[c] = umin2(umin2(k0, k1), umin2(k2, k3));
    }
    u32 mn = umin2(umin2(tm[0], tm[1]), umin2(tm[2], tm[3]));
#pragma unroll
    for (int c = 4; c <= NC; ++c) mn = umin2(mn, tm[c]);
    mn += (u32)m0;                        // m = (c*256+e) + 4t; BIGC stays big
    mn = wave_min_to63(mn);
    const int mstar = __builtin_amdgcn_readlane((int)mn, 63);
    if (t == 0) evtb[mstar] = i;

    // ---- update: Fm[i] -> Fm[i+1]
#pragma unroll
    for (int c = 0; c < 8; ++c) {
        cum[c][0] += rr[c].x; cum[c][1] += rr[c].y;
        cum[c][2] += rr[c].z; cum[c][3] += rr[c].w;
    }
    // ---- poison evicted slot (mstar uniform: scalar-guided selection)
    const int sc = mstar >> 8, se = mstar & 3;
    const bool own = (((mstar >> 2) & 63) == t);
#pragma unroll
    for (int c = 0; c <= NC; ++c)
        if (sc == c) {
#pragma unroll
            for (int e = 0; e < 4; ++e)
                if (se == e) cum[c][e] = own ? NEGINF : cum[c][e];
        }
}

template<int NC>
__device__ __forceinline__ void evict_seg(
    int t, float (&cum)[8][4], float4 (&bankA)[8], float4 (&bankB)[8],
    const float* __restrict__ Sb, int* __restrict__ evtb)
{
    const int m0 = 4 * t;
#pragma unroll 1
    for (int ip = NC * 256; ip < NC * 256 + 256; ip += 2) {
        // prefetch row ip+1 (consumed at end of second step this trip)
#pragma unroll
        for (int c = 0; c < 8; ++c)
            bankB[c] = *(const float4*)&Sb[(size_t)(ip + 1) * M_ + c * 256 + m0];
        evict_step<NC>(ip, t, cum, bankA, evtb);
        if (ip + 2 < 2048) {
            // prefetch row ip+2 (consumed at end of next trip's first step)
#pragma unroll
            for (int c = 0; c < 8; ++c)
                bankA[c] = *(const float4*)&Sb[(size_t)(ip + 2) * M_ + c * 256 + m0];
        }
        evict_step<NC>(ip + 1, t, cum, bankB, evtb);
    }
}

__global__ __launch_bounds__(64) void evict_kernel(
    const float* __restrict__ S, const float* __restrict__ P,
    int* __restrict__ evt)
{
    int b = blockIdx.x, t = threadIdx.x;       // 64 threads = 1 wave
    const float* Sb = S + (size_t)b * N_ * M_;
    int* evtb = evt + b * M_;
    // initial cum = column sums of the 8 partial chunks (same add order as
    // round 0 -> bitwise identical trajectories -> identical argmax results)
    float cum[8][4];
#pragma unroll
    for (int c = 0; c < 8; ++c) {
        float ax = 0.f, ay = 0.f, az = 0.f, aw = 0.f;
#pragma unroll
        for (int cc = 0; cc < 8; ++cc) {
            float4 pv = *(const float4*)&P[((size_t)b * 8 + cc) * M_ + c * 256 + 4 * t];
            ax += pv.x; ay += pv.y; az += pv.z; aw += pv.w;
        }
        cum[c][0] = ax; cum[c][1] = ay; cum[c][2] = az; cum[c][3] = aw;
    }
#pragma unroll
    for (int c = 0; c < 8; ++c) {
        int4 big = {0x3FFFFFFF, 0x3FFFFFFF, 0x3FFFFFFF, 0x3FFFFFFF};
        *(int4*)&evtb[c * 256 + 4 * t] = big;
    }
    float4 bankA[8], bankB[8];
#pragma unroll
    for (int c = 0; c < 8; ++c)
        bankA[c] = *(const float4*)&Sb[(size_t)1024 * M_ + c * 256 + 4 * t];
    evict_seg<4>(t, cum, bankA, bankB, Sb, evtb);
    evict_seg<5>(t, cum, bankA, bankB, Sb, evtb);
    evict_seg<6>(t, cum, bankA, bankB, Sb, evtb);
    evict_seg<7>(t, cum, bankA, bankB, Sb, evtb);
}

// ------------------------------------------------------ flash attention
__global__ __launch_bounds__(256) void flash_kernel(
    const u16* __restrict__ Qb, const u16* __restrict__ Kb,
    const u16* __restrict__ Vb, const int* __restrict__ evt,
    u16* __restrict__ Ob)
{
    int bh = blockIdx.y;
    int b = bh >> 4, h = bh & 15;
    int q0 = blockIdx.x * 64;
    int tid = threadIdx.x, lane = tid & 63, w = tid >> 6;
    int quad = lane >> 4, l16 = lane & 15;
    const u16* Qh = Qb + (size_t)bh * N_ * DH_;
    const u16* Kh = Kb + (size_t)bh * N_ * DH_;
    const u16* Vh = Vb + (size_t)bh * N_ * DH_;
    __shared__ __align__(16) u16 sK[64 * 64];
    __shared__ __align__(16) u16 sV[64 * 64];     // transposed [dh][key]
    __shared__ __align__(16) u16 sP[4][16 * 64];  // wave-private P
    __shared__ int sevt[64];

    // Q A-frags in registers: A[m=lane&15][k=quad*8+j]
    short8 aq0 = *(const short8*)&Qh[(size_t)(q0 + w * 16 + l16) * 64 + quad * 8];
    short8 aq1 = *(const short8*)&Qh[(size_t)(q0 + w * 16 + l16) * 64 + quad * 8 + 32];

    floatx4 zero = {0.f, 0.f, 0.f, 0.f};
    floatx4 accO[4];
#pragma unroll
    for (int d = 0; d < 4; ++d) accO[d] = zero;
    float m_i[4] = {-1e30f, -1e30f, -1e30f, -1e30f};
    float l_i[4] = {0.f, 0.f, 0.f, 0.f};

    int ktiles = blockIdx.x + 1;
    for (int kt = 0; kt < ktiles; ++kt) {
        int k0 = kt * 64;
#pragma unroll
        for (int it = 0; it < 2; ++it) {
            int e = (tid + it * 256) * 8;
            int r = e >> 6, c = e & 63;
            *(uint4*)&sK[e] = *(const uint4*)&Kh[(size_t)(k0 + r) * 64 + c];
            uint4 vv = *(const uint4*)&Vh[(size_t)(k0 + r) * 64 + c];
            sV[(c + 0) * 64 + r] = (u16)(vv.x & 0xFFFF);
            sV[(c + 1) * 64 + r] = (u16)(vv.x >> 16);
            sV[(c + 2) * 64 + r] = (u16)(vv.y & 0xFFFF);
            sV[(c + 3) * 64 + r] = (u16)(vv.y >> 16);
            sV[(c + 4) * 64 + r] = (u16)(vv.z & 0xFFFF);
            sV[(c + 5) * 64 + r] = (u16)(vv.z >> 16);
            sV[(c + 6) * 64 + r] = (u16)(vv.w & 0xFFFF);
            sV[(c + 7) * 64 + r] = (u16)(vv.w >> 16);
        }
        if (tid < 64) sevt[tid] = evt[b * M_ + k0 + tid];
        __syncthreads();

        floatx4 lg[4];
        int nbase = q0 + w * 16 + quad * 4;
#pragma unroll
        for (int s = 0; s < 4; ++s) {
            floatx4 sc = zero;
            short8 bk0 = *(const short8*)&sK[(s * 16 + l16) * 64 + quad * 8];
            short8 bk1 = *(const short8*)&sK[(s * 16 + l16) * 64 + quad * 8 + 32];
            sc = __builtin_amdgcn_mfma_f32_16x16x32_bf16(aq0, bk0, sc, 0, 0, 0);
            sc = __builtin_amdgcn_mfma_f32_16x16x32_bf16(aq1, bk1, sc, 0, 0, 0);
            int m = k0 + s * 16 + l16;
            int ev = sevt[s * 16 + l16];
#pragma unroll
            for (int r = 0; r < 4; ++r) {
                int n = nbase + r;
                bool keep = (m <= n) && (n < ev);
                lg[s][r] = keep ? sc[r] * 0.125f : -1e30f;
            }
        }
        float mnew[4], scale[4], rs[4];
#pragma unroll
        for (int r = 0; r < 4; ++r) {
            float mx = fmaxf(fmaxf(lg[0][r], lg[1][r]), fmaxf(lg[2][r], lg[3][r]));
#pragma unroll
            for (int d = 1; d < 16; d <<= 1) mx = fmaxf(mx, __shfl_xor(mx, d));
            mnew[r] = fmaxf(m_i[r], mx);
            scale[r] = __expf(m_i[r] - mnew[r]);
            m_i[r] = mnew[r];
            rs[r] = 0.f;
        }
#pragma unroll
        for (int s = 0; s < 4; ++s)
#pragma unroll
            for (int r = 0; r < 4; ++r) {
                float p = __expf(lg[s][r] - mnew[r]);
                rs[r] += p;
                sP[w][(quad * 4 + r) * 64 + s * 16 + l16] = f2b(p);
            }
#pragma unroll
        for (int r = 0; r < 4; ++r) {
            float t_ = rs[r];
#pragma unroll
            for (int d = 1; d < 16; d <<= 1) t_ += __shfl_xor(t_, d);
            l_i[r] = l_i[r] * scale[r] + t_;
        }
#pragma unroll
        for (int dd = 0; dd < 4; ++dd) {
            accO[dd][0] *= scale[0]; accO[dd][1] *= scale[1];
            accO[dd][2] *= scale[2]; accO[dd][3] *= scale[3];
        }
        // P: C-layout -> A-layout via wave-private LDS round-trip
        short8 ap0 = *(const short8*)&sP[w][l16 * 64 + quad * 8];
        short8 ap1 = *(const short8*)&sP[w][l16 * 64 + quad * 8 + 32];
#pragma unroll
        for (int dd = 0; dd < 4; ++dd) {
            short8 bv0 = *(const short8*)&sV[(dd * 16 + l16) * 64 + quad * 8];
            short8 bv1 = *(const short8*)&sV[(dd * 16 + l16) * 64 + quad * 8 + 32];
            accO[dd] = __builtin_amdgcn_mfma_f32_16x16x32_bf16(ap0, bv0, accO[dd], 0, 0, 0);
            accO[dd] = __builtin_amdgcn_mfma_f32_16x16x32_bf16(ap1, bv1, accO[dd], 0, 0, 0);
        }
        __syncthreads();
    }
#pragma unroll
    for (int dd = 0; dd < 4; ++dd)
#pragma unroll
        for (int r = 0; r < 4; ++r) {
            int n = q0 + w * 16 + quad * 4 + r;
            int col = h * 64 + dd * 16 + l16;
            Ob[((size_t)b * N_ + n) * D_ + col] = f2b(accO[dd][r] / l_i[r]);
        }
}

// ---------------------------------------------------------------- launch
extern "C" void kernel_launch(void* const* d_in, const int* in_sizes, int n_in,
                              void* d_out, int out_size, void* d_ws, size_t ws_size,
                              hipStream_t stream)
{
    (void)in_sizes; (void)n_in; (void)out_size; (void)ws_size;
    const float* X  = (const float*)d_in[0];
    const float* Wq = (const float*)d_in[1];
    const float* Wk = (const float*)d_in[2];
    const float* Wv = (const float*)d_in[3];
    const float* Wo = (const float*)d_in[4];
    const float* gq = (const float*)d_in[5];
    const float* bq = (const float*)d_in[6];
    const float* gk = (const float*)d_in[7];
    const float* bk = (const float*)d_in[8];
    // d_in[9] cache_k, d_in[10] cache_v, d_in[11] start_pos: start_pos==0 here.

    char* p = (char*)d_ws;
    const size_t SZ_XH = (size_t)ROWS_ * D_ * 2;   // 8 MiB bf16
    const size_t SZ_W  = (size_t)D_ * D_ * 2;      // 2 MiB bf16
    const size_t SZ_Y  = (size_t)ROWS_ * D_ * 4;   // 16 MiB fp32
    const size_t SZ_PK = (size_t)ROWS_ * D_ * 2;   // 8 MiB bf16
    const size_t SZ_H0 = (size_t)ROWS_ * 64 * 4;   // 1 MiB fp32

    size_t o = 0;
    u16* Xhi = (u16*)(p + o); o += SZ_XH;
    u16* Xlo = (u16*)(p + o); o += SZ_XH;
    u16* Wqh = (u16*)(p + o); o += SZ_W;
    u16* Wql = (u16*)(p + o); o += SZ_W;
    u16* Wkh = (u16*)(p + o); o += SZ_W;
    u16* Wkl = (u16*)(p + o); o += SZ_W;
    u16* Wvh = (u16*)(p + o); o += SZ_W;
    u16* Woh = (u16*)(p + o); o += SZ_W;
    float* Yq = (float*)(p + o); size_t oYq = o; o += SZ_Y;
    float* Yk = (float*)(p + o); o += SZ_Y;
    float* Yv = (float*)(p + o); o += SZ_Y;
    u16* Qb = (u16*)(p + o); o += SZ_PK;
    u16* Kb = (u16*)(p + o); o += SZ_PK;
    u16* Vb = (u16*)(p + o); o += SZ_PK;
    float* q0s = (float*)(p + o); o += SZ_H0;
    float* k0s = (float*)(p + o); o += SZ_H0;
    float* Pp  = (float*)(p + o); o += (size_t)B_ * 8 * M_ * 4;
    int* evt   = (int*)(p + o);  o += (size_t)B_ * M_ * 4;
    // overlays (dead slots):
    float* S = (float*)(p + oYq);   // 32 MiB over Yq+Yk, used after LN
    u16* Ob  = Xhi;                 // 8 MiB over Xhi, used after all X-GEMMs

    cast_x_kernel<<<ROWS_ * D_ / (256 * 4), 256, 0, stream>>>(X, Xhi, Xlo);
    dim3 wgrid(32, 32), wblk(32, 32);
    cast_w_kernel<<<wgrid, wblk, 0, stream>>>(Wq, Wqh, Wql, 1);
    cast_w_kernel<<<wgrid, wblk, 0, stream>>>(Wk, Wkh, Wkl, 1);
    cast_w_kernel<<<wgrid, wblk, 0, stream>>>(Wv, Wvh, nullptr, 0);
    cast_w_kernel<<<wgrid, wblk, 0, stream>>>(Wo, Woh, nullptr, 0);

    dim3 ggrid(D_ / 128, ROWS_ / 128);
    gemm_kernel<<<ggrid, 256, 0, stream>>>(Xhi, Xlo, Wqh, Wql, 1, Yq);
    gemm_kernel<<<ggrid, 256, 0, stream>>>(Xhi, Xlo, Wkh, Wkl, 1, Yk);
    gemm_kernel<<<ggrid, 256, 0, stream>>>(Xhi, nullptr, Wvh, nullptr, 0, Yv);

    lnpack_kernel<<<ROWS_, 256, 0, stream>>>(Yq, gq, bq, Qb, q0s, 1);
    lnpack_kernel<<<ROWS_, 256, 0, stream>>>(Yk, gk, bk, Kb, k0s, 1);
    lnpack_kernel<<<ROWS_, 256, 0, stream>>>(Yv, nullptr, nullptr, Vb, nullptr, 0);

    s_kernel<<<dim3(M_ / 16, N_ / 16, B_), dim3(16, 16), 0, stream>>>(q0s, k0s, S);
    p_kernel<<<dim3(M_ / 256, 8, B_), 256, 0, stream>>>(S, Pp);
    evict_kernel<<<B_, 64, 0, stream>>>(S, Pp, evt);

    flash_kernel<<<dim3(N_ / 64, B_ * H_), 256, 0, stream>>>(Qb, Kb, Vb, evt, Ob);
    gemm_kernel<<<ggrid, 256, 0, stream>>>(Ob, nullptr, Woh, nullptr, 0, (float*)d_out);
}

// Round 5
// 1220.497 us; speedup vs baseline: 1.1401x; 1.0547x over previous
//
// MultiheadSelectiveAttentionWithTokenPruning — MI355X round 4
//
// Pipeline (all on `stream`, graph-capture safe, no statics):
//  1  cast_x      : X fp32 -> Xhi/Xlo bf16 (split for bf16x3 GEMM)
//  2  cast_w x4   : W fp32 -> W^T bf16 (hi[+lo for Wq/Wk])
//  3  gemm split  : Yq = X@Wq  (hi*hi + hi*lo + lo*hi)  ~fp32 accuracy
//  4  gemm split  : Yk = X@Wk
//  5  gemm        : Yv = X@Wv  (plain bf16)
//  6  lnpack      : LN(Yq) -> Qb bf16 + q0s fp32 (head-0 selection)
//  7  lnpack      : LN(Yk) -> Kb + k0s
//  8  lnpack      : Yv -> Vb (cast only)
//  9  s_kernel    : S[b,n,m] = relu(q0s.k0s/8), causal/diag/col0-zeroed
// 10  p_kernel    : column partial sums of S rows 0..1023 (8 chunks)
// 11  evict       : ROUND-4: FUSED (value,index) tournament argmax.
//                   Round 3's two-phase scheme serialized two reduce chains
//                   + two readlane hazards (wave ~48% issue / ~52% dep-stall).
//                   Now ONE tree: per-lane 31 combines carrying (v, lo=2048-m)
//                   with strict > and static ascending-index operand order
//                   (tie keeps first operand = smaller m == jnp.argmax
//                   first-max). Cross-lane: 6 DPP stages (same ctrl/masks
//                   validated in round 3) on the {v-bits, lo} pack with
//                   v_cmp_gt_i64 (-inf hi is negative -> always loses;
//                   winner always has v >= 0). ONE readlane.
//                   Prefetch deepened to 4 banks (rows +4..+7 in flight,
//                   ~3 iters of cover > ~900 cyc HBM latency).
//                   Bit-identical add order + argmax semantics -> identical
//                   eviction schedule vs rounds 0-3.
// 12  flash       : all 16 heads, online softmax, mask = causal && n<evt[m]
// 13  gemm        : out = Ob @ Wo -> d_out fp32
//
// ws overlays: Ob reuses Xhi slot (dead after step 5); S reuses Yq+Yk slots
// (dead after steps 6/7). Peak ws ~107.1 MB.

#include <hip/hip_runtime.h>

#define B_    2
#define N_    2048
#define D_    1024
#define H_    16
#define DH_   64
#define M_    2048
#define ROWS_ 4096
#define BUD_  1024

typedef unsigned short u16;
typedef unsigned int   u32;
typedef unsigned long long u64;
typedef __attribute__((ext_vector_type(8))) short short8;
typedef __attribute__((ext_vector_type(4))) float floatx4;

__device__ __forceinline__ u16 f2b(float f) {
    u32 u = __float_as_uint(f);
    return (u16)((u + 0x7FFFu + ((u >> 16) & 1u)) >> 16);   // RNE
}
__device__ __forceinline__ float b2f(u16 h) {
    return __uint_as_float(((u32)h) << 16);
}

// ---------------------------------------------------------------- cast X
__global__ __launch_bounds__(256) void cast_x_kernel(
    const float* __restrict__ X, u16* __restrict__ Xhi, u16* __restrict__ Xlo)
{
    int idx = (blockIdx.x * 256 + threadIdx.x) * 4;
    float4 v = *(const float4*)&X[idx];
    u16 h0 = f2b(v.x), h1 = f2b(v.y), h2 = f2b(v.z), h3 = f2b(v.w);
    ushort4 hv; hv.x = h0; hv.y = h1; hv.z = h2; hv.w = h3;
    *(ushort4*)&Xhi[idx] = hv;
    ushort4 lv;
    lv.x = f2b(v.x - b2f(h0)); lv.y = f2b(v.y - b2f(h1));
    lv.z = f2b(v.z - b2f(h2)); lv.w = f2b(v.w - b2f(h3));
    *(ushort4*)&Xlo[idx] = lv;
}

// ------------------------------------------------- cast + transpose W
__global__ __launch_bounds__(1024) void cast_w_kernel(
    const float* __restrict__ W, u16* __restrict__ Whi, u16* __restrict__ Wlo,
    int do_lo)
{
    __shared__ float tile[32][33];
    int tx = threadIdx.x, ty = threadIdx.y;
    int x = blockIdx.x * 32 + tx, y = blockIdx.y * 32 + ty;
    tile[ty][tx] = W[(size_t)y * D_ + x];
    __syncthreads();
    float v = tile[tx][ty];
    int n = blockIdx.x * 32 + ty, k = blockIdx.y * 32 + tx;
    u16 h = f2b(v);
    Whi[(size_t)n * D_ + k] = h;
    if (do_lo) Wlo[(size_t)n * D_ + k] = f2b(v - b2f(h));
}

// ------------------------------------------------------------- GEMM
// C[4096][1024] = A[4096][1024] @ Bt^T   (Bt stored [n][k])
// mode 1: C = Ah*Bh + Ah*Bl + Al*Bh  (bf16x3 split, ~fp32 precision)
__global__ __launch_bounds__(256) void gemm_kernel(
    const u16* __restrict__ Ah, const u16* __restrict__ Al,
    const u16* __restrict__ Bh, const u16* __restrict__ Bl,
    int mode, float* __restrict__ C)
{
    __shared__ __align__(16) u16 sAh[128 * 32];
    __shared__ __align__(16) u16 sBh[128 * 32];
    __shared__ __align__(16) u16 sAl[128 * 32];
    __shared__ __align__(16) u16 sBl[128 * 32];
    int tid = threadIdx.x;
    int lane = tid & 63, wv = tid >> 6;
    int wr = wv >> 1, wc = wv & 1;
    int quad = lane >> 4, l16 = lane & 15;
    int m0 = blockIdx.y * 128, n0 = blockIdx.x * 128;

    floatx4 acc[4][4];
    floatx4 zero = {0.f, 0.f, 0.f, 0.f};
#pragma unroll
    for (int i = 0; i < 4; ++i)
#pragma unroll
        for (int j = 0; j < 4; ++j) acc[i][j] = zero;

    for (int k0 = 0; k0 < 1024; k0 += 32) {
#pragma unroll
        for (int it = 0; it < 2; ++it) {
            int e = (tid + it * 256) * 8;
            int r = e >> 5, c = e & 31;
            *(uint4*)&sAh[e] = *(const uint4*)&Ah[(size_t)(m0 + r) * 1024 + k0 + c];
            *(uint4*)&sBh[e] = *(const uint4*)&Bh[(size_t)(n0 + r) * 1024 + k0 + c];
            if (mode) {
                *(uint4*)&sAl[e] = *(const uint4*)&Al[(size_t)(m0 + r) * 1024 + k0 + c];
                *(uint4*)&sBl[e] = *(const uint4*)&Bl[(size_t)(n0 + r) * 1024 + k0 + c];
            }
        }
        __syncthreads();
        short8 ah[4], al[4], bh[4], bl[4];
#pragma unroll
        for (int x = 0; x < 4; ++x) {
            int ra = (wr * 64 + x * 16 + l16) * 32 + quad * 8;
            int rb = (wc * 64 + x * 16 + l16) * 32 + quad * 8;
            ah[x] = *(const short8*)&sAh[ra];
            bh[x] = *(const short8*)&sBh[rb];
            if (mode) {
                al[x] = *(const short8*)&sAl[ra];
                bl[x] = *(const short8*)&sBl[rb];
            }
        }
#pragma unroll
        for (int mi = 0; mi < 4; ++mi)
#pragma unroll
            for (int ni = 0; ni < 4; ++ni) {
                acc[mi][ni] = __builtin_amdgcn_mfma_f32_16x16x32_bf16(
                    ah[mi], bh[ni], acc[mi][ni], 0, 0, 0);
                if (mode) {
                    acc[mi][ni] = __builtin_amdgcn_mfma_f32_16x16x32_bf16(
                        ah[mi], bl[ni], acc[mi][ni], 0, 0, 0);
                    acc[mi][ni] = __builtin_amdgcn_mfma_f32_16x16x32_bf16(
                        al[mi], bh[ni], acc[mi][ni], 0, 0, 0);
                }
            }
        __syncthreads();
    }
    // C/D layout: col = lane&15, row = (lane>>4)*4 + reg   [verified m89/m91]
#pragma unroll
    for (int mi = 0; mi < 4; ++mi)
#pragma unroll
        for (int ni = 0; ni < 4; ++ni)
#pragma unroll
            for (int r = 0; r < 4; ++r) {
                int row = m0 + wr * 64 + mi * 16 + quad * 4 + r;
                int col = n0 + wc * 64 + ni * 16 + l16;
                C[(size_t)row * 1024 + col] = acc[mi][ni][r];
            }
}

// ----------------------------------------------------- LayerNorm + pack
__global__ __launch_bounds__(256) void lnpack_kernel(
    const float* __restrict__ Y, const float* __restrict__ gamma,
    const float* __restrict__ beta, u16* __restrict__ Pk,
    float* __restrict__ head0, int do_ln)
{
    int r = blockIdx.x;
    int tid = threadIdx.x;
    float4 v = *(const float4*)&Y[(size_t)r * D_ + tid * 4];
    float mu = 0.f, rsig = 1.f;
    __shared__ float sS[4], sQ[4];
    if (do_ln) {
        float s = v.x + v.y + v.z + v.w;
        float q = v.x * v.x + v.y * v.y + v.z * v.z + v.w * v.w;
#pragma unroll
        for (int d = 1; d < 64; d <<= 1) { s += __shfl_xor(s, d); q += __shfl_xor(q, d); }
        if ((tid & 63) == 0) { sS[tid >> 6] = s; sQ[tid >> 6] = q; }
        __syncthreads();
        s = sS[0] + sS[1] + sS[2] + sS[3];
        q = sQ[0] + sQ[1] + sQ[2] + sQ[3];
        mu = s * (1.f / 1024.f);
        float var = q * (1.f / 1024.f) - mu * mu;
        rsig = rsqrtf(var + 1e-5f);
    }
    int b = r >> 11, n = r & 2047;
    float xs[4] = {v.x, v.y, v.z, v.w};
#pragma unroll
    for (int j = 0; j < 4; ++j) {
        int c = tid * 4 + j;
        float val = do_ln ? ((xs[j] - mu) * rsig * gamma[c] + beta[c]) : xs[j];
        int h = c >> 6, dh = c & 63;
        Pk[(((size_t)b * H_ + h) * N_ + n) * DH_ + dh] = f2b(val);
        if (head0 && c < 64) head0[(size_t)r * 64 + c] = val;
    }
}

// -------------------------------------------- head-0 selection scores S
__global__ void s_kernel(const float* __restrict__ q0,
                         const float* __restrict__ k0, float* __restrict__ S)
{
    int b = blockIdx.z;
    int n0 = blockIdx.y * 16, m0 = blockIdx.x * 16;
    int tx = threadIdx.x, ty = threadIdx.y;
    int n = n0 + ty, m = m0 + tx;
    float* out = S + ((size_t)b * N_ + n) * M_ + m;
    if (m0 > n0 + 15) { *out = 0.f; return; }   // fully above diagonal
    __shared__ float sq[16][65], sk[16][65];
    int tid = ty * 16 + tx;
    {
        int rr = tid >> 4, cc = (tid & 15) * 4;
        float4 qa = *(const float4*)&q0[((size_t)b * N_ + n0 + rr) * 64 + cc];
        sq[rr][cc] = qa.x; sq[rr][cc + 1] = qa.y; sq[rr][cc + 2] = qa.z; sq[rr][cc + 3] = qa.w;
        float4 ka = *(const float4*)&k0[((size_t)b * N_ + m0 + rr) * 64 + cc];
        sk[rr][cc] = ka.x; sk[rr][cc + 1] = ka.y; sk[rr][cc + 2] = ka.z; sk[rr][cc + 3] = ka.w;
    }
    __syncthreads();
    float acc = 0.f;
#pragma unroll 8
    for (int d = 0; d < 64; ++d) acc += sq[ty][d] * sk[tx][d];
    // causal (m>n) -> relu(-inf)=0 ; diagonal m==n -> 0 ; col 0 -> 0
    float val;
    if (m < n && m != 0) val = fmaxf(acc * 0.125f, 0.f); else val = 0.f;
    *out = val;
}

// -------------------------------- partial column sums of S rows 0..1023
__global__ __launch_bounds__(256) void p_kernel(const float* __restrict__ S,
                                                float* __restrict__ P)
{
    int b = blockIdx.z, c = blockIdx.y;
    int m = blockIdx.x * 256 + threadIdx.x;
    const float* base = S + ((size_t)b * N_ + c * 128) * M_ + m;
    float s = 0.f;
    for (int j = 0; j < 128; ++j) s += base[(size_t)j * M_];
    P[((size_t)b * 8 + c) * M_ + m] = s;
}

// --------------------------------------------- sequential greedy eviction
// Single wave (64 lanes) per batch. Lane t owns slots m = c*256 + 4t + e
// (c chunk 0..7, e 0..3), values in cum[8][4] registers; loop-invariant
// VGPRs lov[8][4] hold lo = 2048 - m.
//   - evicted slot -> cum = -inf (stays -inf: adds are nonneg/-inf)
//   - FUSED argmax: per-lane (v, lo) tournament tree, strict >, static
//     ascending-index operand order (tie -> first operand = smaller m);
//     then 6 DPP stages on the {v-bits, lo} pack with signed-i64 compare
//     (-inf hi negative -> loses; winner always has v >= 0; hi-tie falls
//     to u32 lo compare: larger lo = smaller m). One readlane (lane 63).
//     == lexicographic (value, -m) argmax == jnp.argmax first-max.
//   - chunk activity: chunks 0..NC-1 full, chunk NC partial (m<=i), >NC
//     excluded but still accumulated. NC = i>>8, 4 template instantiations.
//   - 4-bank S-row prefetch: rows +4..+7 in flight (~3 iters of cover).
//   - poison via scalar-guided branch on uniform mstar (readlane -> SGPR).

// tournament combine: take (vb,lb) only if strictly greater value.
__device__ __forceinline__ void vsel(float& va, u32& la, float vb, u32 lb) {
    bool tk = vb > va;
    va = tk ? vb : va;
    la = tk ? lb : la;
}

// DPP packed max stage (ctrl/rmask identical to round-3-validated scheme).
template<int CTRL, int RMASK>
__device__ __forceinline__ void dpp_max_pack(float& v, u32& lo) {
    int hi = __float_as_int(v);
    int hi_o = __builtin_amdgcn_update_dpp(hi, hi, CTRL, RMASK, 0xF, false);
    int lo_o = __builtin_amdgcn_update_dpp((int)lo, (int)lo, CTRL, RMASK, 0xF, false);
    long long a = (long long)((((u64)(u32)hi) << 32) | lo);
    long long b = (long long)((((u64)(u32)hi_o) << 32) | (u32)lo_o);
    bool tk = b > a;
    v = tk ? __int_as_float(hi_o) : v;
    lo = tk ? (u32)lo_o : lo;
}

__device__ __forceinline__ void wave_argmax_to63(float& v, u32& lo) {
    dpp_max_pack<0x121, 0xF>(v, lo);   // row_ror:1
    dpp_max_pack<0x122, 0xF>(v, lo);   // row_ror:2
    dpp_max_pack<0x124, 0xF>(v, lo);   // row_ror:4
    dpp_max_pack<0x128, 0xF>(v, lo);   // row_ror:8
    dpp_max_pack<0x142, 0xA>(v, lo);   // row_bcast15 -> rows 1,3
    dpp_max_pack<0x143, 0xC>(v, lo);   // row_bcast31 -> rows 2,3
}

template<int NC>
__device__ __forceinline__ void evict_step(
    int i, int t, const u32 (&lov)[8][4], float (&cum)[8][4],
    const float4 (&rr)[8], int* __restrict__ evtb)
{
    const float NEGINF = __uint_as_float(0xFF800000u);
    const int relm = (i & 255) - 4 * t;  // chunk NC: slot e active iff e <= relm

    // ---- per-chunk (v, lo) winners: static ascending-index order, strict >
    float cv[NC + 1]; u32 cl[NC + 1];
#pragma unroll
    for (int c = 0; c <= NC; ++c) {
        float x0 = cum[c][0], x1 = cum[c][1], x2 = cum[c][2], x3 = cum[c][3];
        if (c == NC) {
            x0 = (relm >= 0) ? x0 : NEGINF;
            x1 = (relm >= 1) ? x1 : NEGINF;
            x2 = (relm >= 2) ? x2 : NEGINF;
            x3 = (relm >= 3) ? x3 : NEGINF;
        }
        float va = x0; u32 la = lov[c][0];
        vsel(va, la, x1, lov[c][1]);
        float vb = x2; u32 lb = lov[c][2];
        vsel(vb, lb, x3, lov[c][3]);
        vsel(va, la, vb, lb);
        cv[c] = va; cl[c] = la;
    }
    // ---- cross-chunk pairwise fold (ascending c keeps index order)
#pragma unroll
    for (int s = 1; s <= NC; s <<= 1)
#pragma unroll
        for (int c = 0; c + s <= NC; c += 2 * s)
            vsel(cv[c], cl[c], cv[c + s], cl[c + s]);

    // ---- cross-lane packed argmax -> lane 63 -> SGPR
    float bv = cv[0]; u32 bl = cl[0];
    wave_argmax_to63(bv, bl);
    const int mstar = 2048 - __builtin_amdgcn_readlane((int)bl, 63);
    if (t == 0) evtb[mstar] = i;

    // ---- update: Fm[i] -> Fm[i+1]
#pragma unroll
    for (int c = 0; c < 8; ++c) {
        cum[c][0] += rr[c].x; cum[c][1] += rr[c].y;
        cum[c][2] += rr[c].z; cum[c][3] += rr[c].w;
    }
    // ---- poison evicted slot (mstar uniform: scalar-guided selection)
    const int sc = mstar >> 8, se = mstar & 3;
    const bool own = (((mstar >> 2) & 63) == t);
#pragma unroll
    for (int c = 0; c <= NC; ++c)
        if (sc == c) {
#pragma unroll
            for (int e = 0; e < 4; ++e)
                if (se == e) cum[c][e] = own ? NEGINF : cum[c][e];
        }
}

#define LOADBANK(bank, row)                                                   \
    {                                                                         \
        int r_ = (row) < 2047 ? (row) : 2047;                                 \
        _Pragma("unroll")                                                     \
        for (int c_ = 0; c_ < 8; ++c_)                                        \
            bank[c_] = *(const float4*)&Sb[(size_t)r_ * M_ + c_ * 256 + m0];  \
    }

template<int NC>
__device__ __forceinline__ void evict_seg(
    int t, const u32 (&lov)[8][4], float (&cum)[8][4],
    float4 (&bA)[8], float4 (&bB)[8], float4 (&bC)[8], float4 (&bD)[8],
    const float* __restrict__ Sb, int* __restrict__ evtb)
{
    const int m0 = 4 * t;
#pragma unroll 1
    for (int ip = NC * 256; ip < NC * 256 + 256; ip += 4) {
        evict_step<NC>(ip + 0, t, lov, cum, bA, evtb);
        LOADBANK(bA, ip + 4)
        evict_step<NC>(ip + 1, t, lov, cum, bB, evtb);
        LOADBANK(bB, ip + 5)
        evict_step<NC>(ip + 2, t, lov, cum, bC, evtb);
        LOADBANK(bC, ip + 6)
        evict_step<NC>(ip + 3, t, lov, cum, bD, evtb);
        LOADBANK(bD, ip + 7)
    }
}

__global__ __launch_bounds__(64) void evict_kernel(
    const float* __restrict__ S, const float* __restrict__ P,
    int* __restrict__ evt)
{
    int b = blockIdx.x, t = threadIdx.x;       // 64 threads = 1 wave
    const float* Sb = S + (size_t)b * N_ * M_;
    int* evtb = evt + b * M_;
    const int m0 = 4 * t;
    // loop-invariant index regs: lo = 2048 - m, m = c*256 + 4t + e
    u32 lov[8][4];
#pragma unroll
    for (int c = 0; c < 8; ++c)
#pragma unroll
        for (int e = 0; e < 4; ++e)
            lov[c][e] = (u32)(2048 - (c * 256 + m0 + e));
    // initial cum = column sums of the 8 partial chunks (same add order as
    // round 0 -> bitwise identical trajectories -> identical argmax results)
    float cum[8][4];
#pragma unroll
    for (int c = 0; c < 8; ++c) {
        float ax = 0.f, ay = 0.f, az = 0.f, aw = 0.f;
#pragma unroll
        for (int cc = 0; cc < 8; ++cc) {
            float4 pv = *(const float4*)&P[((size_t)b * 8 + cc) * M_ + c * 256 + m0];
            ax += pv.x; ay += pv.y; az += pv.z; aw += pv.w;
        }
        cum[c][0] = ax; cum[c][1] = ay; cum[c][2] = az; cum[c][3] = aw;
    }
#pragma unroll
    for (int c = 0; c < 8; ++c) {
        int4 big = {0x3FFFFFFF, 0x3FFFFFFF, 0x3FFFFFFF, 0x3FFFFFFF};
        *(int4*)&evtb[c * 256 + m0] = big;
    }
    float4 bA[8], bB[8], bC[8], bD[8];
    LOADBANK(bA, 1024)
    LOADBANK(bB, 1025)
    LOADBANK(bC, 1026)
    LOADBANK(bD, 1027)
    evict_seg<4>(t, lov, cum, bA, bB, bC, bD, Sb, evtb);
    evict_seg<5>(t, lov, cum, bA, bB, bC, bD, Sb, evtb);
    evict_seg<6>(t, lov, cum, bA, bB, bC, bD, Sb, evtb);
    evict_seg<7>(t, lov, cum, bA, bB, bC, bD, Sb, evtb);
}

// ------------------------------------------------------ flash attention
__global__ __launch_bounds__(256) void flash_kernel(
    const u16* __restrict__ Qb, const u16* __restrict__ Kb,
    const u16* __restrict__ Vb, const int* __restrict__ evt,
    u16* __restrict__ Ob)
{
    int bh = blockIdx.y;
    int b = bh >> 4, h = bh & 15;
    int q0 = blockIdx.x * 64;
    int tid = threadIdx.x, lane = tid & 63, w = tid >> 6;
    int quad = lane >> 4, l16 = lane & 15;
    const u16* Qh = Qb + (size_t)bh * N_ * DH_;
    const u16* Kh = Kb + (size_t)bh * N_ * DH_;
    const u16* Vh = Vb + (size_t)bh * N_ * DH_;
    __shared__ __align__(16) u16 sK[64 * 64];
    __shared__ __align__(16) u16 sV[64 * 64];     // transposed [dh][key]
    __shared__ __align__(16) u16 sP[4][16 * 64];  // wave-private P
    __shared__ int sevt[64];

    // Q A-frags in registers: A[m=lane&15][k=quad*8+j]
    short8 aq0 = *(const short8*)&Qh[(size_t)(q0 + w * 16 + l16) * 64 + quad * 8];
    short8 aq1 = *(const short8*)&Qh[(size_t)(q0 + w * 16 + l16) * 64 + quad * 8 + 32];

    floatx4 zero = {0.f, 0.f, 0.f, 0.f};
    floatx4 accO[4];
#pragma unroll
    for (int d = 0; d < 4; ++d) accO[d] = zero;
    float m_i[4] = {-1e30f, -1e30f, -1e30f, -1e30f};
    float l_i[4] = {0.f, 0.f, 0.f, 0.f};

    int ktiles = blockIdx.x + 1;
    for (int kt = 0; kt < ktiles; ++kt) {
        int k0 = kt * 64;
#pragma unroll
        for (int it = 0; it < 2; ++it) {
            int e = (tid + it * 256) * 8;
            int r = e >> 6, c = e & 63;
            *(uint4*)&sK[e] = *(const uint4*)&Kh[(size_t)(k0 + r) * 64 + c];
            uint4 vv = *(const uint4*)&Vh[(size_t)(k0 + r) * 64 + c];
            sV[(c + 0) * 64 + r] = (u16)(vv.x & 0xFFFF);
            sV[(c + 1) * 64 + r] = (u16)(vv.x >> 16);
            sV[(c + 2) * 64 + r] = (u16)(vv.y & 0xFFFF);
            sV[(c + 3) * 64 + r] = (u16)(vv.y >> 16);
            sV[(c + 4) * 64 + r] = (u16)(vv.z & 0xFFFF);
            sV[(c + 5) * 64 + r] = (u16)(vv.z >> 16);
            sV[(c + 6) * 64 + r] = (u16)(vv.w & 0xFFFF);
            sV[(c + 7) * 64 + r] = (u16)(vv.w >> 16);
        }
        if (tid < 64) sevt[tid] = evt[b * M_ + k0 + tid];
        __syncthreads();

        floatx4 lg[4];
        int nbase = q0 + w * 16 + quad * 4;
#pragma unroll
        for (int s = 0; s < 4; ++s) {
            floatx4 sc = zero;
            short8 bk0 = *(const short8*)&sK[(s * 16 + l16) * 64 + quad * 8];
            short8 bk1 = *(const short8*)&sK[(s * 16 + l16) * 64 + quad * 8 + 32];
            sc = __builtin_amdgcn_mfma_f32_16x16x32_bf16(aq0, bk0, sc, 0, 0, 0);
            sc = __builtin_amdgcn_mfma_f32_16x16x32_bf16(aq1, bk1, sc, 0, 0, 0);
            int m = k0 + s * 16 + l16;
            int ev = sevt[s * 16 + l16];
#pragma unroll
            for (int r = 0; r < 4; ++r) {
                int n = nbase + r;
                bool keep = (m <= n) && (n < ev);
                lg[s][r] = keep ? sc[r] * 0.125f : -1e30f;
            }
        }
        float mnew[4], scale[4], rs[4];
#pragma unroll
        for (int r = 0; r < 4; ++r) {
            float mx = fmaxf(fmaxf(lg[0][r], lg[1][r]), fmaxf(lg[2][r], lg[3][r]));
#pragma unroll
            for (int d = 1; d < 16; d <<= 1) mx = fmaxf(mx, __shfl_xor(mx, d));
            mnew[r] = fmaxf(m_i[r], mx);
            scale[r] = __expf(m_i[r] - mnew[r]);
            m_i[r] = mnew[r];
            rs[r] = 0.f;
        }
#pragma unroll
        for (int s = 0; s < 4; ++s)
#pragma unroll
            for (int r = 0; r < 4; ++r) {
                float p = __expf(lg[s][r] - mnew[r]);
                rs[r] += p;
                sP[w][(quad * 4 + r) * 64 + s * 16 + l16] = f2b(p);
            }
#pragma unroll
        for (int r = 0; r < 4; ++r) {
            float t_ = rs[r];
#pragma unroll
            for (int d = 1; d < 16; d <<= 1) t_ += __shfl_xor(t_, d);
            l_i[r] = l_i[r] * scale[r] + t_;
        }
#pragma unroll
        for (int dd = 0; dd < 4; ++dd) {
            accO[dd][0] *= scale[0]; accO[dd][1] *= scale[1];
            accO[dd][2] *= scale[2]; accO[dd][3] *= scale[3];
        }
        // P: C-layout -> A-layout via wave-private LDS round-trip
        short8 ap0 = *(const short8*)&sP[w][l16 * 64 + quad * 8];
        short8 ap1 = *(const short8*)&sP[w][l16 * 64 + quad * 8 + 32];
#pragma unroll
        for (int dd = 0; dd < 4; ++dd) {
            short8 bv0 = *(const short8*)&sV[(dd * 16 + l16) * 64 + quad * 8];
            short8 bv1 = *(const short8*)&sV[(dd * 16 + l16) * 64 + quad * 8 + 32];
            accO[dd] = __builtin_amdgcn_mfma_f32_16x16x32_bf16(ap0, bv0, accO[dd], 0, 0, 0);
            accO[dd] = __builtin_amdgcn_mfma_f32_16x16x32_bf16(ap1, bv1, accO[dd], 0, 0, 0);
        }
        __syncthreads();
    }
#pragma unroll
    for (int dd = 0; dd < 4; ++dd)
#pragma unroll
        for (int r = 0; r < 4; ++r) {
            int n = q0 + w * 16 + quad * 4 + r;
            int col = h * 64 + dd * 16 + l16;
            Ob[((size_t)b * N_ + n) * D_ + col] = f2b(accO[dd][r] / l_i[r]);
        }
}

// ---------------------------------------------------------------- launch
extern "C" void kernel_launch(void* const* d_in, const int* in_sizes, int n_in,
                              void* d_out, int out_size, void* d_ws, size_t ws_size,
                              hipStream_t stream)
{
    (void)in_sizes; (void)n_in; (void)out_size; (void)ws_size;
    const float* X  = (const float*)d_in[0];
    const float* Wq = (const float*)d_in[1];
    const float* Wk = (const float*)d_in[2];
    const float* Wv = (const float*)d_in[3];
    const float* Wo = (const float*)d_in[4];
    const float* gq = (const float*)d_in[5];
    const float* bq = (const float*)d_in[6];
    const float* gk = (const float*)d_in[7];
    const float* bk = (const float*)d_in[8];
    // d_in[9] cache_k, d_in[10] cache_v, d_in[11] start_pos: start_pos==0 here.

    char* p = (char*)d_ws;
    const size_t SZ_XH = (size_t)ROWS_ * D_ * 2;   // 8 MiB bf16
    const size_t SZ_W  = (size_t)D_ * D_ * 2;      // 2 MiB bf16
    const size_t SZ_Y  = (size_t)ROWS_ * D_ * 4;   // 16 MiB fp32
    const size_t SZ_PK = (size_t)ROWS_ * D_ * 2;   // 8 MiB bf16
    const size_t SZ_H0 = (size_t)ROWS_ * 64 * 4;   // 1 MiB fp32

    size_t o = 0;
    u16* Xhi = (u16*)(p + o); o += SZ_XH;
    u16* Xlo = (u16*)(p + o); o += SZ_XH;
    u16* Wqh = (u16*)(p + o); o += SZ_W;
    u16* Wql = (u16*)(p + o); o += SZ_W;
    u16* Wkh = (u16*)(p + o); o += SZ_W;
    u16* Wkl = (u16*)(p + o); o += SZ_W;
    u16* Wvh = (u16*)(p + o); o += SZ_W;
    u16* Woh = (u16*)(p + o); o += SZ_W;
    float* Yq = (float*)(p + o); size_t oYq = o; o += SZ_Y;
    float* Yk = (float*)(p + o); o += SZ_Y;
    float* Yv = (float*)(p + o); o += SZ_Y;
    u16* Qb = (u16*)(p + o); o += SZ_PK;
    u16* Kb = (u16*)(p + o); o += SZ_PK;
    u16* Vb = (u16*)(p + o); o += SZ_PK;
    float* q0s = (float*)(p + o); o += SZ_H0;
    float* k0s = (float*)(p + o); o += SZ_H0;
    float* Pp  = (float*)(p + o); o += (size_t)B_ * 8 * M_ * 4;
    int* evt   = (int*)(p + o);  o += (size_t)B_ * M_ * 4;
    // overlays (dead slots):
    float* S = (float*)(p + oYq);   // 32 MiB over Yq+Yk, used after LN
    u16* Ob  = Xhi;                 // 8 MiB over Xhi, used after all X-GEMMs

    cast_x_kernel<<<ROWS_ * D_ / (256 * 4), 256, 0, stream>>>(X, Xhi, Xlo);
    dim3 wgrid(32, 32), wblk(32, 32);
    cast_w_kernel<<<wgrid, wblk, 0, stream>>>(Wq, Wqh, Wql, 1);
    cast_w_kernel<<<wgrid, wblk, 0, stream>>>(Wk, Wkh, Wkl, 1);
    cast_w_kernel<<<wgrid, wblk, 0, stream>>>(Wv, Wvh, nullptr, 0);
    cast_w_kernel<<<wgrid, wblk, 0, stream>>>(Wo, Woh, nullptr, 0);

    dim3 ggrid(D_ / 128, ROWS_ / 128);
    gemm_kernel<<<ggrid, 256, 0, stream>>>(Xhi, Xlo, Wqh, Wql, 1, Yq);
    gemm_kernel<<<ggrid, 256, 0, stream>>>(Xhi, Xlo, Wkh, Wkl, 1, Yk);
    gemm_kernel<<<ggrid, 256, 0, stream>>>(Xhi, nullptr, Wvh, nullptr, 0, Yv);

    lnpack_kernel<<<ROWS_, 256, 0, stream>>>(Yq, gq, bq, Qb, q0s, 1);
    lnpack_kernel<<<ROWS_, 256, 0, stream>>>(Yk, gk, bk, Kb, k0s, 1);
    lnpack_kernel<<<ROWS_, 256, 0, stream>>>(Yv, nullptr, nullptr, Vb, nullptr, 0);

    s_kernel<<<dim3(M_ / 16, N_ / 16, B_), dim3(16, 16), 0, stream>>>(q0s, k0s, S);
    p_kernel<<<dim3(M_ / 256, 8, B_), 256, 0, stream>>>(S, Pp);
    evict_kernel<<<B_, 64, 0, stream>>>(S, Pp, evt);

    flash_kernel<<<dim3(N_ / 64, B_ * H_), 256, 0, stream>>>(Qb, Kb, Vb, evt, Ob);
    gemm_kernel<<<ggrid, 256, 0, stream>>>(Ob, nullptr, Woh, nullptr, 0, (float*)d_out);
}

// Round 6
// 1204.719 us; speedup vs baseline: 1.1551x; 1.0131x over previous
//
// MultiheadSelectiveAttentionWithTokenPruning — MI355X round 5
//
// Pipeline (all on `stream`, graph-capture safe, no statics):
//  1  cast_x      : X fp32 -> Xhi/Xlo bf16 (split for bf16x3 GEMM)
//  2  cast_w x4   : W fp32 -> W^T bf16 (hi[+lo for Wq/Wk])
//  3  gemm split  : Yq = X@Wq  (hi*hi + hi*lo + lo*hi)  ~fp32 accuracy
//  4  gemm split  : Yk = X@Wk
//  5  gemm        : Yv = X@Wv  (plain bf16)
//  6  lnpack      : LN(Yq) -> Qb bf16 + q0s fp32 (head-0 selection)
//  7  lnpack      : LN(Yk) -> Kb + k0s
//  8  lnpack      : Yv -> Vb (cast only)
//  9  s_kernel    : S[b,n,m] = relu(q0s.k0s/8), causal/diag/col0-zeroed
// 10  p_kernel    : column partial sums of S rows 0..1023 (8 chunks)
// 11  evict       : ROUND-5: ZERO STORES IN THE SERIAL LOOP.
//                   Diagnosis: rounds 1-4 all kept a per-iteration global
//                   store (evt[mstar]=i) interleaved in the vmcnt queue.
//                   vmcnt is ORDERED and counts stores; every counted wait
//                   for a prefetched S-row bank had to drain the previous
//                   iteration's store retirement (~hundreds of cycles to
//                   L2/L3) -> the stubborn ~1400 cyc/iter floor that VALU
//                   optimizations couldn't touch.
//                   Fix: eviction times recorded in REGISTERS (evti[8][4],
//                   set inside the same scalar-guided poison branch), one
//                   coalesced int4 store pass after the loop. Loop vmem =
//                   8 bank loads only.
//                   Argmax unchanged from round 4: per-lane (v, lo=2048-m)
//                   tournament (strict >, ascending-index order = first-max)
//                   + 6 DPP stages with signed-i64 packed compare + one
//                   readlane. Bit-identical eviction schedule vs rounds 0-4.
// 12  flash       : all 16 heads, online softmax, mask = causal && n<evt[m]
// 13  gemm        : out = Ob @ Wo -> d_out fp32
//
// ws overlays: Ob reuses Xhi slot (dead after step 5); S reuses Yq+Yk slots
// (dead after steps 6/7). Peak ws ~107.1 MB.

#include <hip/hip_runtime.h>

#define B_    2
#define N_    2048
#define D_    1024
#define H_    16
#define DH_   64
#define M_    2048
#define ROWS_ 4096
#define BUD_  1024

typedef unsigned short u16;
typedef unsigned int   u32;
typedef unsigned long long u64;
typedef __attribute__((ext_vector_type(8))) short short8;
typedef __attribute__((ext_vector_type(4))) float floatx4;

__device__ __forceinline__ u16 f2b(float f) {
    u32 u = __float_as_uint(f);
    return (u16)((u + 0x7FFFu + ((u >> 16) & 1u)) >> 16);   // RNE
}
__device__ __forceinline__ float b2f(u16 h) {
    return __uint_as_float(((u32)h) << 16);
}

// ---------------------------------------------------------------- cast X
__global__ __launch_bounds__(256) void cast_x_kernel(
    const float* __restrict__ X, u16* __restrict__ Xhi, u16* __restrict__ Xlo)
{
    int idx = (blockIdx.x * 256 + threadIdx.x) * 4;
    float4 v = *(const float4*)&X[idx];
    u16 h0 = f2b(v.x), h1 = f2b(v.y), h2 = f2b(v.z), h3 = f2b(v.w);
    ushort4 hv; hv.x = h0; hv.y = h1; hv.z = h2; hv.w = h3;
    *(ushort4*)&Xhi[idx] = hv;
    ushort4 lv;
    lv.x = f2b(v.x - b2f(h0)); lv.y = f2b(v.y - b2f(h1));
    lv.z = f2b(v.z - b2f(h2)); lv.w = f2b(v.w - b2f(h3));
    *(ushort4*)&Xlo[idx] = lv;
}

// ------------------------------------------------- cast + transpose W
__global__ __launch_bounds__(1024) void cast_w_kernel(
    const float* __restrict__ W, u16* __restrict__ Whi, u16* __restrict__ Wlo,
    int do_lo)
{
    __shared__ float tile[32][33];
    int tx = threadIdx.x, ty = threadIdx.y;
    int x = blockIdx.x * 32 + tx, y = blockIdx.y * 32 + ty;
    tile[ty][tx] = W[(size_t)y * D_ + x];
    __syncthreads();
    float v = tile[tx][ty];
    int n = blockIdx.x * 32 + ty, k = blockIdx.y * 32 + tx;
    u16 h = f2b(v);
    Whi[(size_t)n * D_ + k] = h;
    if (do_lo) Wlo[(size_t)n * D_ + k] = f2b(v - b2f(h));
}

// ------------------------------------------------------------- GEMM
// C[4096][1024] = A[4096][1024] @ Bt^T   (Bt stored [n][k])
// mode 1: C = Ah*Bh + Ah*Bl + Al*Bh  (bf16x3 split, ~fp32 precision)
__global__ __launch_bounds__(256) void gemm_kernel(
    const u16* __restrict__ Ah, const u16* __restrict__ Al,
    const u16* __restrict__ Bh, const u16* __restrict__ Bl,
    int mode, float* __restrict__ C)
{
    __shared__ __align__(16) u16 sAh[128 * 32];
    __shared__ __align__(16) u16 sBh[128 * 32];
    __shared__ __align__(16) u16 sAl[128 * 32];
    __shared__ __align__(16) u16 sBl[128 * 32];
    int tid = threadIdx.x;
    int lane = tid & 63, wv = tid >> 6;
    int wr = wv >> 1, wc = wv & 1;
    int quad = lane >> 4, l16 = lane & 15;
    int m0 = blockIdx.y * 128, n0 = blockIdx.x * 128;

    floatx4 acc[4][4];
    floatx4 zero = {0.f, 0.f, 0.f, 0.f};
#pragma unroll
    for (int i = 0; i < 4; ++i)
#pragma unroll
        for (int j = 0; j < 4; ++j) acc[i][j] = zero;

    for (int k0 = 0; k0 < 1024; k0 += 32) {
#pragma unroll
        for (int it = 0; it < 2; ++it) {
            int e = (tid + it * 256) * 8;
            int r = e >> 5, c = e & 31;
            *(uint4*)&sAh[e] = *(const uint4*)&Ah[(size_t)(m0 + r) * 1024 + k0 + c];
            *(uint4*)&sBh[e] = *(const uint4*)&Bh[(size_t)(n0 + r) * 1024 + k0 + c];
            if (mode) {
                *(uint4*)&sAl[e] = *(const uint4*)&Al[(size_t)(m0 + r) * 1024 + k0 + c];
                *(uint4*)&sBl[e] = *(const uint4*)&Bl[(size_t)(n0 + r) * 1024 + k0 + c];
            }
        }
        __syncthreads();
        short8 ah[4], al[4], bh[4], bl[4];
#pragma unroll
        for (int x = 0; x < 4; ++x) {
            int ra = (wr * 64 + x * 16 + l16) * 32 + quad * 8;
            int rb = (wc * 64 + x * 16 + l16) * 32 + quad * 8;
            ah[x] = *(const short8*)&sAh[ra];
            bh[x] = *(const short8*)&sBh[rb];
            if (mode) {
                al[x] = *(const short8*)&sAl[ra];
                bl[x] = *(const short8*)&sBl[rb];
            }
        }
#pragma unroll
        for (int mi = 0; mi < 4; ++mi)
#pragma unroll
            for (int ni = 0; ni < 4; ++ni) {
                acc[mi][ni] = __builtin_amdgcn_mfma_f32_16x16x32_bf16(
                    ah[mi], bh[ni], acc[mi][ni], 0, 0, 0);
                if (mode) {
                    acc[mi][ni] = __builtin_amdgcn_mfma_f32_16x16x32_bf16(
                        ah[mi], bl[ni], acc[mi][ni], 0, 0, 0);
                    acc[mi][ni] = __builtin_amdgcn_mfma_f32_16x16x32_bf16(
                        al[mi], bh[ni], acc[mi][ni], 0, 0, 0);
                }
            }
        __syncthreads();
    }
    // C/D layout: col = lane&15, row = (lane>>4)*4 + reg   [verified m89/m91]
#pragma unroll
    for (int mi = 0; mi < 4; ++mi)
#pragma unroll
        for (int ni = 0; ni < 4; ++ni)
#pragma unroll
            for (int r = 0; r < 4; ++r) {
                int row = m0 + wr * 64 + mi * 16 + quad * 4 + r;
                int col = n0 + wc * 64 + ni * 16 + l16;
                C[(size_t)row * 1024 + col] = acc[mi][ni][r];
            }
}

// ----------------------------------------------------- LayerNorm + pack
__global__ __launch_bounds__(256) void lnpack_kernel(
    const float* __restrict__ Y, const float* __restrict__ gamma,
    const float* __restrict__ beta, u16* __restrict__ Pk,
    float* __restrict__ head0, int do_ln)
{
    int r = blockIdx.x;
    int tid = threadIdx.x;
    float4 v = *(const float4*)&Y[(size_t)r * D_ + tid * 4];
    float mu = 0.f, rsig = 1.f;
    __shared__ float sS[4], sQ[4];
    if (do_ln) {
        float s = v.x + v.y + v.z + v.w;
        float q = v.x * v.x + v.y * v.y + v.z * v.z + v.w * v.w;
#pragma unroll
        for (int d = 1; d < 64; d <<= 1) { s += __shfl_xor(s, d); q += __shfl_xor(q, d); }
        if ((tid & 63) == 0) { sS[tid >> 6] = s; sQ[tid >> 6] = q; }
        __syncthreads();
        s = sS[0] + sS[1] + sS[2] + sS[3];
        q = sQ[0] + sQ[1] + sQ[2] + sQ[3];
        mu = s * (1.f / 1024.f);
        float var = q * (1.f / 1024.f) - mu * mu;
        rsig = rsqrtf(var + 1e-5f);
    }
    int b = r >> 11, n = r & 2047;
    float xs[4] = {v.x, v.y, v.z, v.w};
#pragma unroll
    for (int j = 0; j < 4; ++j) {
        int c = tid * 4 + j;
        float val = do_ln ? ((xs[j] - mu) * rsig * gamma[c] + beta[c]) : xs[j];
        int h = c >> 6, dh = c & 63;
        Pk[(((size_t)b * H_ + h) * N_ + n) * DH_ + dh] = f2b(val);
        if (head0 && c < 64) head0[(size_t)r * 64 + c] = val;
    }
}

// -------------------------------------------- head-0 selection scores S
__global__ void s_kernel(const float* __restrict__ q0,
                         const float* __restrict__ k0, float* __restrict__ S)
{
    int b = blockIdx.z;
    int n0 = blockIdx.y * 16, m0 = blockIdx.x * 16;
    int tx = threadIdx.x, ty = threadIdx.y;
    int n = n0 + ty, m = m0 + tx;
    float* out = S + ((size_t)b * N_ + n) * M_ + m;
    if (m0 > n0 + 15) { *out = 0.f; return; }   // fully above diagonal
    __shared__ float sq[16][65], sk[16][65];
    int tid = ty * 16 + tx;
    {
        int rr = tid >> 4, cc = (tid & 15) * 4;
        float4 qa = *(const float4*)&q0[((size_t)b * N_ + n0 + rr) * 64 + cc];
        sq[rr][cc] = qa.x; sq[rr][cc + 1] = qa.y; sq[rr][cc + 2] = qa.z; sq[rr][cc + 3] = qa.w;
        float4 ka = *(const float4*)&k0[((size_t)b * N_ + m0 + rr) * 64 + cc];
        sk[rr][cc] = ka.x; sk[rr][cc + 1] = ka.y; sk[rr][cc + 2] = ka.z; sk[rr][cc + 3] = ka.w;
    }
    __syncthreads();
    float acc = 0.f;
#pragma unroll 8
    for (int d = 0; d < 64; ++d) acc += sq[ty][d] * sk[tx][d];
    // causal (m>n) -> relu(-inf)=0 ; diagonal m==n -> 0 ; col 0 -> 0
    float val;
    if (m < n && m != 0) val = fmaxf(acc * 0.125f, 0.f); else val = 0.f;
    *out = val;
}

// -------------------------------- partial column sums of S rows 0..1023
__global__ __launch_bounds__(256) void p_kernel(const float* __restrict__ S,
                                                float* __restrict__ P)
{
    int b = blockIdx.z, c = blockIdx.y;
    int m = blockIdx.x * 256 + threadIdx.x;
    const float* base = S + ((size_t)b * N_ + c * 128) * M_ + m;
    float s = 0.f;
    for (int j = 0; j < 128; ++j) s += base[(size_t)j * M_];
    P[((size_t)b * 8 + c) * M_ + m] = s;
}

// --------------------------------------------- sequential greedy eviction
// Single wave (64 lanes) per batch. Lane t owns slots m = c*256 + 4t + e
// (c chunk 0..7, e 0..3), values in cum[8][4] registers; loop-invariant
// VGPRs lov[8][4] hold lo = 2048 - m; evti[8][4] record eviction steps.
//   - NO global stores inside the loop (vmcnt queue = bank loads only;
//     counted waits never stall on store retirement).
//   - evicted slot -> cum = -inf, evti = i (same scalar-guided branch).
//   - FUSED argmax: per-lane (v, lo) tournament tree, strict >, static
//     ascending-index operand order (tie -> first operand = smaller m);
//     then 6 DPP stages on the {v-bits, lo} pack with signed-i64 compare
//     (-inf hi negative -> loses; winner always has v >= 0; hi-tie falls
//     to u32 lo compare: larger lo = smaller m). One readlane (lane 63).
//     == lexicographic (value, -m) argmax == jnp.argmax first-max.
//   - chunk activity: chunks 0..NC-1 full, chunk NC partial (m<=i), >NC
//     excluded but still accumulated. NC = i>>8, 4 template instantiations.
//   - 4-bank S-row prefetch: rows +4..+7 in flight (~3 iters of cover).

// tournament combine: take (vb,lb) only if strictly greater value.
__device__ __forceinline__ void vsel(float& va, u32& la, float vb, u32 lb) {
    bool tk = vb > va;
    va = tk ? vb : va;
    la = tk ? lb : la;
}

// DPP packed max stage (ctrl/rmask identical to round-3/4-validated scheme).
template<int CTRL, int RMASK>
__device__ __forceinline__ void dpp_max_pack(float& v, u32& lo) {
    int hi = __float_as_int(v);
    int hi_o = __builtin_amdgcn_update_dpp(hi, hi, CTRL, RMASK, 0xF, false);
    int lo_o = __builtin_amdgcn_update_dpp((int)lo, (int)lo, CTRL, RMASK, 0xF, false);
    long long a = (long long)((((u64)(u32)hi) << 32) | lo);
    long long b = (long long)((((u64)(u32)hi_o) << 32) | (u32)lo_o);
    bool tk = b > a;
    v = tk ? __int_as_float(hi_o) : v;
    lo = tk ? (u32)lo_o : lo;
}

__device__ __forceinline__ void wave_argmax_to63(float& v, u32& lo) {
    dpp_max_pack<0x121, 0xF>(v, lo);   // row_ror:1
    dpp_max_pack<0x122, 0xF>(v, lo);   // row_ror:2
    dpp_max_pack<0x124, 0xF>(v, lo);   // row_ror:4
    dpp_max_pack<0x128, 0xF>(v, lo);   // row_ror:8
    dpp_max_pack<0x142, 0xA>(v, lo);   // row_bcast15 -> rows 1,3
    dpp_max_pack<0x143, 0xC>(v, lo);   // row_bcast31 -> rows 2,3
}

template<int NC>
__device__ __forceinline__ void evict_step(
    int i, int t, const u32 (&lov)[8][4], float (&cum)[8][4],
    int (&evti)[8][4], const float4 (&rr)[8])
{
    const float NEGINF = __uint_as_float(0xFF800000u);
    const int relm = (i & 255) - 4 * t;  // chunk NC: slot e active iff e <= relm

    // ---- per-chunk (v, lo) winners: static ascending-index order, strict >
    float cv[NC + 1]; u32 cl[NC + 1];
#pragma unroll
    for (int c = 0; c <= NC; ++c) {
        float x0 = cum[c][0], x1 = cum[c][1], x2 = cum[c][2], x3 = cum[c][3];
        if (c == NC) {
            x0 = (relm >= 0) ? x0 : NEGINF;
            x1 = (relm >= 1) ? x1 : NEGINF;
            x2 = (relm >= 2) ? x2 : NEGINF;
            x3 = (relm >= 3) ? x3 : NEGINF;
        }
        float va = x0; u32 la = lov[c][0];
        vsel(va, la, x1, lov[c][1]);
        float vb = x2; u32 lb = lov[c][2];
        vsel(vb, lb, x3, lov[c][3]);
        vsel(va, la, vb, lb);
        cv[c] = va; cl[c] = la;
    }
    // ---- cross-chunk pairwise fold (ascending c keeps index order)
#pragma unroll
    for (int s = 1; s <= NC; s <<= 1)
#pragma unroll
        for (int c = 0; c + s <= NC; c += 2 * s)
            vsel(cv[c], cl[c], cv[c + s], cl[c + s]);

    // ---- cross-lane packed argmax -> lane 63 -> SGPR
    float bv = cv[0]; u32 bl = cl[0];
    wave_argmax_to63(bv, bl);
    const int mstar = 2048 - __builtin_amdgcn_readlane((int)bl, 63);

    // ---- update: Fm[i] -> Fm[i+1]
#pragma unroll
    for (int c = 0; c < 8; ++c) {
        cum[c][0] += rr[c].x; cum[c][1] += rr[c].y;
        cum[c][2] += rr[c].z; cum[c][3] += rr[c].w;
    }
    // ---- poison + record (mstar uniform: scalar-guided, register-only)
    const int sc = mstar >> 8, se = mstar & 3;
    const bool own = (((mstar >> 2) & 63) == t);
#pragma unroll
    for (int c = 0; c <= NC; ++c)
        if (sc == c) {
#pragma unroll
            for (int e = 0; e < 4; ++e)
                if (se == e) {
                    cum[c][e] = own ? NEGINF : cum[c][e];
                    evti[c][e] = own ? i : evti[c][e];
                }
        }
}

#define LOADBANK(bank, row)                                                   \
    {                                                                         \
        int r_ = (row) < 2047 ? (row) : 2047;                                 \
        _Pragma("unroll")                                                     \
        for (int c_ = 0; c_ < 8; ++c_)                                        \
            bank[c_] = *(const float4*)&Sb[(size_t)r_ * M_ + c_ * 256 + m0];  \
    }

template<int NC>
__device__ __forceinline__ void evict_seg(
    int t, const u32 (&lov)[8][4], float (&cum)[8][4], int (&evti)[8][4],
    float4 (&bA)[8], float4 (&bB)[8], float4 (&bC)[8], float4 (&bD)[8],
    const float* __restrict__ Sb)
{
    const int m0 = 4 * t;
#pragma unroll 1
    for (int ip = NC * 256; ip < NC * 256 + 256; ip += 4) {
        evict_step<NC>(ip + 0, t, lov, cum, evti, bA);
        LOADBANK(bA, ip + 4)
        evict_step<NC>(ip + 1, t, lov, cum, evti, bB);
        LOADBANK(bB, ip + 5)
        evict_step<NC>(ip + 2, t, lov, cum, evti, bC);
        LOADBANK(bC, ip + 6)
        evict_step<NC>(ip + 3, t, lov, cum, evti, bD);
        LOADBANK(bD, ip + 7)
    }
}

__global__ __launch_bounds__(64) void evict_kernel(
    const float* __restrict__ S, const float* __restrict__ P,
    int* __restrict__ evt)
{
    int b = blockIdx.x, t = threadIdx.x;       // 64 threads = 1 wave
    const float* Sb = S + (size_t)b * N_ * M_;
    int* evtb = evt + b * M_;
    const int m0 = 4 * t;
    // loop-invariant index regs: lo = 2048 - m, m = c*256 + 4t + e
    u32 lov[8][4];
    int evti[8][4];
#pragma unroll
    for (int c = 0; c < 8; ++c)
#pragma unroll
        for (int e = 0; e < 4; ++e) {
            lov[c][e] = (u32)(2048 - (c * 256 + m0 + e));
            evti[c][e] = 0x3FFFFFFF;
        }
    // initial cum = column sums of the 8 partial chunks (same add order as
    // round 0 -> bitwise identical trajectories -> identical argmax results)
    float cum[8][4];
#pragma unroll
    for (int c = 0; c < 8; ++c) {
        float ax = 0.f, ay = 0.f, az = 0.f, aw = 0.f;
#pragma unroll
        for (int cc = 0; cc < 8; ++cc) {
            float4 pv = *(const float4*)&P[((size_t)b * 8 + cc) * M_ + c * 256 + m0];
            ax += pv.x; ay += pv.y; az += pv.z; aw += pv.w;
        }
        cum[c][0] = ax; cum[c][1] = ay; cum[c][2] = az; cum[c][3] = aw;
    }
    float4 bA[8], bB[8], bC[8], bD[8];
    LOADBANK(bA, 1024)
    LOADBANK(bB, 1025)
    LOADBANK(bC, 1026)
    LOADBANK(bD, 1027)
    evict_seg<4>(t, lov, cum, evti, bA, bB, bC, bD, Sb);
    evict_seg<5>(t, lov, cum, evti, bA, bB, bC, bD, Sb);
    evict_seg<6>(t, lov, cum, evti, bA, bB, bC, bD, Sb);
    evict_seg<7>(t, lov, cum, evti, bA, bB, bC, bD, Sb);
    // single coalesced write pass (the only stores in this kernel)
#pragma unroll
    for (int c = 0; c < 8; ++c) {
        int4 o; o.x = evti[c][0]; o.y = evti[c][1];
        o.z = evti[c][2]; o.w = evti[c][3];
        *(int4*)&evtb[c * 256 + m0] = o;
    }
}

// ------------------------------------------------------ flash attention
__global__ __launch_bounds__(256) void flash_kernel(
    const u16* __restrict__ Qb, const u16* __restrict__ Kb,
    const u16* __restrict__ Vb, const int* __restrict__ evt,
    u16* __restrict__ Ob)
{
    int bh = blockIdx.y;
    int b = bh >> 4, h = bh & 15;
    int q0 = blockIdx.x * 64;
    int tid = threadIdx.x, lane = tid & 63, w = tid >> 6;
    int quad = lane >> 4, l16 = lane & 15;
    const u16* Qh = Qb + (size_t)bh * N_ * DH_;
    const u16* Kh = Kb + (size_t)bh * N_ * DH_;
    const u16* Vh = Vb + (size_t)bh * N_ * DH_;
    __shared__ __align__(16) u16 sK[64 * 64];
    __shared__ __align__(16) u16 sV[64 * 64];     // transposed [dh][key]
    __shared__ __align__(16) u16 sP[4][16 * 64];  // wave-private P
    __shared__ int sevt[64];

    // Q A-frags in registers: A[m=lane&15][k=quad*8+j]
    short8 aq0 = *(const short8*)&Qh[(size_t)(q0 + w * 16 + l16) * 64 + quad * 8];
    short8 aq1 = *(const short8*)&Qh[(size_t)(q0 + w * 16 + l16) * 64 + quad * 8 + 32];

    floatx4 zero = {0.f, 0.f, 0.f, 0.f};
    floatx4 accO[4];
#pragma unroll
    for (int d = 0; d < 4; ++d) accO[d] = zero;
    float m_i[4] = {-1e30f, -1e30f, -1e30f, -1e30f};
    float l_i[4] = {0.f, 0.f, 0.f, 0.f};

    int ktiles = blockIdx.x + 1;
    for (int kt = 0; kt < ktiles; ++kt) {
        int k0 = kt * 64;
#pragma unroll
        for (int it = 0; it < 2; ++it) {
            int e = (tid + it * 256) * 8;
            int r = e >> 6, c = e & 63;
            *(uint4*)&sK[e] = *(const uint4*)&Kh[(size_t)(k0 + r) * 64 + c];
            uint4 vv = *(const uint4*)&Vh[(size_t)(k0 + r) * 64 + c];
            sV[(c + 0) * 64 + r] = (u16)(vv.x & 0xFFFF);
            sV[(c + 1) * 64 + r] = (u16)(vv.x >> 16);
            sV[(c + 2) * 64 + r] = (u16)(vv.y & 0xFFFF);
            sV[(c + 3) * 64 + r] = (u16)(vv.y >> 16);
            sV[(c + 4) * 64 + r] = (u16)(vv.z & 0xFFFF);
            sV[(c + 5) * 64 + r] = (u16)(vv.z >> 16);
            sV[(c + 6) * 64 + r] = (u16)(vv.w & 0xFFFF);
            sV[(c + 7) * 64 + r] = (u16)(vv.w >> 16);
        }
        if (tid < 64) sevt[tid] = evt[b * M_ + k0 + tid];
        __syncthreads();

        floatx4 lg[4];
        int nbase = q0 + w * 16 + quad * 4;
#pragma unroll
        for (int s = 0; s < 4; ++s) {
            floatx4 sc = zero;
            short8 bk0 = *(const short8*)&sK[(s * 16 + l16) * 64 + quad * 8];
            short8 bk1 = *(const short8*)&sK[(s * 16 + l16) * 64 + quad * 8 + 32];
            sc = __builtin_amdgcn_mfma_f32_16x16x32_bf16(aq0, bk0, sc, 0, 0, 0);
            sc = __builtin_amdgcn_mfma_f32_16x16x32_bf16(aq1, bk1, sc, 0, 0, 0);
            int m = k0 + s * 16 + l16;
            int ev = sevt[s * 16 + l16];
#pragma unroll
            for (int r = 0; r < 4; ++r) {
                int n = nbase + r;
                bool keep = (m <= n) && (n < ev);
                lg[s][r] = keep ? sc[r] * 0.125f : -1e30f;
            }
        }
        float mnew[4], scale[4], rs[4];
#pragma unroll
        for (int r = 0; r < 4; ++r) {
            float mx = fmaxf(fmaxf(lg[0][r], lg[1][r]), fmaxf(lg[2][r], lg[3][r]));
#pragma unroll
            for (int d = 1; d < 16; d <<= 1) mx = fmaxf(mx, __shfl_xor(mx, d));
            mnew[r] = fmaxf(m_i[r], mx);
            scale[r] = __expf(m_i[r] - mnew[r]);
            m_i[r] = mnew[r];
            rs[r] = 0.f;
        }
#pragma unroll
        for (int s = 0; s < 4; ++s)
#pragma unroll
            for (int r = 0; r < 4; ++r) {
                float p = __expf(lg[s][r] - mnew[r]);
                rs[r] += p;
                sP[w][(quad * 4 + r) * 64 + s * 16 + l16] = f2b(p);
            }
#pragma unroll
        for (int r = 0; r < 4; ++r) {
            float t_ = rs[r];
#pragma unroll
            for (int d = 1; d < 16; d <<= 1) t_ += __shfl_xor(t_, d);
            l_i[r] = l_i[r] * scale[r] + t_;
        }
#pragma unroll
        for (int dd = 0; dd < 4; ++dd) {
            accO[dd][0] *= scale[0]; accO[dd][1] *= scale[1];
            accO[dd][2] *= scale[2]; accO[dd][3] *= scale[3];
        }
        // P: C-layout -> A-layout via wave-private LDS round-trip
        short8 ap0 = *(const short8*)&sP[w][l16 * 64 + quad * 8];
        short8 ap1 = *(const short8*)&sP[w][l16 * 64 + quad * 8 + 32];
#pragma unroll
        for (int dd = 0; dd < 4; ++dd) {
            short8 bv0 = *(const short8*)&sV[(dd * 16 + l16) * 64 + quad * 8];
            short8 bv1 = *(const short8*)&sV[(dd * 16 + l16) * 64 + quad * 8 + 32];
            accO[dd] = __builtin_amdgcn_mfma_f32_16x16x32_bf16(ap0, bv0, accO[dd], 0, 0, 0);
            accO[dd] = __builtin_amdgcn_mfma_f32_16x16x32_bf16(ap1, bv1, accO[dd], 0, 0, 0);
        }
        __syncthreads();
    }
#pragma unroll
    for (int dd = 0; dd < 4; ++dd)
#pragma unroll
        for (int r = 0; r < 4; ++r) {
            int n = q0 + w * 16 + quad * 4 + r;
            int col = h * 64 + dd * 16 + l16;
            Ob[((size_t)b * N_ + n) * D_ + col] = f2b(accO[dd][r] / l_i[r]);
        }
}

// ---------------------------------------------------------------- launch
extern "C" void kernel_launch(void* const* d_in, const int* in_sizes, int n_in,
                              void* d_out, int out_size, void* d_ws, size_t ws_size,
                              hipStream_t stream)
{
    (void)in_sizes; (void)n_in; (void)out_size; (void)ws_size;
    const float* X  = (const float*)d_in[0];
    const float* Wq = (const float*)d_in[1];
    const float* Wk = (const float*)d_in[2];
    const float* Wv = (const float*)d_in[3];
    const float* Wo = (const float*)d_in[4];
    const float* gq = (const float*)d_in[5];
    const float* bq = (const float*)d_in[6];
    const float* gk = (const float*)d_in[7];
    const float* bk = (const float*)d_in[8];
    // d_in[9] cache_k, d_in[10] cache_v, d_in[11] start_pos: start_pos==0 here.

    char* p = (char*)d_ws;
    const size_t SZ_XH = (size_t)ROWS_ * D_ * 2;   // 8 MiB bf16
    const size_t SZ_W  = (size_t)D_ * D_ * 2;      // 2 MiB bf16
    const size_t SZ_Y  = (size_t)ROWS_ * D_ * 4;   // 16 MiB fp32
    const size_t SZ_PK = (size_t)ROWS_ * D_ * 2;   // 8 MiB bf16
    const size_t SZ_H0 = (size_t)ROWS_ * 64 * 4;   // 1 MiB fp32

    size_t o = 0;
    u16* Xhi = (u16*)(p + o); o += SZ_XH;
    u16* Xlo = (u16*)(p + o); o += SZ_XH;
    u16* Wqh = (u16*)(p + o); o += SZ_W;
    u16* Wql = (u16*)(p + o); o += SZ_W;
    u16* Wkh = (u16*)(p + o); o += SZ_W;
    u16* Wkl = (u16*)(p + o); o += SZ_W;
    u16* Wvh = (u16*)(p + o); o += SZ_W;
    u16* Woh = (u16*)(p + o); o += SZ_W;
    float* Yq = (float*)(p + o); size_t oYq = o; o += SZ_Y;
    float* Yk = (float*)(p + o); o += SZ_Y;
    float* Yv = (float*)(p + o); o += SZ_Y;
    u16* Qb = (u16*)(p + o); o += SZ_PK;
    u16* Kb = (u16*)(p + o); o += SZ_PK;
    u16* Vb = (u16*)(p + o); o += SZ_PK;
    float* q0s = (float*)(p + o); o += SZ_H0;
    float* k0s = (float*)(p + o); o += SZ_H0;
    float* Pp  = (float*)(p + o); o += (size_t)B_ * 8 * M_ * 4;
    int* evt   = (int*)(p + o);  o += (size_t)B_ * M_ * 4;
    // overlays (dead slots):
    float* S = (float*)(p + oYq);   // 32 MiB over Yq+Yk, used after LN
    u16* Ob  = Xhi;                 // 8 MiB over Xhi, used after all X-GEMMs

    cast_x_kernel<<<ROWS_ * D_ / (256 * 4), 256, 0, stream>>>(X, Xhi, Xlo);
    dim3 wgrid(32, 32), wblk(32, 32);
    cast_w_kernel<<<wgrid, wblk, 0, stream>>>(Wq, Wqh, Wql, 1);
    cast_w_kernel<<<wgrid, wblk, 0, stream>>>(Wk, Wkh, Wkl, 1);
    cast_w_kernel<<<wgrid, wblk, 0, stream>>>(Wv, Wvh, nullptr, 0);
    cast_w_kernel<<<wgrid, wblk, 0, stream>>>(Wo, Woh, nullptr, 0);

    dim3 ggrid(D_ / 128, ROWS_ / 128);
    gemm_kernel<<<ggrid, 256, 0, stream>>>(Xhi, Xlo, Wqh, Wql, 1, Yq);
    gemm_kernel<<<ggrid, 256, 0, stream>>>(Xhi, Xlo, Wkh, Wkl, 1, Yk);
    gemm_kernel<<<ggrid, 256, 0, stream>>>(Xhi, nullptr, Wvh, nullptr, 0, Yv);

    lnpack_kernel<<<ROWS_, 256, 0, stream>>>(Yq, gq, bq, Qb, q0s, 1);
    lnpack_kernel<<<ROWS_, 256, 0, stream>>>(Yk, gk, bk, Kb, k0s, 1);
    lnpack_kernel<<<ROWS_, 256, 0, stream>>>(Yv, nullptr, nullptr, Vb, nullptr, 0);

    s_kernel<<<dim3(M_ / 16, N_ / 16, B_), dim3(16, 16), 0, stream>>>(q0s, k0s, S);
    p_kernel<<<dim3(M_ / 256, 8, B_), 256, 0, stream>>>(S, Pp);
    evict_kernel<<<B_, 64, 0, stream>>>(S, Pp, evt);

    flash_kernel<<<dim3(N_ / 64, B_ * H_), 256, 0, stream>>>(Qb, Kb, Vb, evt, Ob);
    gemm_kernel<<<ggrid, 256, 0, stream>>>(Ob, nullptr, Woh, nullptr, 0, (float*)d_out);
}

// Round 7
// 1180.534 us; speedup vs baseline: 1.1787x; 1.0205x over previous
//
// MultiheadSelectiveAttentionWithTokenPruning — MI355X round 6
//
// Pipeline (all on `stream`, graph-capture safe, no statics):
//  1  cast_x      : X fp32 -> Xhi/Xlo bf16 (split for bf16x3 GEMM)
//  2  cast_w x4   : W fp32 -> W^T bf16 (hi[+lo for Wq/Wk])
//  3  gemm split  : Yq = X@Wq  (hi*hi + hi*lo + lo*hi)  ~fp32 accuracy
//  4  gemm split  : Yk = X@Wk
//  5  gemm        : Yv = X@Wv  (plain bf16)
//  6  lnpack      : LN(Yq) -> Qb bf16 + q0s fp32 (head-0 selection)
//  7  lnpack      : LN(Yk) -> Kb + k0s
//  8  lnpack      : Yv -> Vb (cast only)
//  9  s_kernel    : S[b,n,m] = relu(q0s.k0s/8), causal/diag/col0-zeroed
// 10  p_kernel    : column partial sums of S rows 0..1023 (8 chunks)
// 11  evict       : ROUND-6: MANUAL vmcnt PIPELINE (inline-asm loads).
//                   r5 post-mortem: barriers/LDS/shuffles/stores all
//                   eliminated, yet ~1490 cyc/iter persists with only
//                   ~220 cyc of VALU issue -> the only remaining stall
//                   mechanism is the compiler's conservative s_waitcnt
//                   before each bank use (counted-vmcnt pipelines are not
//                   preserved by hipcc across the unroll-1 backedge; each
//                   iter pays an L3/HBM round-trip).
//                   Fix: S-row bank loads are inline-asm global_load_dwordx4
//                   (compiler inserts NO waits for them); each bank consume
//                   is guarded by asm s_waitcnt vmcnt(24) + sched_barrier(0)
//                   (rule #18). 32 loads always in flight; each wait drains
//                   exactly the oldest bank (issued ~3.5 iters earlier).
//                   vmcnt(0) fences after cum-init and before the final
//                   store pass keep the queue accounting exact.
//                   Argmax/poison unchanged from r4/r5: fused (v, lo=2048-m)
//                   tournament + 6 DPP stages + one readlane; evti recorded
//                   in registers; single coalesced store pass at the end.
//                   Bit-identical eviction schedule vs rounds 0-5.
// 12  flash       : all 16 heads, online softmax, mask = causal && n<evt[m]
// 13  gemm        : out = Ob @ Wo -> d_out fp32
//
// ws overlays: Ob reuses Xhi slot (dead after step 5); S reuses Yq+Yk slots
// (dead after steps 6/7). Peak ws ~107.1 MB.

#include <hip/hip_runtime.h>

#define B_    2
#define N_    2048
#define D_    1024
#define H_    16
#define DH_   64
#define M_    2048
#define ROWS_ 4096
#define BUD_  1024

typedef unsigned short u16;
typedef unsigned int   u32;
typedef unsigned long long u64;
typedef __attribute__((ext_vector_type(8))) short short8;
typedef __attribute__((ext_vector_type(4))) float floatx4;

__device__ __forceinline__ u16 f2b(float f) {
    u32 u = __float_as_uint(f);
    return (u16)((u + 0x7FFFu + ((u >> 16) & 1u)) >> 16);   // RNE
}
__device__ __forceinline__ float b2f(u16 h) {
    return __uint_as_float(((u32)h) << 16);
}

// ---------------------------------------------------------------- cast X
__global__ __launch_bounds__(256) void cast_x_kernel(
    const float* __restrict__ X, u16* __restrict__ Xhi, u16* __restrict__ Xlo)
{
    int idx = (blockIdx.x * 256 + threadIdx.x) * 4;
    float4 v = *(const float4*)&X[idx];
    u16 h0 = f2b(v.x), h1 = f2b(v.y), h2 = f2b(v.z), h3 = f2b(v.w);
    ushort4 hv; hv.x = h0; hv.y = h1; hv.z = h2; hv.w = h3;
    *(ushort4*)&Xhi[idx] = hv;
    ushort4 lv;
    lv.x = f2b(v.x - b2f(h0)); lv.y = f2b(v.y - b2f(h1));
    lv.z = f2b(v.z - b2f(h2)); lv.w = f2b(v.w - b2f(h3));
    *(ushort4*)&Xlo[idx] = lv;
}

// ------------------------------------------------- cast + transpose W
__global__ __launch_bounds__(1024) void cast_w_kernel(
    const float* __restrict__ W, u16* __restrict__ Whi, u16* __restrict__ Wlo,
    int do_lo)
{
    __shared__ float tile[32][33];
    int tx = threadIdx.x, ty = threadIdx.y;
    int x = blockIdx.x * 32 + tx, y = blockIdx.y * 32 + ty;
    tile[ty][tx] = W[(size_t)y * D_ + x];
    __syncthreads();
    float v = tile[tx][ty];
    int n = blockIdx.x * 32 + ty, k = blockIdx.y * 32 + tx;
    u16 h = f2b(v);
    Whi[(size_t)n * D_ + k] = h;
    if (do_lo) Wlo[(size_t)n * D_ + k] = f2b(v - b2f(h));
}

// ------------------------------------------------------------- GEMM
// C[4096][1024] = A[4096][1024] @ Bt^T   (Bt stored [n][k])
// mode 1: C = Ah*Bh + Ah*Bl + Al*Bh  (bf16x3 split, ~fp32 precision)
__global__ __launch_bounds__(256) void gemm_kernel(
    const u16* __restrict__ Ah, const u16* __restrict__ Al,
    const u16* __restrict__ Bh, const u16* __restrict__ Bl,
    int mode, float* __restrict__ C)
{
    __shared__ __align__(16) u16 sAh[128 * 32];
    __shared__ __align__(16) u16 sBh[128 * 32];
    __shared__ __align__(16) u16 sAl[128 * 32];
    __shared__ __align__(16) u16 sBl[128 * 32];
    int tid = threadIdx.x;
    int lane = tid & 63, wv = tid >> 6;
    int wr = wv >> 1, wc = wv & 1;
    int quad = lane >> 4, l16 = lane & 15;
    int m0 = blockIdx.y * 128, n0 = blockIdx.x * 128;

    floatx4 acc[4][4];
    floatx4 zero = {0.f, 0.f, 0.f, 0.f};
#pragma unroll
    for (int i = 0; i < 4; ++i)
#pragma unroll
        for (int j = 0; j < 4; ++j) acc[i][j] = zero;

    for (int k0 = 0; k0 < 1024; k0 += 32) {
#pragma unroll
        for (int it = 0; it < 2; ++it) {
            int e = (tid + it * 256) * 8;
            int r = e >> 5, c = e & 31;
            *(uint4*)&sAh[e] = *(const uint4*)&Ah[(size_t)(m0 + r) * 1024 + k0 + c];
            *(uint4*)&sBh[e] = *(const uint4*)&Bh[(size_t)(n0 + r) * 1024 + k0 + c];
            if (mode) {
                *(uint4*)&sAl[e] = *(const uint4*)&Al[(size_t)(m0 + r) * 1024 + k0 + c];
                *(uint4*)&sBl[e] = *(const uint4*)&Bl[(size_t)(n0 + r) * 1024 + k0 + c];
            }
        }
        __syncthreads();
        short8 ah[4], al[4], bh[4], bl[4];
#pragma unroll
        for (int x = 0; x < 4; ++x) {
            int ra = (wr * 64 + x * 16 + l16) * 32 + quad * 8;
            int rb = (wc * 64 + x * 16 + l16) * 32 + quad * 8;
            ah[x] = *(const short8*)&sAh[ra];
            bh[x] = *(const short8*)&sBh[rb];
            if (mode) {
                al[x] = *(const short8*)&sAl[ra];
                bl[x] = *(const short8*)&sBl[rb];
            }
        }
#pragma unroll
        for (int mi = 0; mi < 4; ++mi)
#pragma unroll
            for (int ni = 0; ni < 4; ++ni) {
                acc[mi][ni] = __builtin_amdgcn_mfma_f32_16x16x32_bf16(
                    ah[mi], bh[ni], acc[mi][ni], 0, 0, 0);
                if (mode) {
                    acc[mi][ni] = __builtin_amdgcn_mfma_f32_16x16x32_bf16(
                        ah[mi], bl[ni], acc[mi][ni], 0, 0, 0);
                    acc[mi][ni] = __builtin_amdgcn_mfma_f32_16x16x32_bf16(
                        al[mi], bh[ni], acc[mi][ni], 0, 0, 0);
                }
            }
        __syncthreads();
    }
    // C/D layout: col = lane&15, row = (lane>>4)*4 + reg   [verified m89/m91]
#pragma unroll
    for (int mi = 0; mi < 4; ++mi)
#pragma unroll
        for (int ni = 0; ni < 4; ++ni)
#pragma unroll
            for (int r = 0; r < 4; ++r) {
                int row = m0 + wr * 64 + mi * 16 + quad * 4 + r;
                int col = n0 + wc * 64 + ni * 16 + l16;
                C[(size_t)row * 1024 + col] = acc[mi][ni][r];
            }
}

// ----------------------------------------------------- LayerNorm + pack
__global__ __launch_bounds__(256) void lnpack_kernel(
    const float* __restrict__ Y, const float* __restrict__ gamma,
    const float* __restrict__ beta, u16* __restrict__ Pk,
    float* __restrict__ head0, int do_ln)
{
    int r = blockIdx.x;
    int tid = threadIdx.x;
    float4 v = *(const float4*)&Y[(size_t)r * D_ + tid * 4];
    float mu = 0.f, rsig = 1.f;
    __shared__ float sS[4], sQ[4];
    if (do_ln) {
        float s = v.x + v.y + v.z + v.w;
        float q = v.x * v.x + v.y * v.y + v.z * v.z + v.w * v.w;
#pragma unroll
        for (int d = 1; d < 64; d <<= 1) { s += __shfl_xor(s, d); q += __shfl_xor(q, d); }
        if ((tid & 63) == 0) { sS[tid >> 6] = s; sQ[tid >> 6] = q; }
        __syncthreads();
        s = sS[0] + sS[1] + sS[2] + sS[3];
        q = sQ[0] + sQ[1] + sQ[2] + sQ[3];
        mu = s * (1.f / 1024.f);
        float var = q * (1.f / 1024.f) - mu * mu;
        rsig = rsqrtf(var + 1e-5f);
    }
    int b = r >> 11, n = r & 2047;
    float xs[4] = {v.x, v.y, v.z, v.w};
#pragma unroll
    for (int j = 0; j < 4; ++j) {
        int c = tid * 4 + j;
        float val = do_ln ? ((xs[j] - mu) * rsig * gamma[c] + beta[c]) : xs[j];
        int h = c >> 6, dh = c & 63;
        Pk[(((size_t)b * H_ + h) * N_ + n) * DH_ + dh] = f2b(val);
        if (head0 && c < 64) head0[(size_t)r * 64 + c] = val;
    }
}

// -------------------------------------------- head-0 selection scores S
__global__ void s_kernel(const float* __restrict__ q0,
                         const float* __restrict__ k0, float* __restrict__ S)
{
    int b = blockIdx.z;
    int n0 = blockIdx.y * 16, m0 = blockIdx.x * 16;
    int tx = threadIdx.x, ty = threadIdx.y;
    int n = n0 + ty, m = m0 + tx;
    float* out = S + ((size_t)b * N_ + n) * M_ + m;
    if (m0 > n0 + 15) { *out = 0.f; return; }   // fully above diagonal
    __shared__ float sq[16][65], sk[16][65];
    int tid = ty * 16 + tx;
    {
        int rr = tid >> 4, cc = (tid & 15) * 4;
        float4 qa = *(const float4*)&q0[((size_t)b * N_ + n0 + rr) * 64 + cc];
        sq[rr][cc] = qa.x; sq[rr][cc + 1] = qa.y; sq[rr][cc + 2] = qa.z; sq[rr][cc + 3] = qa.w;
        float4 ka = *(const float4*)&k0[((size_t)b * N_ + m0 + rr) * 64 + cc];
        sk[rr][cc] = ka.x; sk[rr][cc + 1] = ka.y; sk[rr][cc + 2] = ka.z; sk[rr][cc + 3] = ka.w;
    }
    __syncthreads();
    float acc = 0.f;
#pragma unroll 8
    for (int d = 0; d < 64; ++d) acc += sq[ty][d] * sk[tx][d];
    // causal (m>n) -> relu(-inf)=0 ; diagonal m==n -> 0 ; col 0 -> 0
    float val;
    if (m < n && m != 0) val = fmaxf(acc * 0.125f, 0.f); else val = 0.f;
    *out = val;
}

// -------------------------------- partial column sums of S rows 0..1023
__global__ __launch_bounds__(256) void p_kernel(const float* __restrict__ S,
                                                float* __restrict__ P)
{
    int b = blockIdx.z, c = blockIdx.y;
    int m = blockIdx.x * 256 + threadIdx.x;
    const float* base = S + ((size_t)b * N_ + c * 128) * M_ + m;
    float s = 0.f;
    for (int j = 0; j < 128; ++j) s += base[(size_t)j * M_];
    P[((size_t)b * 8 + c) * M_ + m] = s;
}

// --------------------------------------------- sequential greedy eviction
// Single wave (64 lanes) per batch. Lane t owns slots m = c*256 + 4t + e
// (c chunk 0..7, e 0..3), values in cum[8][4] registers; loop-invariant
// VGPRs lov[8][4] hold lo = 2048 - m; evti[8][4] record eviction steps.
//   - S-row banks loaded via INLINE-ASM global_load_dwordx4 (compiler's
//     waitcnt pass never sees them -> no conservative drains); consumes
//     guarded by asm s_waitcnt vmcnt(24) + sched_barrier(0). 32 loads in
//     flight, 4-bank rotation, each wait drains exactly the oldest bank.
//   - evicted slot -> cum = -inf, evti = i (scalar-guided, register-only).
//   - FUSED argmax: per-lane (v, lo) tournament tree, strict >, static
//     ascending-index operand order; 6 DPP stages, signed-i64 packed
//     compare; one readlane. == jnp.argmax first-max.
//   - chunk activity: NC = i>>8 via 4 template instantiations.

// tournament combine: take (vb,lb) only if strictly greater value.
__device__ __forceinline__ void vsel(float& va, u32& la, float vb, u32 lb) {
    bool tk = vb > va;
    va = tk ? vb : va;
    la = tk ? lb : la;
}

// DPP packed max stage (ctrl/rmask identical to round-3/4/5 scheme).
template<int CTRL, int RMASK>
__device__ __forceinline__ void dpp_max_pack(float& v, u32& lo) {
    int hi = __float_as_int(v);
    int hi_o = __builtin_amdgcn_update_dpp(hi, hi, CTRL, RMASK, 0xF, false);
    int lo_o = __builtin_amdgcn_update_dpp((int)lo, (int)lo, CTRL, RMASK, 0xF, false);
    long long a = (long long)((((u64)(u32)hi) << 32) | lo);
    long long b = (long long)((((u64)(u32)hi_o) << 32) | (u32)lo_o);
    bool tk = b > a;
    v = tk ? __int_as_float(hi_o) : v;
    lo = tk ? (u32)lo_o : lo;
}

__device__ __forceinline__ void wave_argmax_to63(float& v, u32& lo) {
    dpp_max_pack<0x121, 0xF>(v, lo);   // row_ror:1
    dpp_max_pack<0x122, 0xF>(v, lo);   // row_ror:2
    dpp_max_pack<0x124, 0xF>(v, lo);   // row_ror:4
    dpp_max_pack<0x128, 0xF>(v, lo);   // row_ror:8
    dpp_max_pack<0x142, 0xA>(v, lo);   // row_bcast15 -> rows 1,3
    dpp_max_pack<0x143, 0xC>(v, lo);   // row_bcast31 -> rows 2,3
}

// inline-asm 16B load: dst <- Sb[voff + imm]  (SGPR base + 32b voffset)
#define GLOAD(dst, voff, ptr, imm)                                    \
    asm volatile("global_load_dwordx4 %0, %1, %2 offset:" #imm        \
                 : "=v"(dst) : "v"(voff), "s"(ptr) : "memory")

// issue one bank (8x16B = one S row slice for this lane)
#define ISSUE_BANK(bank, row)                                         \
    {                                                                 \
        u32 r_ = (u32)((row) < 2047 ? (row) : 2047);                  \
        u32 vo = lane16 + r_ * 8192u;                                 \
        u32 vo2 = vo + 4096u;                                         \
        GLOAD(bank[0], vo,  Sb, 0);                                   \
        GLOAD(bank[1], vo,  Sb, 1024);                                \
        GLOAD(bank[2], vo,  Sb, 2048);                                \
        GLOAD(bank[3], vo,  Sb, 3072);                                \
        GLOAD(bank[4], vo2, Sb, 0);                                   \
        GLOAD(bank[5], vo2, Sb, 1024);                                \
        GLOAD(bank[6], vo2, Sb, 2048);                                \
        GLOAD(bank[7], vo2, Sb, 3072);                                \
    }

// counted wait + scheduler fence (rule #18: fence stops reg-use hoisting)
#define VWAIT24()                                                     \
    do { asm volatile("s_waitcnt vmcnt(24)" ::: "memory");            \
         __builtin_amdgcn_sched_barrier(0); } while (0)
#define VWAIT0()                                                      \
    do { asm volatile("s_waitcnt vmcnt(0)" ::: "memory");             \
         __builtin_amdgcn_sched_barrier(0); } while (0)

template<int NC>
__device__ __forceinline__ void evict_step(
    int i, int t, const u32 (&lov)[8][4], float (&cum)[8][4],
    int (&evti)[8][4], const floatx4 (&rr)[8])
{
    const float NEGINF = __uint_as_float(0xFF800000u);
    const int relm = (i & 255) - 4 * t;  // chunk NC: slot e active iff e <= relm

    // ---- per-chunk (v, lo) winners: static ascending-index order, strict >
    float cv[NC + 1]; u32 cl[NC + 1];
#pragma unroll
    for (int c = 0; c <= NC; ++c) {
        float x0 = cum[c][0], x1 = cum[c][1], x2 = cum[c][2], x3 = cum[c][3];
        if (c == NC) {
            x0 = (relm >= 0) ? x0 : NEGINF;
            x1 = (relm >= 1) ? x1 : NEGINF;
            x2 = (relm >= 2) ? x2 : NEGINF;
            x3 = (relm >= 3) ? x3 : NEGINF;
        }
        float va = x0; u32 la = lov[c][0];
        vsel(va, la, x1, lov[c][1]);
        float vb = x2; u32 lb = lov[c][2];
        vsel(vb, lb, x3, lov[c][3]);
        vsel(va, la, vb, lb);
        cv[c] = va; cl[c] = la;
    }
    // ---- cross-chunk pairwise fold (ascending c keeps index order)
#pragma unroll
    for (int s = 1; s <= NC; s <<= 1)
#pragma unroll
        for (int c = 0; c + s <= NC; c += 2 * s)
            vsel(cv[c], cl[c], cv[c + s], cl[c + s]);

    // ---- cross-lane packed argmax -> lane 63 -> SGPR
    float bv = cv[0]; u32 bl = cl[0];
    wave_argmax_to63(bv, bl);
    const int mstar = 2048 - __builtin_amdgcn_readlane((int)bl, 63);

    // ---- update: Fm[i] -> Fm[i+1]
#pragma unroll
    for (int c = 0; c < 8; ++c) {
        cum[c][0] += rr[c][0]; cum[c][1] += rr[c][1];
        cum[c][2] += rr[c][2]; cum[c][3] += rr[c][3];
    }
    // ---- poison + record (mstar uniform: scalar-guided, register-only)
    const int sc = mstar >> 8, se = mstar & 3;
    const bool own = (((mstar >> 2) & 63) == t);
#pragma unroll
    for (int c = 0; c <= NC; ++c)
        if (sc == c) {
#pragma unroll
            for (int e = 0; e < 4; ++e)
                if (se == e) {
                    cum[c][e] = own ? NEGINF : cum[c][e];
                    evti[c][e] = own ? i : evti[c][e];
                }
        }
}

template<int NC>
__device__ __forceinline__ void evict_seg(
    int t, u32 lane16, const u32 (&lov)[8][4], float (&cum)[8][4],
    int (&evti)[8][4],
    floatx4 (&bA)[8], floatx4 (&bB)[8], floatx4 (&bC)[8], floatx4 (&bD)[8],
    const float* __restrict__ Sb)
{
#pragma unroll 1
    for (int ip = NC * 256; ip < NC * 256 + 256; ip += 4) {
        VWAIT24();
        evict_step<NC>(ip + 0, t, lov, cum, evti, bA);
        ISSUE_BANK(bA, ip + 4)
        VWAIT24();
        evict_step<NC>(ip + 1, t, lov, cum, evti, bB);
        ISSUE_BANK(bB, ip + 5)
        VWAIT24();
        evict_step<NC>(ip + 2, t, lov, cum, evti, bC);
        ISSUE_BANK(bC, ip + 6)
        VWAIT24();
        evict_step<NC>(ip + 3, t, lov, cum, evti, bD);
        ISSUE_BANK(bD, ip + 7)
    }
}

__global__ __launch_bounds__(64) void evict_kernel(
    const float* __restrict__ S, const float* __restrict__ P,
    int* __restrict__ evt)
{
    int b = blockIdx.x, t = threadIdx.x;       // 64 threads = 1 wave
    const float* Sb = S + (size_t)b * N_ * M_;
    int* evtb = evt + b * M_;
    const int m0 = 4 * t;
    const u32 lane16 = (u32)(16 * t);          // byte offset of this lane
    // loop-invariant index regs: lo = 2048 - m, m = c*256 + 4t + e
    u32 lov[8][4];
    int evti[8][4];
#pragma unroll
    for (int c = 0; c < 8; ++c)
#pragma unroll
        for (int e = 0; e < 4; ++e) {
            lov[c][e] = (u32)(2048 - (c * 256 + m0 + e));
            evti[c][e] = 0x3FFFFFFF;
        }
    // initial cum = column sums of the 8 partial chunks (same add order as
    // round 0 -> bitwise identical trajectories -> identical argmax results)
    float cum[8][4];
#pragma unroll
    for (int c = 0; c < 8; ++c) {
        float ax = 0.f, ay = 0.f, az = 0.f, aw = 0.f;
#pragma unroll
        for (int cc = 0; cc < 8; ++cc) {
            floatx4 pv = *(const floatx4*)&P[((size_t)b * 8 + cc) * M_ + c * 256 + m0];
            ax += pv[0]; ay += pv[1]; az += pv[2]; aw += pv[3];
        }
        cum[c][0] = ax; cum[c][1] = ay; cum[c][2] = az; cum[c][3] = aw;
    }
    // fence: drain all compiler-tracked loads so asm vmcnt counting is exact
    VWAIT0();
    floatx4 bA[8], bB[8], bC[8], bD[8];
    ISSUE_BANK(bA, 1024)
    ISSUE_BANK(bB, 1025)
    ISSUE_BANK(bC, 1026)
    ISSUE_BANK(bD, 1027)
    evict_seg<4>(t, lane16, lov, cum, evti, bA, bB, bC, bD, Sb);
    evict_seg<5>(t, lane16, lov, cum, evti, bA, bB, bC, bD, Sb);
    evict_seg<6>(t, lane16, lov, cum, evti, bA, bB, bC, bD, Sb);
    evict_seg<7>(t, lane16, lov, cum, evti, bA, bB, bC, bD, Sb);
    VWAIT0();   // drain leftover bank loads before reusing the vmem queue
    // single coalesced write pass (the only stores in this kernel)
#pragma unroll
    for (int c = 0; c < 8; ++c) {
        int4 o; o.x = evti[c][0]; o.y = evti[c][1];
        o.z = evti[c][2]; o.w = evti[c][3];
        *(int4*)&evtb[c * 256 + m0] = o;
    }
}

// ------------------------------------------------------ flash attention
__global__ __launch_bounds__(256) void flash_kernel(
    const u16* __restrict__ Qb, const u16* __restrict__ Kb,
    const u16* __restrict__ Vb, const int* __restrict__ evt,
    u16* __restrict__ Ob)
{
    int bh = blockIdx.y;
    int b = bh >> 4, h = bh & 15;
    int q0 = blockIdx.x * 64;
    int tid = threadIdx.x, lane = tid & 63, w = tid >> 6;
    int quad = lane >> 4, l16 = lane & 15;
    const u16* Qh = Qb + (size_t)bh * N_ * DH_;
    const u16* Kh = Kb + (size_t)bh * N_ * DH_;
    const u16* Vh = Vb + (size_t)bh * N_ * DH_;
    __shared__ __align__(16) u16 sK[64 * 64];
    __shared__ __align__(16) u16 sV[64 * 64];     // transposed [dh][key]
    __shared__ __align__(16) u16 sP[4][16 * 64];  // wave-private P
    __shared__ int sevt[64];

    // Q A-frags in registers: A[m=lane&15][k=quad*8+j]
    short8 aq0 = *(const short8*)&Qh[(size_t)(q0 + w * 16 + l16) * 64 + quad * 8];
    short8 aq1 = *(const short8*)&Qh[(size_t)(q0 + w * 16 + l16) * 64 + quad * 8 + 32];

    floatx4 zero = {0.f, 0.f, 0.f, 0.f};
    floatx4 accO[4];
#pragma unroll
    for (int d = 0; d < 4; ++d) accO[d] = zero;
    float m_i[4] = {-1e30f, -1e30f, -1e30f, -1e30f};
    float l_i[4] = {0.f, 0.f, 0.f, 0.f};

    int ktiles = blockIdx.x + 1;
    for (int kt = 0; kt < ktiles; ++kt) {
        int k0 = kt * 64;
#pragma unroll
        for (int it = 0; it < 2; ++it) {
            int e = (tid + it * 256) * 8;
            int r = e >> 6, c = e & 63;
            *(uint4*)&sK[e] = *(const uint4*)&Kh[(size_t)(k0 + r) * 64 + c];
            uint4 vv = *(const uint4*)&Vh[(size_t)(k0 + r) * 64 + c];
            sV[(c + 0) * 64 + r] = (u16)(vv.x & 0xFFFF);
            sV[(c + 1) * 64 + r] = (u16)(vv.x >> 16);
            sV[(c + 2) * 64 + r] = (u16)(vv.y & 0xFFFF);
            sV[(c + 3) * 64 + r] = (u16)(vv.y >> 16);
            sV[(c + 4) * 64 + r] = (u16)(vv.z & 0xFFFF);
            sV[(c + 5) * 64 + r] = (u16)(vv.z >> 16);
            sV[(c + 6) * 64 + r] = (u16)(vv.w & 0xFFFF);
            sV[(c + 7) * 64 + r] = (u16)(vv.w >> 16);
        }
        if (tid < 64) sevt[tid] = evt[b * M_ + k0 + tid];
        __syncthreads();

        floatx4 lg[4];
        int nbase = q0 + w * 16 + quad * 4;
#pragma unroll
        for (int s = 0; s < 4; ++s) {
            floatx4 sc = zero;
            short8 bk0 = *(const short8*)&sK[(s * 16 + l16) * 64 + quad * 8];
            short8 bk1 = *(const short8*)&sK[(s * 16 + l16) * 64 + quad * 8 + 32];
            sc = __builtin_amdgcn_mfma_f32_16x16x32_bf16(aq0, bk0, sc, 0, 0, 0);
            sc = __builtin_amdgcn_mfma_f32_16x16x32_bf16(aq1, bk1, sc, 0, 0, 0);
            int m = k0 + s * 16 + l16;
            int ev = sevt[s * 16 + l16];
#pragma unroll
            for (int r = 0; r < 4; ++r) {
                int n = nbase + r;
                bool keep = (m <= n) && (n < ev);
                lg[s][r] = keep ? sc[r] * 0.125f : -1e30f;
            }
        }
        float mnew[4], scale[4], rs[4];
#pragma unroll
        for (int r = 0; r < 4; ++r) {
            float mx = fmaxf(fmaxf(lg[0][r], lg[1][r]), fmaxf(lg[2][r], lg[3][r]));
#pragma unroll
            for (int d = 1; d < 16; d <<= 1) mx = fmaxf(mx, __shfl_xor(mx, d));
            mnew[r] = fmaxf(m_i[r], mx);
            scale[r] = __expf(m_i[r] - mnew[r]);
            m_i[r] = mnew[r];
            rs[r] = 0.f;
        }
#pragma unroll
        for (int s = 0; s < 4; ++s)
#pragma unroll
            for (int r = 0; r < 4; ++r) {
                float p = __expf(lg[s][r] - mnew[r]);
                rs[r] += p;
                sP[w][(quad * 4 + r) * 64 + s * 16 + l16] = f2b(p);
            }
#pragma unroll
        for (int r = 0; r < 4; ++r) {
            float t_ = rs[r];
#pragma unroll
            for (int d = 1; d < 16; d <<= 1) t_ += __shfl_xor(t_, d);
            l_i[r] = l_i[r] * scale[r] + t_;
        }
#pragma unroll
        for (int dd = 0; dd < 4; ++dd) {
            accO[dd][0] *= scale[0]; accO[dd][1] *= scale[1];
            accO[dd][2] *= scale[2]; accO[dd][3] *= scale[3];
        }
        // P: C-layout -> A-layout via wave-private LDS round-trip
        short8 ap0 = *(const short8*)&sP[w][l16 * 64 + quad * 8];
        short8 ap1 = *(const short8*)&sP[w][l16 * 64 + quad * 8 + 32];
#pragma unroll
        for (int dd = 0; dd < 4; ++dd) {
            short8 bv0 = *(const short8*)&sV[(dd * 16 + l16) * 64 + quad * 8];
            short8 bv1 = *(const short8*)&sV[(dd * 16 + l16) * 64 + quad * 8 + 32];
            accO[dd] = __builtin_amdgcn_mfma_f32_16x16x32_bf16(ap0, bv0, accO[dd], 0, 0, 0);
            accO[dd] = __builtin_amdgcn_mfma_f32_16x16x32_bf16(ap1, bv1, accO[dd], 0, 0, 0);
        }
        __syncthreads();
    }
#pragma unroll
    for (int dd = 0; dd < 4; ++dd)
#pragma unroll
        for (int r = 0; r < 4; ++r) {
            int n = q0 + w * 16 + quad * 4 + r;
            int col = h * 64 + dd * 16 + l16;
            Ob[((size_t)b * N_ + n) * D_ + col] = f2b(accO[dd][r] / l_i[r]);
        }
}

// ---------------------------------------------------------------- launch
extern "C" void kernel_launch(void* const* d_in, const int* in_sizes, int n_in,
                              void* d_out, int out_size, void* d_ws, size_t ws_size,
                              hipStream_t stream)
{
    (void)in_sizes; (void)n_in; (void)out_size; (void)ws_size;
    const float* X  = (const float*)d_in[0];
    const float* Wq = (const float*)d_in[1];
    const float* Wk = (const float*)d_in[2];
    const float* Wv = (const float*)d_in[3];
    const float* Wo = (const float*)d_in[4];
    const float* gq = (const float*)d_in[5];
    const float* bq = (const float*)d_in[6];
    const float* gk = (const float*)d_in[7];
    const float* bk = (const float*)d_in[8];
    // d_in[9] cache_k, d_in[10] cache_v, d_in[11] start_pos: start_pos==0 here.

    char* p = (char*)d_ws;
    const size_t SZ_XH = (size_t)ROWS_ * D_ * 2;   // 8 MiB bf16
    const size_t SZ_W  = (size_t)D_ * D_ * 2;      // 2 MiB bf16
    const size_t SZ_Y  = (size_t)ROWS_ * D_ * 4;   // 16 MiB fp32
    const size_t SZ_PK = (size_t)ROWS_ * D_ * 2;   // 8 MiB bf16
    const size_t SZ_H0 = (size_t)ROWS_ * 64 * 4;   // 1 MiB fp32

    size_t o = 0;
    u16* Xhi = (u16*)(p + o); o += SZ_XH;
    u16* Xlo = (u16*)(p + o); o += SZ_XH;
    u16* Wqh = (u16*)(p + o); o += SZ_W;
    u16* Wql = (u16*)(p + o); o += SZ_W;
    u16* Wkh = (u16*)(p + o); o += SZ_W;
    u16* Wkl = (u16*)(p + o); o += SZ_W;
    u16* Wvh = (u16*)(p + o); o += SZ_W;
    u16* Woh = (u16*)(p + o); o += SZ_W;
    float* Yq = (float*)(p + o); size_t oYq = o; o += SZ_Y;
    float* Yk = (float*)(p + o); o += SZ_Y;
    float* Yv = (float*)(p + o); o += SZ_Y;
    u16* Qb = (u16*)(p + o); o += SZ_PK;
    u16* Kb = (u16*)(p + o); o += SZ_PK;
    u16* Vb = (u16*)(p + o); o += SZ_PK;
    float* q0s = (float*)(p + o); o += SZ_H0;
    float* k0s = (float*)(p + o); o += SZ_H0;
    float* Pp  = (float*)(p + o); o += (size_t)B_ * 8 * M_ * 4;
    int* evt   = (int*)(p + o);  o += (size_t)B_ * M_ * 4;
    // overlays (dead slots):
    float* S = (float*)(p + oYq);   // 32 MiB over Yq+Yk, used after LN
    u16* Ob  = Xhi;                 // 8 MiB over Xhi, used after all X-GEMMs

    cast_x_kernel<<<ROWS_ * D_ / (256 * 4), 256, 0, stream>>>(X, Xhi, Xlo);
    dim3 wgrid(32, 32), wblk(32, 32);
    cast_w_kernel<<<wgrid, wblk, 0, stream>>>(Wq, Wqh, Wql, 1);
    cast_w_kernel<<<wgrid, wblk, 0, stream>>>(Wk, Wkh, Wkl, 1);
    cast_w_kernel<<<wgrid, wblk, 0, stream>>>(Wv, Wvh, nullptr, 0);
    cast_w_kernel<<<wgrid, wblk, 0, stream>>>(Wo, Woh, nullptr, 0);

    dim3 ggrid(D_ / 128, ROWS_ / 128);
    gemm_kernel<<<ggrid, 256, 0, stream>>>(Xhi, Xlo, Wqh, Wql, 1, Yq);
    gemm_kernel<<<ggrid, 256, 0, stream>>>(Xhi, Xlo, Wkh, Wkl, 1, Yk);
    gemm_kernel<<<ggrid, 256, 0, stream>>>(Xhi, nullptr, Wvh, nullptr, 0, Yv);

    lnpack_kernel<<<ROWS_, 256, 0, stream>>>(Yq, gq, bq, Qb, q0s, 1);
    lnpack_kernel<<<ROWS_, 256, 0, stream>>>(Yk, gk, bk, Kb, k0s, 1);
    lnpack_kernel<<<ROWS_, 256, 0, stream>>>(Yv, nullptr, nullptr, Vb, nullptr, 0);

    s_kernel<<<dim3(M_ / 16, N_ / 16, B_), dim3(16, 16), 0, stream>>>(q0s, k0s, S);
    p_kernel<<<dim3(M_ / 256, 8, B_), 256, 0, stream>>>(S, Pp);
    evict_kernel<<<B_, 64, 0, stream>>>(S, Pp, evt);

    flash_kernel<<<dim3(N_ / 64, B_ * H_), 256, 0, stream>>>(Qb, Kb, Vb, evt, Ob);
    gemm_kernel<<<ggrid, 256, 0, stream>>>(Ob, nullptr, Woh, nullptr, 0, (float*)d_out);
}

// Round 9
// 916.887 us; speedup vs baseline: 1.5177x; 1.2875x over previous
//
// MultiheadSelectiveAttentionWithTokenPruning — MI355X round 8 (= round 7 resubmit; infra failure, no data)
//
// Pipeline (all on `stream`, graph-capture safe, no statics):
//  1  cast_x      : X fp32 -> Xhi/Xlo bf16 (split for bf16x3 GEMM)
//  2  cast_w x4   : W fp32 -> W^T bf16 (hi[+lo for Wq/Wk])
//  3  gemm split  : Yq = X@Wq  (hi*hi + hi*lo + lo*hi)  ~fp32 accuracy
//  4  gemm split  : Yk = X@Wk
//  5  gemm        : Yv = X@Wv  (plain bf16)
//  6  lnpack      : LN(Yq) -> Qb bf16 + q0s fp32 (head-0 selection)
//  7  lnpack      : LN(Yk) -> Kb + k0s
//  8  lnpack      : Yv -> Vb (cast only)
//  9  s_kernel    : S[b,n,m] = relu(q0s.k0s/8), causal/diag/col0-zeroed
// 10  p_kernel    : column partial sums of S rows 0..1023 (8 chunks)
// 11  evict       : 4-WAVE SPLIT (issue-bound diagnosis from r6 counters).
//                   r6: with barriers/LDS/shuffles/stores/compiler-waitcnt
//                   all eliminated, the single wave issues ~58% of its
//                   SIMD's cycles -> ~400+ VALU inst/iter through ONE SIMD
//                   issue port. Fix: split 2048 slots over 4 waves (8
//                   slots/lane), ~115 VALU/iter/wave on 4 SIMDs in parallel.
//                   Cross-wave winner exchange: lane-63 ds_write of packed
//                   (v,lo=2048-m) -> lgkmcnt(0) + RAW s_barrier (not
//                   __syncthreads: that emits vmcnt(0) and would drain the
//                   asm load pipeline) -> broadcast ds_read of 4 pairs ->
//                   3 signed-i64 compares in all lanes -> uniform lostar;
//                   poison/evti = branch-free v_cmp_eq/cndmask.
//                   Double-buffered pair slots (parity=step&1): one barrier
//                   per step, WAR-safe (reads consumed before next barrier).
//                   Masking/template<NC> deleted — provably unnecessary:
//                   S is strictly causal so tokens m>i have cum exactly +0.0
//                   and larger index than any active token -> can never win
//                   the (value desc, m asc) argmax. Bit-identical schedule.
//                   Retained from r4-r6: inline-asm global_load_dwordx4
//                   banks with counted s_waitcnt vmcnt(6) (2 loads/bank,
//                   4 banks in flight), register evti, single end-of-kernel
//                   store pass.
// 12  flash       : all 16 heads, online softmax, mask = causal && n<evt[m]
// 13  gemm        : out = Ob @ Wo -> d_out fp32
//
// ws overlays: Ob reuses Xhi slot (dead after step 5); S reuses Yq+Yk slots
// (dead after steps 6/7). Peak ws ~107.1 MB.

#include <hip/hip_runtime.h>

#define B_    2
#define N_    2048
#define D_    1024
#define H_    16
#define DH_   64
#define M_    2048
#define ROWS_ 4096
#define BUD_  1024

typedef unsigned short u16;
typedef unsigned int   u32;
typedef unsigned long long u64;
typedef __attribute__((ext_vector_type(8))) short short8;
typedef __attribute__((ext_vector_type(4))) float floatx4;

__device__ __forceinline__ u16 f2b(float f) {
    u32 u = __float_as_uint(f);
    return (u16)((u + 0x7FFFu + ((u >> 16) & 1u)) >> 16);   // RNE
}
__device__ __forceinline__ float b2f(u16 h) {
    return __uint_as_float(((u32)h) << 16);
}

// ---------------------------------------------------------------- cast X
__global__ __launch_bounds__(256) void cast_x_kernel(
    const float* __restrict__ X, u16* __restrict__ Xhi, u16* __restrict__ Xlo)
{
    int idx = (blockIdx.x * 256 + threadIdx.x) * 4;
    float4 v = *(const float4*)&X[idx];
    u16 h0 = f2b(v.x), h1 = f2b(v.y), h2 = f2b(v.z), h3 = f2b(v.w);
    ushort4 hv; hv.x = h0; hv.y = h1; hv.z = h2; hv.w = h3;
    *(ushort4*)&Xhi[idx] = hv;
    ushort4 lv;
    lv.x = f2b(v.x - b2f(h0)); lv.y = f2b(v.y - b2f(h1));
    lv.z = f2b(v.z - b2f(h2)); lv.w = f2b(v.w - b2f(h3));
    *(ushort4*)&Xlo[idx] = lv;
}

// ------------------------------------------------- cast + transpose W
__global__ __launch_bounds__(1024) void cast_w_kernel(
    const float* __restrict__ W, u16* __restrict__ Whi, u16* __restrict__ Wlo,
    int do_lo)
{
    __shared__ float tile[32][33];
    int tx = threadIdx.x, ty = threadIdx.y;
    int x = blockIdx.x * 32 + tx, y = blockIdx.y * 32 + ty;
    tile[ty][tx] = W[(size_t)y * D_ + x];
    __syncthreads();
    float v = tile[tx][ty];
    int n = blockIdx.x * 32 + ty, k = blockIdx.y * 32 + tx;
    u16 h = f2b(v);
    Whi[(size_t)n * D_ + k] = h;
    if (do_lo) Wlo[(size_t)n * D_ + k] = f2b(v - b2f(h));
}

// ------------------------------------------------------------- GEMM
// C[4096][1024] = A[4096][1024] @ Bt^T   (Bt stored [n][k])
// mode 1: C = Ah*Bh + Ah*Bl + Al*Bh  (bf16x3 split, ~fp32 precision)
__global__ __launch_bounds__(256) void gemm_kernel(
    const u16* __restrict__ Ah, const u16* __restrict__ Al,
    const u16* __restrict__ Bh, const u16* __restrict__ Bl,
    int mode, float* __restrict__ C)
{
    __shared__ __align__(16) u16 sAh[128 * 32];
    __shared__ __align__(16) u16 sBh[128 * 32];
    __shared__ __align__(16) u16 sAl[128 * 32];
    __shared__ __align__(16) u16 sBl[128 * 32];
    int tid = threadIdx.x;
    int lane = tid & 63, wv = tid >> 6;
    int wr = wv >> 1, wc = wv & 1;
    int quad = lane >> 4, l16 = lane & 15;
    int m0 = blockIdx.y * 128, n0 = blockIdx.x * 128;

    floatx4 acc[4][4];
    floatx4 zero = {0.f, 0.f, 0.f, 0.f};
#pragma unroll
    for (int i = 0; i < 4; ++i)
#pragma unroll
        for (int j = 0; j < 4; ++j) acc[i][j] = zero;

    for (int k0 = 0; k0 < 1024; k0 += 32) {
#pragma unroll
        for (int it = 0; it < 2; ++it) {
            int e = (tid + it * 256) * 8;
            int r = e >> 5, c = e & 31;
            *(uint4*)&sAh[e] = *(const uint4*)&Ah[(size_t)(m0 + r) * 1024 + k0 + c];
            *(uint4*)&sBh[e] = *(const uint4*)&Bh[(size_t)(n0 + r) * 1024 + k0 + c];
            if (mode) {
                *(uint4*)&sAl[e] = *(const uint4*)&Al[(size_t)(m0 + r) * 1024 + k0 + c];
                *(uint4*)&sBl[e] = *(const uint4*)&Bl[(size_t)(n0 + r) * 1024 + k0 + c];
            }
        }
        __syncthreads();
        short8 ah[4], al[4], bh[4], bl[4];
#pragma unroll
        for (int x = 0; x < 4; ++x) {
            int ra = (wr * 64 + x * 16 + l16) * 32 + quad * 8;
            int rb = (wc * 64 + x * 16 + l16) * 32 + quad * 8;
            ah[x] = *(const short8*)&sAh[ra];
            bh[x] = *(const short8*)&sBh[rb];
            if (mode) {
                al[x] = *(const short8*)&sAl[ra];
                bl[x] = *(const short8*)&sBl[rb];
            }
        }
#pragma unroll
        for (int mi = 0; mi < 4; ++mi)
#pragma unroll
            for (int ni = 0; ni < 4; ++ni) {
                acc[mi][ni] = __builtin_amdgcn_mfma_f32_16x16x32_bf16(
                    ah[mi], bh[ni], acc[mi][ni], 0, 0, 0);
                if (mode) {
                    acc[mi][ni] = __builtin_amdgcn_mfma_f32_16x16x32_bf16(
                        ah[mi], bl[ni], acc[mi][ni], 0, 0, 0);
                    acc[mi][ni] = __builtin_amdgcn_mfma_f32_16x16x32_bf16(
                        al[mi], bh[ni], acc[mi][ni], 0, 0, 0);
                }
            }
        __syncthreads();
    }
    // C/D layout: col = lane&15, row = (lane>>4)*4 + reg   [verified m89/m91]
#pragma unroll
    for (int mi = 0; mi < 4; ++mi)
#pragma unroll
        for (int ni = 0; ni < 4; ++ni)
#pragma unroll
            for (int r = 0; r < 4; ++r) {
                int row = m0 + wr * 64 + mi * 16 + quad * 4 + r;
                int col = n0 + wc * 64 + ni * 16 + l16;
                C[(size_t)row * 1024 + col] = acc[mi][ni][r];
            }
}

// ----------------------------------------------------- LayerNorm + pack
__global__ __launch_bounds__(256) void lnpack_kernel(
    const float* __restrict__ Y, const float* __restrict__ gamma,
    const float* __restrict__ beta, u16* __restrict__ Pk,
    float* __restrict__ head0, int do_ln)
{
    int r = blockIdx.x;
    int tid = threadIdx.x;
    float4 v = *(const float4*)&Y[(size_t)r * D_ + tid * 4];
    float mu = 0.f, rsig = 1.f;
    __shared__ float sS[4], sQ[4];
    if (do_ln) {
        float s = v.x + v.y + v.z + v.w;
        float q = v.x * v.x + v.y * v.y + v.z * v.z + v.w * v.w;
#pragma unroll
        for (int d = 1; d < 64; d <<= 1) { s += __shfl_xor(s, d); q += __shfl_xor(q, d); }
        if ((tid & 63) == 0) { sS[tid >> 6] = s; sQ[tid >> 6] = q; }
        __syncthreads();
        s = sS[0] + sS[1] + sS[2] + sS[3];
        q = sQ[0] + sQ[1] + sQ[2] + sQ[3];
        mu = s * (1.f / 1024.f);
        float var = q * (1.f / 1024.f) - mu * mu;
        rsig = rsqrtf(var + 1e-5f);
    }
    int b = r >> 11, n = r & 2047;
    float xs[4] = {v.x, v.y, v.z, v.w};
#pragma unroll
    for (int j = 0; j < 4; ++j) {
        int c = tid * 4 + j;
        float val = do_ln ? ((xs[j] - mu) * rsig * gamma[c] + beta[c]) : xs[j];
        int h = c >> 6, dh = c & 63;
        Pk[(((size_t)b * H_ + h) * N_ + n) * DH_ + dh] = f2b(val);
        if (head0 && c < 64) head0[(size_t)r * 64 + c] = val;
    }
}

// -------------------------------------------- head-0 selection scores S
__global__ void s_kernel(const float* __restrict__ q0,
                         const float* __restrict__ k0, float* __restrict__ S)
{
    int b = blockIdx.z;
    int n0 = blockIdx.y * 16, m0 = blockIdx.x * 16;
    int tx = threadIdx.x, ty = threadIdx.y;
    int n = n0 + ty, m = m0 + tx;
    float* out = S + ((size_t)b * N_ + n) * M_ + m;
    if (m0 > n0 + 15) { *out = 0.f; return; }   // fully above diagonal
    __shared__ float sq[16][65], sk[16][65];
    int tid = ty * 16 + tx;
    {
        int rr = tid >> 4, cc = (tid & 15) * 4;
        float4 qa = *(const float4*)&q0[((size_t)b * N_ + n0 + rr) * 64 + cc];
        sq[rr][cc] = qa.x; sq[rr][cc + 1] = qa.y; sq[rr][cc + 2] = qa.z; sq[rr][cc + 3] = qa.w;
        float4 ka = *(const float4*)&k0[((size_t)b * N_ + m0 + rr) * 64 + cc];
        sk[rr][cc] = ka.x; sk[rr][cc + 1] = ka.y; sk[rr][cc + 2] = ka.z; sk[rr][cc + 3] = ka.w;
    }
    __syncthreads();
    float acc = 0.f;
#pragma unroll 8
    for (int d = 0; d < 64; ++d) acc += sq[ty][d] * sk[tx][d];
    // causal (m>n) -> relu(-inf)=0 ; diagonal m==n -> 0 ; col 0 -> 0
    float val;
    if (m < n && m != 0) val = fmaxf(acc * 0.125f, 0.f); else val = 0.f;
    *out = val;
}

// -------------------------------- partial column sums of S rows 0..1023
__global__ __launch_bounds__(256) void p_kernel(const float* __restrict__ S,
                                                float* __restrict__ P)
{
    int b = blockIdx.z, c = blockIdx.y;
    int m = blockIdx.x * 256 + threadIdx.x;
    const float* base = S + ((size_t)b * N_ + c * 128) * M_ + m;
    float s = 0.f;
    for (int j = 0; j < 128; ++j) s += base[(size_t)j * M_];
    P[((size_t)b * 8 + c) * M_ + m] = s;
}

// --------------------------------------------- sequential greedy eviction
// 4 waves (256 thr) per batch. Wave w owns m in [512w, 512w+512): lane t,
// chunk c in {0,1}, elem e: m = 512w + 256c + 4t + e. cum in registers.
//   - evicted slot -> cum = -inf, evti = i (branch-free cndmask on
//     lov == lostar; lostar uniform from cross-wave combine).
//   - no activity masking needed: causal S => tokens m>i have cum == +0.0
//     exactly and larger m than any active token -> can never win the
//     (value desc, m asc) lexicographic argmax.
//   - per-wave: (v,lo) tournament (strict >, ascending order = first-max)
//     + 6 DPP stages (signed-i64 packed compare) -> lane 63.
//   - cross-wave: lane63 ds_write pair -> lgkmcnt(0) -> raw s_barrier ->
//     broadcast ds_read 4 pairs -> 3 i64 compares in all lanes.
//     Double-buffered pair slots (parity=step&1), one barrier/step.
//   - S-row banks: inline-asm global_load_dwordx4, 2 loads/bank, 4 banks
//     in flight; s_waitcnt vmcnt(6) + sched_barrier(0) before consume.

// tournament combine: take (vb,lb) only if strictly greater value.
__device__ __forceinline__ void vsel(float& va, u32& la, float vb, u32 lb) {
    bool tk = vb > va;
    va = tk ? vb : va;
    la = tk ? lb : la;
}

// DPP packed max stage (ctrl/rmask identical to round-3..6 scheme).
template<int CTRL, int RMASK>
__device__ __forceinline__ void dpp_max_pack(float& v, u32& lo) {
    int hi = __float_as_int(v);
    int hi_o = __builtin_amdgcn_update_dpp(hi, hi, CTRL, RMASK, 0xF, false);
    int lo_o = __builtin_amdgcn_update_dpp((int)lo, (int)lo, CTRL, RMASK, 0xF, false);
    long long a = (long long)((((u64)(u32)hi) << 32) | lo);
    long long b = (long long)((((u64)(u32)hi_o) << 32) | (u32)lo_o);
    bool tk = b > a;
    v = tk ? __int_as_float(hi_o) : v;
    lo = tk ? (u32)lo_o : lo;
}

__device__ __forceinline__ void wave_argmax_to63(float& v, u32& lo) {
    dpp_max_pack<0x121, 0xF>(v, lo);   // row_ror:1
    dpp_max_pack<0x122, 0xF>(v, lo);   // row_ror:2
    dpp_max_pack<0x124, 0xF>(v, lo);   // row_ror:4
    dpp_max_pack<0x128, 0xF>(v, lo);   // row_ror:8
    dpp_max_pack<0x142, 0xA>(v, lo);   // row_bcast15 -> rows 1,3
    dpp_max_pack<0x143, 0xC>(v, lo);   // row_bcast31 -> rows 2,3
}

// inline-asm 16B load: dst <- Sb[voff + imm]  (SGPR base + 32b voffset)
#define GLOAD(dst, voff, ptr, imm)                                    \
    asm volatile("global_load_dwordx4 %0, %1, %2 offset:" #imm        \
                 : "=v"(dst) : "v"(voff), "s"(ptr) : "memory")

// issue one bank: this wave's 2 float4 of row `row` (cols 512w+4t, +256)
#define ISSUE2(bank, row)                                             \
    {                                                                 \
        u32 r_ = (u32)((row) < 2047 ? (row) : 2047);                  \
        u32 vo = wbyte + r_ * 8192u;                                  \
        GLOAD(bank[0], vo, Sb, 0);                                    \
        GLOAD(bank[1], vo, Sb, 1024);                                 \
    }

#define VWAIT6()                                                      \
    do { asm volatile("s_waitcnt vmcnt(6)" ::: "memory");             \
         __builtin_amdgcn_sched_barrier(0); } while (0)
#define VWAIT0()                                                      \
    do { asm volatile("s_waitcnt vmcnt(0)" ::: "memory");             \
         __builtin_amdgcn_sched_barrier(0); } while (0)

__device__ __forceinline__ void evict_step4(
    int i, int t, int w, int par,
    const u32 (&lov)[2][4], float (&cum)[2][4], int (&evti)[2][4],
    const floatx4 (&bank)[2], uint2 (*spair)[4])
{
    const float NEGINF = __uint_as_float(0xFF800000u);
    // ---- per-wave (v, lo) tournament: ascending-index order, strict >
    float v0 = cum[0][0]; u32 l0 = lov[0][0];
    vsel(v0, l0, cum[0][1], lov[0][1]);
    float v1 = cum[0][2]; u32 l1 = lov[0][2];
    vsel(v1, l1, cum[0][3], lov[0][3]);
    vsel(v0, l0, v1, l1);
    float v2 = cum[1][0]; u32 l2 = lov[1][0];
    vsel(v2, l2, cum[1][1], lov[1][1]);
    float v3 = cum[1][2]; u32 l3 = lov[1][2];
    vsel(v3, l3, cum[1][3], lov[1][3]);
    vsel(v2, l2, v3, l3);
    vsel(v0, l0, v2, l2);
    wave_argmax_to63(v0, l0);
    // ---- cross-wave exchange (double-buffered by parity)
    if (t == 63) spair[par][w] = make_uint2(l0, (u32)__float_as_int(v0));
    asm volatile("s_waitcnt lgkmcnt(0)" ::: "memory");
    __builtin_amdgcn_sched_barrier(0);
    __builtin_amdgcn_s_barrier();      // raw barrier: no vmcnt drain
    __builtin_amdgcn_sched_barrier(0);
    uint2 q0 = spair[par][0], q1 = spair[par][1];
    uint2 q2 = spair[par][2], q3 = spair[par][3];
    long long k0 = (long long)((((u64)q0.y) << 32) | q0.x);
    long long k1 = (long long)((((u64)q1.y) << 32) | q1.x);
    long long k2 = (long long)((((u64)q2.y) << 32) | q2.x);
    long long k3 = (long long)((((u64)q3.y) << 32) | q3.x);
    long long ba = k0 > k1 ? k0 : k1;
    long long bb = k2 > k3 ? k2 : k3;
    long long bst = ba > bb ? ba : bb;   // packs unique (lo distinct)
    const u32 lostar = (u32)(bst & 0xFFFFFFFFll);
    // ---- update: Fm[i] -> Fm[i+1]
#pragma unroll
    for (int c = 0; c < 2; ++c) {
        cum[c][0] += bank[c][0]; cum[c][1] += bank[c][1];
        cum[c][2] += bank[c][2]; cum[c][3] += bank[c][3];
    }
    // ---- poison + record: branch-free, lostar uniform
#pragma unroll
    for (int c = 0; c < 2; ++c)
#pragma unroll
        for (int e = 0; e < 4; ++e) {
            bool hit = (lov[c][e] == lostar);
            cum[c][e] = hit ? NEGINF : cum[c][e];
            evti[c][e] = hit ? i : evti[c][e];
        }
}

__global__ __launch_bounds__(256) void evict_kernel(
    const float* __restrict__ S, const float* __restrict__ P,
    int* __restrict__ evt)
{
    int b = blockIdx.x;
    int tid = threadIdx.x;
    int w = tid >> 6, t = tid & 63;            // 4 waves
    const float* Sb = S + (size_t)b * N_ * M_;
    int* evtb = evt + b * M_;
    const int mbase = 512 * w + 4 * t;
    const u32 wbyte = (u32)(2048 * w + 16 * t);  // byte offset within a row
    __shared__ uint2 spair[2][4];               // [parity][wave]
    u32 lov[2][4];
    int evti[2][4];
#pragma unroll
    for (int c = 0; c < 2; ++c)
#pragma unroll
        for (int e = 0; e < 4; ++e) {
            lov[c][e] = (u32)(2048 - (mbase + 256 * c + e));
            evti[c][e] = 0x3FFFFFFF;
        }
    // initial cum = column sums of the 8 partial chunks (same per-slot add
    // order as rounds 0-6 -> bitwise identical trajectories)
    float cum[2][4];
#pragma unroll
    for (int c = 0; c < 2; ++c) {
        float ax = 0.f, ay = 0.f, az = 0.f, aw = 0.f;
#pragma unroll
        for (int cc = 0; cc < 8; ++cc) {
            floatx4 pv = *(const floatx4*)&P[((size_t)b * 8 + cc) * M_ + mbase + 256 * c];
            ax += pv[0]; ay += pv[1]; az += pv[2]; aw += pv[3];
        }
        cum[c][0] = ax; cum[c][1] = ay; cum[c][2] = az; cum[c][3] = aw;
    }
    // fence: drain compiler-tracked loads so asm vmcnt counting is exact
    VWAIT0();
    floatx4 bA[2], bB[2], bC[2], bD[2];
    ISSUE2(bA, 1024)
    ISSUE2(bB, 1025)
    ISSUE2(bC, 1026)
    ISSUE2(bD, 1027)
#pragma unroll 1
    for (int ip = 1024; ip < 2048; ip += 4) {
        VWAIT6();
        evict_step4(ip + 0, t, w, 0, lov, cum, evti, bA, spair);
        ISSUE2(bA, ip + 4)
        VWAIT6();
        evict_step4(ip + 1, t, w, 1, lov, cum, evti, bB, spair);
        ISSUE2(bB, ip + 5)
        VWAIT6();
        evict_step4(ip + 2, t, w, 0, lov, cum, evti, bC, spair);
        ISSUE2(bC, ip + 6)
        VWAIT6();
        evict_step4(ip + 3, t, w, 1, lov, cum, evti, bD, spair);
        ISSUE2(bD, ip + 7)
    }
    VWAIT0();   // drain leftover bank loads before reusing the vmem queue
    // single coalesced write pass (the only global stores in this kernel)
#pragma unroll
    for (int c = 0; c < 2; ++c) {
        int4 o; o.x = evti[c][0]; o.y = evti[c][1];
        o.z = evti[c][2]; o.w = evti[c][3];
        *(int4*)&evtb[mbase + 256 * c] = o;
    }
}

// ------------------------------------------------------ flash attention
__global__ __launch_bounds__(256) void flash_kernel(
    const u16* __restrict__ Qb, const u16* __restrict__ Kb,
    const u16* __restrict__ Vb, const int* __restrict__ evt,
    u16* __restrict__ Ob)
{
    int bh = blockIdx.y;
    int b = bh >> 4, h = bh & 15;
    int q0 = blockIdx.x * 64;
    int tid = threadIdx.x, lane = tid & 63, w = tid >> 6;
    int quad = lane >> 4, l16 = lane & 15;
    const u16* Qh = Qb + (size_t)bh * N_ * DH_;
    const u16* Kh = Kb + (size_t)bh * N_ * DH_;
    const u16* Vh = Vb + (size_t)bh * N_ * DH_;
    __shared__ __align__(16) u16 sK[64 * 64];
    __shared__ __align__(16) u16 sV[64 * 64];     // transposed [dh][key]
    __shared__ __align__(16) u16 sP[4][16 * 64];  // wave-private P
    __shared__ int sevt[64];

    // Q A-frags in registers: A[m=lane&15][k=quad*8+j]
    short8 aq0 = *(const short8*)&Qh[(size_t)(q0 + w * 16 + l16) * 64 + quad * 8];
    short8 aq1 = *(const short8*)&Qh[(size_t)(q0 + w * 16 + l16) * 64 + quad * 8 + 32];

    floatx4 zero = {0.f, 0.f, 0.f, 0.f};
    floatx4 accO[4];
#pragma unroll
    for (int d = 0; d < 4; ++d) accO[d] = zero;
    float m_i[4] = {-1e30f, -1e30f, -1e30f, -1e30f};
    float l_i[4] = {0.f, 0.f, 0.f, 0.f};

    int ktiles = blockIdx.x + 1;
    for (int kt = 0; kt < ktiles; ++kt) {
        int k0 = kt * 64;
#pragma unroll
        for (int it = 0; it < 2; ++it) {
            int e = (tid + it * 256) * 8;
            int r = e >> 6, c = e & 63;
            *(uint4*)&sK[e] = *(const uint4*)&Kh[(size_t)(k0 + r) * 64 + c];
            uint4 vv = *(const uint4*)&Vh[(size_t)(k0 + r) * 64 + c];
            sV[(c + 0) * 64 + r] = (u16)(vv.x & 0xFFFF);
            sV[(c + 1) * 64 + r] = (u16)(vv.x >> 16);
            sV[(c + 2) * 64 + r] = (u16)(vv.y & 0xFFFF);
            sV[(c + 3) * 64 + r] = (u16)(vv.y >> 16);
            sV[(c + 4) * 64 + r] = (u16)(vv.z & 0xFFFF);
            sV[(c + 5) * 64 + r] = (u16)(vv.z >> 16);
            sV[(c + 6) * 64 + r] = (u16)(vv.w & 0xFFFF);
            sV[(c + 7) * 64 + r] = (u16)(vv.w >> 16);
        }
        if (tid < 64) sevt[tid] = evt[b * M_ + k0 + tid];
        __syncthreads();

        floatx4 lg[4];
        int nbase = q0 + w * 16 + quad * 4;
#pragma unroll
        for (int s = 0; s < 4; ++s) {
            floatx4 sc = zero;
            short8 bk0 = *(const short8*)&sK[(s * 16 + l16) * 64 + quad * 8];
            short8 bk1 = *(const short8*)&sK[(s * 16 + l16) * 64 + quad * 8 + 32];
            sc = __builtin_amdgcn_mfma_f32_16x16x32_bf16(aq0, bk0, sc, 0, 0, 0);
            sc = __builtin_amdgcn_mfma_f32_16x16x32_bf16(aq1, bk1, sc, 0, 0, 0);
            int m = k0 + s * 16 + l16;
            int ev = sevt[s * 16 + l16];
#pragma unroll
            for (int r = 0; r < 4; ++r) {
                int n = nbase + r;
                bool keep = (m <= n) && (n < ev);
                lg[s][r] = keep ? sc[r] * 0.125f : -1e30f;
            }
        }
        float mnew[4], scale[4], rs[4];
#pragma unroll
        for (int r = 0; r < 4; ++r) {
            float mx = fmaxf(fmaxf(lg[0][r], lg[1][r]), fmaxf(lg[2][r], lg[3][r]));
#pragma unroll
            for (int d = 1; d < 16; d <<= 1) mx = fmaxf(mx, __shfl_xor(mx, d));
            mnew[r] = fmaxf(m_i[r], mx);
            scale[r] = __expf(m_i[r] - mnew[r]);
            m_i[r] = mnew[r];
            rs[r] = 0.f;
        }
#pragma unroll
        for (int s = 0; s < 4; ++s)
#pragma unroll
            for (int r = 0; r < 4; ++r) {
                float p = __expf(lg[s][r] - mnew[r]);
                rs[r] += p;
                sP[w][(quad * 4 + r) * 64 + s * 16 + l16] = f2b(p);
            }
#pragma unroll
        for (int r = 0; r < 4; ++r) {
            float t_ = rs[r];
#pragma unroll
            for (int d = 1; d < 16; d <<= 1) t_ += __shfl_xor(t_, d);
            l_i[r] = l_i[r] * scale[r] + t_;
        }
#pragma unroll
        for (int dd = 0; dd < 4; ++dd) {
            accO[dd][0] *= scale[0]; accO[dd][1] *= scale[1];
            accO[dd][2] *= scale[2]; accO[dd][3] *= scale[3];
        }
        // P: C-layout -> A-layout via wave-private LDS round-trip
        short8 ap0 = *(const short8*)&sP[w][l16 * 64 + quad * 8];
        short8 ap1 = *(const short8*)&sP[w][l16 * 64 + quad * 8 + 32];
#pragma unroll
        for (int dd = 0; dd < 4; ++dd) {
            short8 bv0 = *(const short8*)&sV[(dd * 16 + l16) * 64 + quad * 8];
            short8 bv1 = *(const short8*)&sV[(dd * 16 + l16) * 64 + quad * 8 + 32];
            accO[dd] = __builtin_amdgcn_mfma_f32_16x16x32_bf16(ap0, bv0, accO[dd], 0, 0, 0);
            accO[dd] = __builtin_amdgcn_mfma_f32_16x16x32_bf16(ap1, bv1, accO[dd], 0, 0, 0);
        }
        __syncthreads();
    }
#pragma unroll
    for (int dd = 0; dd < 4; ++dd)
#pragma unroll
        for (int r = 0; r < 4; ++r) {
            int n = q0 + w * 16 + quad * 4 + r;
            int col = h * 64 + dd * 16 + l16;
            Ob[((size_t)b * N_ + n) * D_ + col] = f2b(accO[dd][r] / l_i[r]);
        }
}

// ---------------------------------------------------------------- launch
extern "C" void kernel_launch(void* const* d_in, const int* in_sizes, int n_in,
                              void* d_out, int out_size, void* d_ws, size_t ws_size,
                              hipStream_t stream)
{
    (void)in_sizes; (void)n_in; (void)out_size; (void)ws_size;
    const float* X  = (const float*)d_in[0];
    const float* Wq = (const float*)d_in[1];
    const float* Wk = (const float*)d_in[2];
    const float* Wv = (const float*)d_in[3];
    const float* Wo = (const float*)d_in[4];
    const float* gq = (const float*)d_in[5];
    const float* bq = (const float*)d_in[6];
    const float* gk = (const float*)d_in[7];
    const float* bk = (const float*)d_in[8];
    // d_in[9] cache_k, d_in[10] cache_v, d_in[11] start_pos: start_pos==0 here.

    char* p = (char*)d_ws;
    const size_t SZ_XH = (size_t)ROWS_ * D_ * 2;   // 8 MiB bf16
    const size_t SZ_W  = (size_t)D_ * D_ * 2;      // 2 MiB bf16
    const size_t SZ_Y  = (size_t)ROWS_ * D_ * 4;   // 16 MiB fp32
    const size_t SZ_PK = (size_t)ROWS_ * D_ * 2;   // 8 MiB bf16
    const size_t SZ_H0 = (size_t)ROWS_ * 64 * 4;   // 1 MiB fp32

    size_t o = 0;
    u16* Xhi = (u16*)(p + o); o += SZ_XH;
    u16* Xlo = (u16*)(p + o); o += SZ_XH;
    u16* Wqh = (u16*)(p + o); o += SZ_W;
    u16* Wql = (u16*)(p + o); o += SZ_W;
    u16* Wkh = (u16*)(p + o); o += SZ_W;
    u16* Wkl = (u16*)(p + o); o += SZ_W;
    u16* Wvh = (u16*)(p + o); o += SZ_W;
    u16* Woh = (u16*)(p + o); o += SZ_W;
    float* Yq = (float*)(p + o); size_t oYq = o; o += SZ_Y;
    float* Yk = (float*)(p + o); o += SZ_Y;
    float* Yv = (float*)(p + o); o += SZ_Y;
    u16* Qb = (u16*)(p + o); o += SZ_PK;
    u16* Kb = (u16*)(p + o); o += SZ_PK;
    u16* Vb = (u16*)(p + o); o += SZ_PK;
    float* q0s = (float*)(p + o); o += SZ_H0;
    float* k0s = (float*)(p + o); o += SZ_H0;
    float* Pp  = (float*)(p + o); o += (size_t)B_ * 8 * M_ * 4;
    int* evt   = (int*)(p + o);  o += (size_t)B_ * M_ * 4;
    // overlays (dead slots):
    float* S = (float*)(p + oYq);   // 32 MiB over Yq+Yk, used after LN
    u16* Ob  = Xhi;                 // 8 MiB over Xhi, used after all X-GEMMs

    cast_x_kernel<<<ROWS_ * D_ / (256 * 4), 256, 0, stream>>>(X, Xhi, Xlo);
    dim3 wgrid(32, 32), wblk(32, 32);
    cast_w_kernel<<<wgrid, wblk, 0, stream>>>(Wq, Wqh, Wql, 1);
    cast_w_kernel<<<wgrid, wblk, 0, stream>>>(Wk, Wkh, Wkl, 1);
    cast_w_kernel<<<wgrid, wblk, 0, stream>>>(Wv, Wvh, nullptr, 0);
    cast_w_kernel<<<wgrid, wblk, 0, stream>>>(Wo, Woh, nullptr, 0);

    dim3 ggrid(D_ / 128, ROWS_ / 128);
    gemm_kernel<<<ggrid, 256, 0, stream>>>(Xhi, Xlo, Wqh, Wql, 1, Yq);
    gemm_kernel<<<ggrid, 256, 0, stream>>>(Xhi, Xlo, Wkh, Wkl, 1, Yk);
    gemm_kernel<<<ggrid, 256, 0, stream>>>(Xhi, nullptr, Wvh, nullptr, 0, Yv);

    lnpack_kernel<<<ROWS_, 256, 0, stream>>>(Yq, gq, bq, Qb, q0s, 1);
    lnpack_kernel<<<ROWS_, 256, 0, stream>>>(Yk, gk, bk, Kb, k0s, 1);
    lnpack_kernel<<<ROWS_, 256, 0, stream>>>(Yv, nullptr, nullptr, Vb, nullptr, 0);

    s_kernel<<<dim3(M_ / 16, N_ / 16, B_), dim3(16, 16), 0, stream>>>(q0s, k0s, S);
    p_kernel<<<dim3(M_ / 256, 8, B_), 256, 0, stream>>>(S, Pp);
    evict_kernel<<<B_, 256, 0, stream>>>(S, Pp, evt);

    flash_kernel<<<dim3(N_ / 64, B_ * H_), 256, 0, stream>>>(Qb, Kb, Vb, evt, Ob);
    gemm_kernel<<<ggrid, 256, 0, stream>>>(Ob, nullptr, Woh, nullptr, 0, (float*)d_out);
}

// Round 10
// 844.551 us; speedup vs baseline: 1.6477x; 1.0857x over previous
//
// MultiheadSelectiveAttentionWithTokenPruning — MI355X round 10
//
// Pipeline (all on `stream`, graph-capture safe, no statics):
//  1  cast_x      : X fp32 -> Xhi/Xlo bf16 (split for bf16x3 GEMM)
//  2  cast_w x4   : W fp32 -> W^T bf16 (hi[+lo for Wq/Wk])
//  3  gemm split  : Yq = X@Wq  (hi*hi + hi*lo + lo*hi)  ~fp32 accuracy
//  4  gemm split  : Yk = X@Wk
//  5  gemm        : Yv = X@Wv  (plain bf16)
//  6  lnpack      : LN(Yq) -> Qb bf16 + q0s fp32 (head-0 selection)
//  7  lnpack      : LN(Yk) -> Kb + k0s
//  8  lnpack      : Yv -> Vb (cast only)
//  9  s_kernel    : S[b,n,m] = relu(q0s.k0s/8), causal/diag/col0-zeroed
// 10  p_kernel    : column partial sums of S rows 0..1023 (8 chunks)
// 11  FUSED       : evict (2 blocks, r9-proven 4-wave code, byte-identical)
//                   ∥ flash part 1 (512 blocks, q-tiles j=0..15).
//                   Queries n<1024 NEVER need evt: all evictions occur at
//                   steps i>=1024, so n<evt[m] is always true -> flash1's
//                   mask is pure causal. 26% of flash work overlaps the
//                   352 µs serial evict on otherwise-idle CUs. No
//                   inter-block dependency -> deadlock-free under any
//                   dispatch order (worst case = serial = round 9).
// 12  flash2      : q-tiles j=16..31 (needs evt), after the fused launch.
// 13  gemm        : out = Ob @ Wo -> d_out fp32
//
// ws overlays: Ob reuses Xhi slot (dead after step 5); S reuses Yq+Yk slots
// (dead after steps 6/7). Peak ws ~107.1 MB.

#include <hip/hip_runtime.h>

#define B_    2
#define N_    2048
#define D_    1024
#define H_    16
#define DH_   64
#define M_    2048
#define ROWS_ 4096
#define BUD_  1024

typedef unsigned short u16;
typedef unsigned int   u32;
typedef unsigned long long u64;
typedef __attribute__((ext_vector_type(8))) short short8;
typedef __attribute__((ext_vector_type(4))) float floatx4;

__device__ __forceinline__ u16 f2b(float f) {
    u32 u = __float_as_uint(f);
    return (u16)((u + 0x7FFFu + ((u >> 16) & 1u)) >> 16);   // RNE
}
__device__ __forceinline__ float b2f(u16 h) {
    return __uint_as_float(((u32)h) << 16);
}

// ---------------------------------------------------------------- cast X
__global__ __launch_bounds__(256) void cast_x_kernel(
    const float* __restrict__ X, u16* __restrict__ Xhi, u16* __restrict__ Xlo)
{
    int idx = (blockIdx.x * 256 + threadIdx.x) * 4;
    float4 v = *(const float4*)&X[idx];
    u16 h0 = f2b(v.x), h1 = f2b(v.y), h2 = f2b(v.z), h3 = f2b(v.w);
    ushort4 hv; hv.x = h0; hv.y = h1; hv.z = h2; hv.w = h3;
    *(ushort4*)&Xhi[idx] = hv;
    ushort4 lv;
    lv.x = f2b(v.x - b2f(h0)); lv.y = f2b(v.y - b2f(h1));
    lv.z = f2b(v.z - b2f(h2)); lv.w = f2b(v.w - b2f(h3));
    *(ushort4*)&Xlo[idx] = lv;
}

// ------------------------------------------------- cast + transpose W
__global__ __launch_bounds__(1024) void cast_w_kernel(
    const float* __restrict__ W, u16* __restrict__ Whi, u16* __restrict__ Wlo,
    int do_lo)
{
    __shared__ float tile[32][33];
    int tx = threadIdx.x, ty = threadIdx.y;
    int x = blockIdx.x * 32 + tx, y = blockIdx.y * 32 + ty;
    tile[ty][tx] = W[(size_t)y * D_ + x];
    __syncthreads();
    float v = tile[tx][ty];
    int n = blockIdx.x * 32 + ty, k = blockIdx.y * 32 + tx;
    u16 h = f2b(v);
    Whi[(size_t)n * D_ + k] = h;
    if (do_lo) Wlo[(size_t)n * D_ + k] = f2b(v - b2f(h));
}

// ------------------------------------------------------------- GEMM
// C[4096][1024] = A[4096][1024] @ Bt^T   (Bt stored [n][k])
// mode 1: C = Ah*Bh + Ah*Bl + Al*Bh  (bf16x3 split, ~fp32 precision)
__global__ __launch_bounds__(256) void gemm_kernel(
    const u16* __restrict__ Ah, const u16* __restrict__ Al,
    const u16* __restrict__ Bh, const u16* __restrict__ Bl,
    int mode, float* __restrict__ C)
{
    __shared__ __align__(16) u16 sAh[128 * 32];
    __shared__ __align__(16) u16 sBh[128 * 32];
    __shared__ __align__(16) u16 sAl[128 * 32];
    __shared__ __align__(16) u16 sBl[128 * 32];
    int tid = threadIdx.x;
    int lane = tid & 63, wv = tid >> 6;
    int wr = wv >> 1, wc = wv & 1;
    int quad = lane >> 4, l16 = lane & 15;
    int m0 = blockIdx.y * 128, n0 = blockIdx.x * 128;

    floatx4 acc[4][4];
    floatx4 zero = {0.f, 0.f, 0.f, 0.f};
#pragma unroll
    for (int i = 0; i < 4; ++i)
#pragma unroll
        for (int j = 0; j < 4; ++j) acc[i][j] = zero;

    for (int k0 = 0; k0 < 1024; k0 += 32) {
#pragma unroll
        for (int it = 0; it < 2; ++it) {
            int e = (tid + it * 256) * 8;
            int r = e >> 5, c = e & 31;
            *(uint4*)&sAh[e] = *(const uint4*)&Ah[(size_t)(m0 + r) * 1024 + k0 + c];
            *(uint4*)&sBh[e] = *(const uint4*)&Bh[(size_t)(n0 + r) * 1024 + k0 + c];
            if (mode) {
                *(uint4*)&sAl[e] = *(const uint4*)&Al[(size_t)(m0 + r) * 1024 + k0 + c];
                *(uint4*)&sBl[e] = *(const uint4*)&Bl[(size_t)(n0 + r) * 1024 + k0 + c];
            }
        }
        __syncthreads();
        short8 ah[4], al[4], bh[4], bl[4];
#pragma unroll
        for (int x = 0; x < 4; ++x) {
            int ra = (wr * 64 + x * 16 + l16) * 32 + quad * 8;
            int rb = (wc * 64 + x * 16 + l16) * 32 + quad * 8;
            ah[x] = *(const short8*)&sAh[ra];
            bh[x] = *(const short8*)&sBh[rb];
            if (mode) {
                al[x] = *(const short8*)&sAl[ra];
                bl[x] = *(const short8*)&sBl[rb];
            }
        }
#pragma unroll
        for (int mi = 0; mi < 4; ++mi)
#pragma unroll
            for (int ni = 0; ni < 4; ++ni) {
                acc[mi][ni] = __builtin_amdgcn_mfma_f32_16x16x32_bf16(
                    ah[mi], bh[ni], acc[mi][ni], 0, 0, 0);
                if (mode) {
                    acc[mi][ni] = __builtin_amdgcn_mfma_f32_16x16x32_bf16(
                        ah[mi], bl[ni], acc[mi][ni], 0, 0, 0);
                    acc[mi][ni] = __builtin_amdgcn_mfma_f32_16x16x32_bf16(
                        al[mi], bh[ni], acc[mi][ni], 0, 0, 0);
                }
            }
        __syncthreads();
    }
    // C/D layout: col = lane&15, row = (lane>>4)*4 + reg   [verified m89/m91]
#pragma unroll
    for (int mi = 0; mi < 4; ++mi)
#pragma unroll
        for (int ni = 0; ni < 4; ++ni)
#pragma unroll
            for (int r = 0; r < 4; ++r) {
                int row = m0 + wr * 64 + mi * 16 + quad * 4 + r;
                int col = n0 + wc * 64 + ni * 16 + l16;
                C[(size_t)row * 1024 + col] = acc[mi][ni][r];
            }
}

// ----------------------------------------------------- LayerNorm + pack
__global__ __launch_bounds__(256) void lnpack_kernel(
    const float* __restrict__ Y, const float* __restrict__ gamma,
    const float* __restrict__ beta, u16* __restrict__ Pk,
    float* __restrict__ head0, int do_ln)
{
    int r = blockIdx.x;
    int tid = threadIdx.x;
    float4 v = *(const float4*)&Y[(size_t)r * D_ + tid * 4];
    float mu = 0.f, rsig = 1.f;
    __shared__ float sS[4], sQ[4];
    if (do_ln) {
        float s = v.x + v.y + v.z + v.w;
        float q = v.x * v.x + v.y * v.y + v.z * v.z + v.w * v.w;
#pragma unroll
        for (int d = 1; d < 64; d <<= 1) { s += __shfl_xor(s, d); q += __shfl_xor(q, d); }
        if ((tid & 63) == 0) { sS[tid >> 6] = s; sQ[tid >> 6] = q; }
        __syncthreads();
        s = sS[0] + sS[1] + sS[2] + sS[3];
        q = sQ[0] + sQ[1] + sQ[2] + sQ[3];
        mu = s * (1.f / 1024.f);
        float var = q * (1.f / 1024.f) - mu * mu;
        rsig = rsqrtf(var + 1e-5f);
    }
    int b = r >> 11, n = r & 2047;
    float xs[4] = {v.x, v.y, v.z, v.w};
#pragma unroll
    for (int j = 0; j < 4; ++j) {
        int c = tid * 4 + j;
        float val = do_ln ? ((xs[j] - mu) * rsig * gamma[c] + beta[c]) : xs[j];
        int h = c >> 6, dh = c & 63;
        Pk[(((size_t)b * H_ + h) * N_ + n) * DH_ + dh] = f2b(val);
        if (head0 && c < 64) head0[(size_t)r * 64 + c] = val;
    }
}

// -------------------------------------------- head-0 selection scores S
__global__ void s_kernel(const float* __restrict__ q0,
                         const float* __restrict__ k0, float* __restrict__ S)
{
    int b = blockIdx.z;
    int n0 = blockIdx.y * 16, m0 = blockIdx.x * 16;
    int tx = threadIdx.x, ty = threadIdx.y;
    int n = n0 + ty, m = m0 + tx;
    float* out = S + ((size_t)b * N_ + n) * M_ + m;
    if (m0 > n0 + 15) { *out = 0.f; return; }   // fully above diagonal
    __shared__ float sq[16][65], sk[16][65];
    int tid = ty * 16 + tx;
    {
        int rr = tid >> 4, cc = (tid & 15) * 4;
        float4 qa = *(const float4*)&q0[((size_t)b * N_ + n0 + rr) * 64 + cc];
        sq[rr][cc] = qa.x; sq[rr][cc + 1] = qa.y; sq[rr][cc + 2] = qa.z; sq[rr][cc + 3] = qa.w;
        float4 ka = *(const float4*)&k0[((size_t)b * N_ + m0 + rr) * 64 + cc];
        sk[rr][cc] = ka.x; sk[rr][cc + 1] = ka.y; sk[rr][cc + 2] = ka.z; sk[rr][cc + 3] = ka.w;
    }
    __syncthreads();
    float acc = 0.f;
#pragma unroll 8
    for (int d = 0; d < 64; ++d) acc += sq[ty][d] * sk[tx][d];
    // causal (m>n) -> relu(-inf)=0 ; diagonal m==n -> 0 ; col 0 -> 0
    float val;
    if (m < n && m != 0) val = fmaxf(acc * 0.125f, 0.f); else val = 0.f;
    *out = val;
}

// -------------------------------- partial column sums of S rows 0..1023
__global__ __launch_bounds__(256) void p_kernel(const float* __restrict__ S,
                                                float* __restrict__ P)
{
    int b = blockIdx.z, c = blockIdx.y;
    int m = blockIdx.x * 256 + threadIdx.x;
    const float* base = S + ((size_t)b * N_ + c * 128) * M_ + m;
    float s = 0.f;
    for (int j = 0; j < 128; ++j) s += base[(size_t)j * M_];
    P[((size_t)b * 8 + c) * M_ + m] = s;
}

// --------------------------------------------- sequential greedy eviction
// (r9-proven 4-wave code, byte-identical logic, now a device function)
__device__ __forceinline__ void vsel(float& va, u32& la, float vb, u32 lb) {
    bool tk = vb > va;
    va = tk ? vb : va;
    la = tk ? lb : la;
}

template<int CTRL, int RMASK>
__device__ __forceinline__ void dpp_max_pack(float& v, u32& lo) {
    int hi = __float_as_int(v);
    int hi_o = __builtin_amdgcn_update_dpp(hi, hi, CTRL, RMASK, 0xF, false);
    int lo_o = __builtin_amdgcn_update_dpp((int)lo, (int)lo, CTRL, RMASK, 0xF, false);
    long long a = (long long)((((u64)(u32)hi) << 32) | lo);
    long long b = (long long)((((u64)(u32)hi_o) << 32) | (u32)lo_o);
    bool tk = b > a;
    v = tk ? __int_as_float(hi_o) : v;
    lo = tk ? (u32)lo_o : lo;
}

__device__ __forceinline__ void wave_argmax_to63(float& v, u32& lo) {
    dpp_max_pack<0x121, 0xF>(v, lo);   // row_ror:1
    dpp_max_pack<0x122, 0xF>(v, lo);   // row_ror:2
    dpp_max_pack<0x124, 0xF>(v, lo);   // row_ror:4
    dpp_max_pack<0x128, 0xF>(v, lo);   // row_ror:8
    dpp_max_pack<0x142, 0xA>(v, lo);   // row_bcast15 -> rows 1,3
    dpp_max_pack<0x143, 0xC>(v, lo);   // row_bcast31 -> rows 2,3
}

#define GLOAD(dst, voff, ptr, imm)                                    \
    asm volatile("global_load_dwordx4 %0, %1, %2 offset:" #imm        \
                 : "=v"(dst) : "v"(voff), "s"(ptr) : "memory")

#define ISSUE2(bank, row)                                             \
    {                                                                 \
        u32 r_ = (u32)((row) < 2047 ? (row) : 2047);                  \
        u32 vo = wbyte + r_ * 8192u;                                  \
        GLOAD(bank[0], vo, Sb, 0);                                    \
        GLOAD(bank[1], vo, Sb, 1024);                                 \
    }

#define VWAIT6()                                                      \
    do { asm volatile("s_waitcnt vmcnt(6)" ::: "memory");             \
         __builtin_amdgcn_sched_barrier(0); } while (0)
#define VWAIT0()                                                      \
    do { asm volatile("s_waitcnt vmcnt(0)" ::: "memory");             \
         __builtin_amdgcn_sched_barrier(0); } while (0)

__device__ __forceinline__ void evict_step4(
    int i, int t, int w, int par,
    const u32 (&lov)[2][4], float (&cum)[2][4], int (&evti)[2][4],
    const floatx4 (&bank)[2], uint2 (*spair)[4])
{
    const float NEGINF = __uint_as_float(0xFF800000u);
    // ---- per-wave (v, lo) tournament: ascending-index order, strict >
    float v0 = cum[0][0]; u32 l0 = lov[0][0];
    vsel(v0, l0, cum[0][1], lov[0][1]);
    float v1 = cum[0][2]; u32 l1 = lov[0][2];
    vsel(v1, l1, cum[0][3], lov[0][3]);
    vsel(v0, l0, v1, l1);
    float v2 = cum[1][0]; u32 l2 = lov[1][0];
    vsel(v2, l2, cum[1][1], lov[1][1]);
    float v3 = cum[1][2]; u32 l3 = lov[1][2];
    vsel(v3, l3, cum[1][3], lov[1][3]);
    vsel(v2, l2, v3, l3);
    vsel(v0, l0, v2, l2);
    wave_argmax_to63(v0, l0);
    // ---- cross-wave exchange (double-buffered by parity)
    if (t == 63) spair[par][w] = make_uint2(l0, (u32)__float_as_int(v0));
    asm volatile("s_waitcnt lgkmcnt(0)" ::: "memory");
    __builtin_amdgcn_sched_barrier(0);
    __builtin_amdgcn_s_barrier();      // raw barrier: no vmcnt drain
    __builtin_amdgcn_sched_barrier(0);
    uint2 q0 = spair[par][0], q1 = spair[par][1];
    uint2 q2 = spair[par][2], q3 = spair[par][3];
    long long k0 = (long long)((((u64)q0.y) << 32) | q0.x);
    long long k1 = (long long)((((u64)q1.y) << 32) | q1.x);
    long long k2 = (long long)((((u64)q2.y) << 32) | q2.x);
    long long k3 = (long long)((((u64)q3.y) << 32) | q3.x);
    long long ba = k0 > k1 ? k0 : k1;
    long long bb = k2 > k3 ? k2 : k3;
    long long bst = ba > bb ? ba : bb;   // packs unique (lo distinct)
    const u32 lostar = (u32)(bst & 0xFFFFFFFFll);
    // ---- update: Fm[i] -> Fm[i+1]
#pragma unroll
    for (int c = 0; c < 2; ++c) {
        cum[c][0] += bank[c][0]; cum[c][1] += bank[c][1];
        cum[c][2] += bank[c][2]; cum[c][3] += bank[c][3];
    }
    // ---- poison + record: branch-free, lostar uniform
#pragma unroll
    for (int c = 0; c < 2; ++c)
#pragma unroll
        for (int e = 0; e < 4; ++e) {
            bool hit = (lov[c][e] == lostar);
            cum[c][e] = hit ? NEGINF : cum[c][e];
            evti[c][e] = hit ? i : evti[c][e];
        }
}

__device__ void evict_role(const float* __restrict__ S,
                           const float* __restrict__ P,
                           int* __restrict__ evt)
{
    int b = blockIdx.x;
    int tid = threadIdx.x;
    int w = tid >> 6, t = tid & 63;            // 4 waves
    const float* Sb = S + (size_t)b * N_ * M_;
    int* evtb = evt + b * M_;
    const int mbase = 512 * w + 4 * t;
    const u32 wbyte = (u32)(2048 * w + 16 * t);  // byte offset within a row
    __shared__ uint2 spair[2][4];               // [parity][wave]
    u32 lov[2][4];
    int evti[2][4];
#pragma unroll
    for (int c = 0; c < 2; ++c)
#pragma unroll
        for (int e = 0; e < 4; ++e) {
            lov[c][e] = (u32)(2048 - (mbase + 256 * c + e));
            evti[c][e] = 0x3FFFFFFF;
        }
    // initial cum = column sums of the 8 partial chunks (same per-slot add
    // order as rounds 0-9 -> bitwise identical trajectories)
    float cum[2][4];
#pragma unroll
    for (int c = 0; c < 2; ++c) {
        float ax = 0.f, ay = 0.f, az = 0.f, aw = 0.f;
#pragma unroll
        for (int cc = 0; cc < 8; ++cc) {
            floatx4 pv = *(const floatx4*)&P[((size_t)b * 8 + cc) * M_ + mbase + 256 * c];
            ax += pv[0]; ay += pv[1]; az += pv[2]; aw += pv[3];
        }
        cum[c][0] = ax; cum[c][1] = ay; cum[c][2] = az; cum[c][3] = aw;
    }
    // fence: drain compiler-tracked loads so asm vmcnt counting is exact
    VWAIT0();
    floatx4 bA[2], bB[2], bC[2], bD[2];
    ISSUE2(bA, 1024)
    ISSUE2(bB, 1025)
    ISSUE2(bC, 1026)
    ISSUE2(bD, 1027)
#pragma unroll 1
    for (int ip = 1024; ip < 2048; ip += 4) {
        VWAIT6();
        evict_step4(ip + 0, t, w, 0, lov, cum, evti, bA, spair);
        ISSUE2(bA, ip + 4)
        VWAIT6();
        evict_step4(ip + 1, t, w, 1, lov, cum, evti, bB, spair);
        ISSUE2(bB, ip + 5)
        VWAIT6();
        evict_step4(ip + 2, t, w, 0, lov, cum, evti, bC, spair);
        ISSUE2(bC, ip + 6)
        VWAIT6();
        evict_step4(ip + 3, t, w, 1, lov, cum, evti, bD, spair);
        ISSUE2(bD, ip + 7)
    }
    VWAIT0();   // drain leftover bank loads before reusing the vmem queue
    // single coalesced write pass (the only global stores in this role)
#pragma unroll
    for (int c = 0; c < 2; ++c) {
        int4 o; o.x = evti[c][0]; o.y = evti[c][1];
        o.z = evti[c][2]; o.w = evti[c][3];
        *(int4*)&evtb[mbase + 256 * c] = o;
    }
}

// ------------------------------------------------------ flash attention
// role shared by the fused launch (evtg==nullptr: q<1024, mask pure causal)
// and flash2 (evtg!=nullptr).
__device__ void flash_role(
    const u16* __restrict__ Qb, const u16* __restrict__ Kb,
    const u16* __restrict__ Vb, const int* __restrict__ evtg,
    u16* __restrict__ Ob, int bh, int q0, int ktiles)
{
    int b = bh >> 4, h = bh & 15;
    int tid = threadIdx.x, lane = tid & 63, w = tid >> 6;
    int quad = lane >> 4, l16 = lane & 15;
    const u16* Qh = Qb + (size_t)bh * N_ * DH_;
    const u16* Kh = Kb + (size_t)bh * N_ * DH_;
    const u16* Vh = Vb + (size_t)bh * N_ * DH_;
    __shared__ __align__(16) u16 sK[64 * 64];
    __shared__ __align__(16) u16 sV[64 * 64];     // transposed [dh][key]
    __shared__ __align__(16) u16 sP[4][16 * 64];  // wave-private P
    __shared__ int sevt[64];

    // Q A-frags in registers: A[m=lane&15][k=quad*8+j]
    short8 aq0 = *(const short8*)&Qh[(size_t)(q0 + w * 16 + l16) * 64 + quad * 8];
    short8 aq1 = *(const short8*)&Qh[(size_t)(q0 + w * 16 + l16) * 64 + quad * 8 + 32];

    floatx4 zero = {0.f, 0.f, 0.f, 0.f};
    floatx4 accO[4];
#pragma unroll
    for (int d = 0; d < 4; ++d) accO[d] = zero;
    float m_i[4] = {-1e30f, -1e30f, -1e30f, -1e30f};
    float l_i[4] = {0.f, 0.f, 0.f, 0.f};

    for (int kt = 0; kt < ktiles; ++kt) {
        int k0 = kt * 64;
#pragma unroll
        for (int it = 0; it < 2; ++it) {
            int e = (tid + it * 256) * 8;
            int r = e >> 6, c = e & 63;
            *(uint4*)&sK[e] = *(const uint4*)&Kh[(size_t)(k0 + r) * 64 + c];
            uint4 vv = *(const uint4*)&Vh[(size_t)(k0 + r) * 64 + c];
            sV[(c + 0) * 64 + r] = (u16)(vv.x & 0xFFFF);
            sV[(c + 1) * 64 + r] = (u16)(vv.x >> 16);
            sV[(c + 2) * 64 + r] = (u16)(vv.y & 0xFFFF);
            sV[(c + 3) * 64 + r] = (u16)(vv.y >> 16);
            sV[(c + 4) * 64 + r] = (u16)(vv.z & 0xFFFF);
            sV[(c + 5) * 64 + r] = (u16)(vv.z >> 16);
            sV[(c + 6) * 64 + r] = (u16)(vv.w & 0xFFFF);
            sV[(c + 7) * 64 + r] = (u16)(vv.w >> 16);
        }
        if (evtg && tid < 64) sevt[tid] = evtg[b * M_ + k0 + tid];
        __syncthreads();

        floatx4 lg[4];
        int nbase = q0 + w * 16 + quad * 4;
#pragma unroll
        for (int s = 0; s < 4; ++s) {
            floatx4 sc = zero;
            short8 bk0 = *(const short8*)&sK[(s * 16 + l16) * 64 + quad * 8];
            short8 bk1 = *(const short8*)&sK[(s * 16 + l16) * 64 + quad * 8 + 32];
            sc = __builtin_amdgcn_mfma_f32_16x16x32_bf16(aq0, bk0, sc, 0, 0, 0);
            sc = __builtin_amdgcn_mfma_f32_16x16x32_bf16(aq1, bk1, sc, 0, 0, 0);
            int m = k0 + s * 16 + l16;
            int ev = evtg ? sevt[s * 16 + l16] : 0x7FFFFFFF;
#pragma unroll
            for (int r = 0; r < 4; ++r) {
                int n = nbase + r;
                bool keep = (m <= n) && (n < ev);
                lg[s][r] = keep ? sc[r] * 0.125f : -1e30f;
            }
        }
        float mnew[4], scale[4], rs[4];
#pragma unroll
        for (int r = 0; r < 4; ++r) {
            float mx = fmaxf(fmaxf(lg[0][r], lg[1][r]), fmaxf(lg[2][r], lg[3][r]));
#pragma unroll
            for (int d = 1; d < 16; d <<= 1) mx = fmaxf(mx, __shfl_xor(mx, d));
            mnew[r] = fmaxf(m_i[r], mx);
            scale[r] = __expf(m_i[r] - mnew[r]);
            m_i[r] = mnew[r];
            rs[r] = 0.f;
        }
#pragma unroll
        for (int s = 0; s < 4; ++s)
#pragma unroll
            for (int r = 0; r < 4; ++r) {
                float p = __expf(lg[s][r] - mnew[r]);
                rs[r] += p;
                sP[w][(quad * 4 + r) * 64 + s * 16 + l16] = f2b(p);
            }
#pragma unroll
        for (int r = 0; r < 4; ++r) {
            float t_ = rs[r];
#pragma unroll
            for (int d = 1; d < 16; d <<= 1) t_ += __shfl_xor(t_, d);
            l_i[r] = l_i[r] * scale[r] + t_;
        }
#pragma unroll
        for (int dd = 0; dd < 4; ++dd) {
            accO[dd][0] *= scale[0]; accO[dd][1] *= scale[1];
            accO[dd][2] *= scale[2]; accO[dd][3] *= scale[3];
        }
        // P: C-layout -> A-layout via wave-private LDS round-trip
        short8 ap0 = *(const short8*)&sP[w][l16 * 64 + quad * 8];
        short8 ap1 = *(const short8*)&sP[w][l16 * 64 + quad * 8 + 32];
#pragma unroll
        for (int dd = 0; dd < 4; ++dd) {
            short8 bv0 = *(const short8*)&sV[(dd * 16 + l16) * 64 + quad * 8];
            short8 bv1 = *(const short8*)&sV[(dd * 16 + l16) * 64 + quad * 8 + 32];
            accO[dd] = __builtin_amdgcn_mfma_f32_16x16x32_bf16(ap0, bv0, accO[dd], 0, 0, 0);
            accO[dd] = __builtin_amdgcn_mfma_f32_16x16x32_bf16(ap1, bv1, accO[dd], 0, 0, 0);
        }
        __syncthreads();
    }
#pragma unroll
    for (int dd = 0; dd < 4; ++dd)
#pragma unroll
        for (int r = 0; r < 4; ++r) {
            int n = q0 + w * 16 + quad * 4 + r;
            int col = h * 64 + dd * 16 + l16;
            Ob[((size_t)b * N_ + n) * D_ + col] = f2b(accO[dd][r] / l_i[r]);
        }
}

// --------------------------- fused launch: evict ∥ flash part 1 (q<1024)
__global__ __launch_bounds__(256) void fused_evict_flash1(
    const float* __restrict__ S, const float* __restrict__ P,
    int* __restrict__ evt,
    const u16* __restrict__ Qb, const u16* __restrict__ Kb,
    const u16* __restrict__ Vb, u16* __restrict__ Ob)
{
    if (blockIdx.x < 2) {
        evict_role(S, P, evt);
    } else {
        int fid = blockIdx.x - 2;          // 0..511
        int bh = fid >> 4, j = fid & 15;   // q-tiles 0..15: n < 1024, no evt
        flash_role(Qb, Kb, Vb, nullptr, Ob, bh, j * 64, j + 1);
    }
}

// --------------------------------------- flash part 2 (q>=1024, needs evt)
__global__ __launch_bounds__(256) void flash2_kernel(
    const u16* __restrict__ Qb, const u16* __restrict__ Kb,
    const u16* __restrict__ Vb, const int* __restrict__ evt,
    u16* __restrict__ Ob)
{
    int j = blockIdx.x + 16;               // q-tiles 16..31
    flash_role(Qb, Kb, Vb, evt, Ob, blockIdx.y, j * 64, j + 1);
}

// ---------------------------------------------------------------- launch
extern "C" void kernel_launch(void* const* d_in, const int* in_sizes, int n_in,
                              void* d_out, int out_size, void* d_ws, size_t ws_size,
                              hipStream_t stream)
{
    (void)in_sizes; (void)n_in; (void)out_size; (void)ws_size;
    const float* X  = (const float*)d_in[0];
    const float* Wq = (const float*)d_in[1];
    const float* Wk = (const float*)d_in[2];
    const float* Wv = (const float*)d_in[3];
    const float* Wo = (const float*)d_in[4];
    const float* gq = (const float*)d_in[5];
    const float* bq = (const float*)d_in[6];
    const float* gk = (const float*)d_in[7];
    const float* bk = (const float*)d_in[8];
    // d_in[9] cache_k, d_in[10] cache_v, d_in[11] start_pos: start_pos==0 here.

    char* p = (char*)d_ws;
    const size_t SZ_XH = (size_t)ROWS_ * D_ * 2;   // 8 MiB bf16
    const size_t SZ_W  = (size_t)D_ * D_ * 2;      // 2 MiB bf16
    const size_t SZ_Y  = (size_t)ROWS_ * D_ * 4;   // 16 MiB fp32
    const size_t SZ_PK = (size_t)ROWS_ * D_ * 2;   // 8 MiB bf16
    const size_t SZ_H0 = (size_t)ROWS_ * 64 * 4;   // 1 MiB fp32

    size_t o = 0;
    u16* Xhi = (u16*)(p + o); o += SZ_XH;
    u16* Xlo = (u16*)(p + o); o += SZ_XH;
    u16* Wqh = (u16*)(p + o); o += SZ_W;
    u16* Wql = (u16*)(p + o); o += SZ_W;
    u16* Wkh = (u16*)(p + o); o += SZ_W;
    u16* Wkl = (u16*)(p + o); o += SZ_W;
    u16* Wvh = (u16*)(p + o); o += SZ_W;
    u16* Woh = (u16*)(p + o); o += SZ_W;
    float* Yq = (float*)(p + o); size_t oYq = o; o += SZ_Y;
    float* Yk = (float*)(p + o); o += SZ_Y;
    float* Yv = (float*)(p + o); o += SZ_Y;
    u16* Qb = (u16*)(p + o); o += SZ_PK;
    u16* Kb = (u16*)(p + o); o += SZ_PK;
    u16* Vb = (u16*)(p + o); o += SZ_PK;
    float* q0s = (float*)(p + o); o += SZ_H0;
    float* k0s = (float*)(p + o); o += SZ_H0;
    float* Pp  = (float*)(p + o); o += (size_t)B_ * 8 * M_ * 4;
    int* evt   = (int*)(p + o);  o += (size_t)B_ * M_ * 4;
    // overlays (dead slots):
    float* S = (float*)(p + oYq);   // 32 MiB over Yq+Yk, used after LN
    u16* Ob  = Xhi;                 // 8 MiB over Xhi, used after all X-GEMMs

    cast_x_kernel<<<ROWS_ * D_ / (256 * 4), 256, 0, stream>>>(X, Xhi, Xlo);
    dim3 wgrid(32, 32), wblk(32, 32);
    cast_w_kernel<<<wgrid, wblk, 0, stream>>>(Wq, Wqh, Wql, 1);
    cast_w_kernel<<<wgrid, wblk, 0, stream>>>(Wk, Wkh, Wkl, 1);
    cast_w_kernel<<<wgrid, wblk, 0, stream>>>(Wv, Wvh, nullptr, 0);
    cast_w_kernel<<<wgrid, wblk, 0, stream>>>(Wo, Woh, nullptr, 0);

    dim3 ggrid(D_ / 128, ROWS_ / 128);
    gemm_kernel<<<ggrid, 256, 0, stream>>>(Xhi, Xlo, Wqh, Wql, 1, Yq);
    gemm_kernel<<<ggrid, 256, 0, stream>>>(Xhi, Xlo, Wkh, Wkl, 1, Yk);
    gemm_kernel<<<ggrid, 256, 0, stream>>>(Xhi, nullptr, Wvh, nullptr, 0, Yv);

    lnpack_kernel<<<ROWS_, 256, 0, stream>>>(Yq, gq, bq, Qb, q0s, 1);
    lnpack_kernel<<<ROWS_, 256, 0, stream>>>(Yk, gk, bk, Kb, k0s, 1);
    lnpack_kernel<<<ROWS_, 256, 0, stream>>>(Yv, nullptr, nullptr, Vb, nullptr, 0);

    s_kernel<<<dim3(M_ / 16, N_ / 16, B_), dim3(16, 16), 0, stream>>>(q0s, k0s, S);
    p_kernel<<<dim3(M_ / 256, 8, B_), 256, 0, stream>>>(S, Pp);

    // evict (blocks 0,1) runs concurrently with flash q<1024 (blocks 2..513)
    fused_evict_flash1<<<514, 256, 0, stream>>>(S, Pp, evt, Qb, Kb, Vb, Ob);
    flash2_kernel<<<dim3(16, B_ * H_), 256, 0, stream>>>(Qb, Kb, Vb, evt, Ob);

    gemm_kernel<<<ggrid, 256, 0, stream>>>(Ob, nullptr, Woh, nullptr, 0, (float*)d_out);
}